// Round 2
// baseline (916.293 us; speedup 1.0000x reference)
//
#include <hip/hip_runtime.h>
#include <cstddef>
#include <cstdint>

// Shapes: B=4, M=16, T=256, D=128, H=8, CTX=16, L=2
static constexpr int D_ = 128;
static constexpr int NROW = 16384;              // B*M*T rows
static constexpr size_t S_ = (size_t)NROW * D_; // elements per activation tensor

__device__ __forceinline__ float wsum64(float s) {
#pragma unroll
  for (int off = 32; off >= 1; off >>= 1) s += __shfl_xor(s, off);
  return s;
}

// ---------------- per-row LN stats: st[row] = (mu, rstd) ----------------
__global__ __launch_bounds__(256) void stats_kernel(const float* __restrict__ X,
                                                    float2* __restrict__ st) {
  int wid = threadIdx.x >> 6, lane = threadIdx.x & 63;
  int row = (blockIdx.x << 2) + wid;
  float2 xv = *(const float2*)(X + (size_t)row * D_ + lane * 2);
  float s = wsum64(xv.x + xv.y);
  float sq = wsum64(xv.x * xv.x + xv.y * xv.y);
  float mu = s * (1.0f / 128.0f);
  float var = sq * (1.0f / 128.0f) - mu * mu;
  if (lane == 0) st[row] = make_float2(mu, rsqrtf(var + 1e-6f));
}

// ---------------- full LayerNorm (final, in-place safe) ----------------
__global__ __launch_bounds__(256) void ln_kernel(
    const float* __restrict__ X, const float* __restrict__ g,
    const float* __restrict__ b, float* __restrict__ Y) {
  int wid = threadIdx.x >> 6, lane = threadIdx.x & 63;
  int row = (blockIdx.x << 2) + wid;
  float2 xv = *(const float2*)(X + (size_t)row * D_ + lane * 2);
  float s = wsum64(xv.x + xv.y);
  float sq = wsum64(xv.x * xv.x + xv.y * xv.y);
  float mu = s * (1.0f / 128.0f);
  float var = sq * (1.0f / 128.0f) - mu * mu;
  float rstd = rsqrtf(var + 1e-6f);
  float2 gv = *(const float2*)(g + lane * 2);
  float2 bv = *(const float2*)(b + lane * 2);
  float2 o;
  o.x = (xv.x - mu) * rstd * gv.x + bv.x;
  o.y = (xv.y - mu) * rstd * gv.y + bv.y;
  *(float2*)(Y + (size_t)row * D_ + lane * 2) = o;
}

// ------- GEMM: C[N,128] = op(A)[N,128] @ W[128 rows, ldw]^T + bias (+relu) (+resid)
// op(A) = LayerNorm(A) via stats st + gamma/beta if st != nullptr.
__global__ __launch_bounds__(256) void gemm128_kernel(
    const float* __restrict__ A, const float* __restrict__ W, int ldw,
    const float* __restrict__ bias, const float2* __restrict__ st,
    const float* __restrict__ lng, const float* __restrict__ lnb,
    const float* __restrict__ resid, float* __restrict__ C, int relu) {
  __shared__ float As[64][33];
  __shared__ float Ws[64][33];
  const int n0 = blockIdx.y << 6;
  const int e0 = blockIdx.x << 6;
  const int tid = threadIdx.x;
  const int tr = tid >> 4, tc = tid & 15;
  float acc[4][4] = {};
  for (int k0 = 0; k0 < 128; k0 += 32) {
#pragma unroll
    for (int i = 0; i < 8; i++) {
      int idx = tid + (i << 8);
      int r = idx >> 5, c = idx & 31;
      float a = A[(size_t)(n0 + r) * 128 + k0 + c];
      if (st) {
        float2 s2 = st[n0 + r];
        a = (a - s2.x) * s2.y * lng[k0 + c] + lnb[k0 + c];
      }
      As[r][c] = a;
      Ws[r][c] = W[(size_t)(e0 + r) * ldw + k0 + c];
    }
    __syncthreads();
#pragma unroll
    for (int kk = 0; kk < 32; kk++) {
      float a[4], w[4];
#pragma unroll
      for (int i = 0; i < 4; i++) a[i] = As[tr * 4 + i][kk];
#pragma unroll
      for (int j = 0; j < 4; j++) w[j] = Ws[tc * 4 + j][kk];
#pragma unroll
      for (int i = 0; i < 4; i++)
#pragma unroll
        for (int j = 0; j < 4; j++) acc[i][j] = fmaf(a[i], w[j], acc[i][j]);
    }
    __syncthreads();
  }
#pragma unroll
  for (int i = 0; i < 4; i++) {
    int n = n0 + tr * 4 + i;
    int e = e0 + tc * 4;
    float4 v;
    float* vp = (float*)&v;
#pragma unroll
    for (int j = 0; j < 4; j++) {
      float val = acc[i][j];
      if (bias) val += bias[e + j];
      if (relu) val = fmaxf(val, 0.0f);
      vp[j] = val;
    }
    if (resid) {
      float4 rv = *(const float4*)(resid + (size_t)n * 128 + e);
      v.x += rv.x; v.y += rv.y; v.z += rv.z; v.w += rv.w;
    }
    *(float4*)(C + (size_t)n * 128 + e) = v;
  }
}

// ------- context-attention softmax weights per row (window 16, zero-pad scores=0) -------
__global__ __launch_bounds__(64) void ctxw_kernel(
    const float* __restrict__ q, const float* __restrict__ k,
    float* __restrict__ wq, float* __restrict__ wk) {
  const float* src = blockIdx.y ? k : q;
  float* dst = blockIdx.y ? wk : wq;
  int row = blockIdx.x;
  int t = row & 255;
  int lane = threadIdx.x;
  float2 xv = *(const float2*)(src + (size_t)row * D_ + lane * 2);
  float sc[16];
#pragma unroll
  for (int l = 0; l < 16; l++) {
    int ts = t - 15 + l;
    float d = 0.f;
    if (ts >= 0) {
      float2 w = *(const float2*)(src + (size_t)(row - 15 + l) * D_ + lane * 2);
      d = xv.x * w.x + xv.y * w.y;
    }
    sc[l] = wsum64(d) * 0.08838834764831845f;  // 1/sqrt(128)
  }
  float mx = sc[0];
#pragma unroll
  for (int l = 1; l < 16; l++) mx = fmaxf(mx, sc[l]);
  float den = 0.f;
#pragma unroll
  for (int l = 0; l < 16; l++) { sc[l] = __expf(sc[l] - mx); den += sc[l]; }
  float inv = 1.0f / den;
  float myv = sc[0];
#pragma unroll
  for (int l = 1; l < 16; l++) myv = (lane == l) ? sc[l] : myv;
  if (lane < 16) dst[(size_t)row * 16 + lane] = myv * inv;
}

// ------- attn1: builds cq/ck per head-slice from (q,k,weights), flash over T=256,
//         writes output IN-PLACE over the q buffer (block-exclusive slice) -------
__global__ __launch_bounds__(256) void attn1_kernel(
    const float* __restrict__ q, const float* __restrict__ k,
    const float* __restrict__ v, const float* __restrict__ wq,
    const float* __restrict__ wk, float* __restrict__ xa) {
  __shared__ float4 cqs[256][4];
  __shared__ float4 cks[256][4];
  __shared__ float4 vs[256][4];
  int bm = blockIdx.x >> 3, h = blockIdx.x & 7;
  int tid = threadIdx.x;
  const size_t rbase = (size_t)bm * 256;
  const int cbase = h * 16;
  // phase 1: build cq,ck rows (row = tid) from global + stage v
  const float* wqr = wq + (rbase + tid) * 16;
  const float* wkr = wk + (rbase + tid) * 16;
  float4 aq[4], ak[4];
#pragma unroll
  for (int c = 0; c < 4; c++) { aq[c] = make_float4(0,0,0,0); ak[c] = make_float4(0,0,0,0); }
#pragma unroll
  for (int l = 0; l < 16; l++) {
    int ts = tid - 15 + l;
    if (ts >= 0) {
      float wql = wqr[l], wkl = wkr[l];
      const float* qp = q + (rbase + ts) * 128 + cbase;
      const float* kp = k + (rbase + ts) * 128 + cbase;
#pragma unroll
      for (int c = 0; c < 4; c++) {
        float4 qv = *(const float4*)(qp + c * 4);
        aq[c].x = fmaf(wql, qv.x, aq[c].x); aq[c].y = fmaf(wql, qv.y, aq[c].y);
        aq[c].z = fmaf(wql, qv.z, aq[c].z); aq[c].w = fmaf(wql, qv.w, aq[c].w);
        float4 kv = *(const float4*)(kp + c * 4);
        ak[c].x = fmaf(wkl, kv.x, ak[c].x); ak[c].y = fmaf(wkl, kv.y, ak[c].y);
        ak[c].z = fmaf(wkl, kv.z, ak[c].z); ak[c].w = fmaf(wkl, kv.w, ak[c].w);
      }
    }
  }
#pragma unroll
  for (int c = 0; c < 4; c++) {
    cqs[tid][c] = aq[c];
    cks[tid][c] = ak[c];
    vs[tid][c] = *(const float4*)(v + (rbase + tid) * 128 + cbase + c * 4);
  }
  __syncthreads();
  // phase 2: flash attention over 256 keys (head dim 16)
  float4 q0 = cqs[tid][0], q1 = cqs[tid][1], q2 = cqs[tid][2], q3 = cqs[tid][3];
  float m = -1e30f, l = 0.f;
  float4 a0 = {0,0,0,0}, a1 = {0,0,0,0}, a2 = {0,0,0,0}, a3 = {0,0,0,0};
  for (int kk = 0; kk < 256; kk++) {
    float4 c0 = cks[kk][0], c1 = cks[kk][1], c2 = cks[kk][2], c3 = cks[kk][3];
    float s = q0.x*c0.x + q0.y*c0.y + q0.z*c0.z + q0.w*c0.w +
              q1.x*c1.x + q1.y*c1.y + q1.z*c1.z + q1.w*c1.w +
              q2.x*c2.x + q2.y*c2.y + q2.z*c2.z + q2.w*c2.w +
              q3.x*c3.x + q3.y*c3.y + q3.z*c3.z + q3.w*c3.w;
    s *= 0.25f;  // 1/sqrt(16)
    float mn = fmaxf(m, s);
    float scale = __expf(m - mn);
    float p = __expf(s - mn);
    l = l * scale + p;
    float4 v0 = vs[kk][0], v1 = vs[kk][1], v2 = vs[kk][2], v3 = vs[kk][3];
    a0.x = a0.x*scale + p*v0.x; a0.y = a0.y*scale + p*v0.y;
    a0.z = a0.z*scale + p*v0.z; a0.w = a0.w*scale + p*v0.w;
    a1.x = a1.x*scale + p*v1.x; a1.y = a1.y*scale + p*v1.y;
    a1.z = a1.z*scale + p*v1.z; a1.w = a1.w*scale + p*v1.w;
    a2.x = a2.x*scale + p*v2.x; a2.y = a2.y*scale + p*v2.y;
    a2.z = a2.z*scale + p*v2.z; a2.w = a2.w*scale + p*v2.w;
    a3.x = a3.x*scale + p*v3.x; a3.y = a3.y*scale + p*v3.y;
    a3.z = a3.z*scale + p*v3.z; a3.w = a3.w*scale + p*v3.w;
    m = mn;
  }
  float inv = 1.0f / l;
  float* out = xa + (rbase + tid) * 128 + cbase;
  a0.x*=inv; a0.y*=inv; a0.z*=inv; a0.w*=inv;
  a1.x*=inv; a1.y*=inv; a1.z*=inv; a1.w*=inv;
  a2.x*=inv; a2.y*=inv; a2.z*=inv; a2.w*=inv;
  a3.x*=inv; a3.y*=inv; a3.z*=inv; a3.w*=inv;
  *(float4*)(out + 0)  = a0;
  *(float4*)(out + 4)  = a1;
  *(float4*)(out + 8)  = a2;
  *(float4*)(out + 12) = a3;
}

// ------- attn2 over M=16 axis; writes scrambled layout g=q*4+b -------
__global__ __launch_bounds__(128) void attn2_kernel(
    const float* __restrict__ xa, float* __restrict__ xr) {
  __shared__ float xas[16][128];
  int b = blockIdx.x >> 8, t = blockIdx.x & 255;
  int tid = threadIdx.x;
#pragma unroll
  for (int j = 0; j < 4; j++) {
    int idx = tid + (j << 7);
    int r = idx >> 5, c4 = idx & 31;
    *(float4*)&xas[r][c4 * 4] =
        *(const float4*)(xa + ((size_t)((b * 16 + r) * 256 + t)) * 128 + c4 * 4);
  }
  __syncthreads();
  int h = tid >> 4, q = tid & 15;
  float xq[16];
#pragma unroll
  for (int d = 0; d < 16; d++) xq[d] = xas[q][h * 16 + d];
  float sc[16];
  float mx = -1e30f;
#pragma unroll
  for (int k = 0; k < 16; k++) {
    float s = 0.f;
#pragma unroll
    for (int d = 0; d < 16; d++) s += xq[d] * xas[k][h * 16 + d];
    s *= 0.25f;
    sc[k] = s;
    mx = fmaxf(mx, s);
  }
  float den = 0.f;
#pragma unroll
  for (int k = 0; k < 16; k++) { sc[k] = __expf(sc[k] - mx); den += sc[k]; }
  float inv = 1.0f / den;
  float out[16] = {};
#pragma unroll
  for (int k = 0; k < 16; k++) {
    float w = sc[k];
#pragma unroll
    for (int d = 0; d < 16; d++) out[d] += w * xas[k][h * 16 + d];
  }
  int g = q * 4 + b;
  float* dst = xr + ((size_t)(g * 256 + t)) * 128 + h * 16;
#pragma unroll
  for (int p = 0; p < 4; p++) {
    float4 o;
    o.x = out[p*4+0]*inv; o.y = out[p*4+1]*inv;
    o.z = out[p*4+2]*inv; o.w = out[p*4+3]*inv;
    *(float4*)(dst + p * 4) = o;
  }
}

extern "C" void kernel_launch(void* const* d_in, const int* in_sizes, int n_in,
                              void* d_out, int out_size, void* d_ws, size_t ws_size,
                              hipStream_t stream) {
  const float* x    = (const float*)d_in[0];
  const float* Wq   = (const float*)d_in[1];
  const float* bq   = (const float*)d_in[2];
  const float* Wk   = (const float*)d_in[3];
  const float* bk   = (const float*)d_in[4];
  const float* Wv   = (const float*)d_in[5];
  const float* bv   = (const float*)d_in[6];
  const float* Wo   = (const float*)d_in[7];
  const float* bo   = (const float*)d_in[8];
  const float* W1   = (const float*)d_in[9];
  const float* b1   = (const float*)d_in[10];
  const float* W2   = (const float*)d_in[11];
  const float* b2   = (const float*)d_in[12];
  const float* ln1g = (const float*)d_in[13];
  const float* ln1b = (const float*)d_in[14];
  const float* ln2g = (const float*)d_in[15];
  const float* ln2b = (const float*)d_in[16];
  const float* lnfg = (const float*)d_in[17];
  const float* lnfb = (const float*)d_in[18];

  // Workspace footprint: 3*S_ + 2*NROW*16 + NROW*2 floats = 26.1 MB
  float* wsf = (float*)d_ws;
  float* B0 = wsf;            // q -> xa -> ffn mid chunk
  float* B1 = wsf + S_;       // k -> xr
  float* B2 = wsf + 2 * S_;   // v -> ffn accumulator
  float* wqw = wsf + 3 * S_;              // [NROW*16]
  float* wkw = wqw + (size_t)NROW * 16;   // [NROW*16]
  float2* T  = (float2*)(wkw + (size_t)NROW * 16);  // [NROW] (mu, rstd)
  float* Y = (float*)d_out;   // residual stream lives in d_out

  for (int i = 0; i < 2; i++) {
    const float* cur = (i == 0) ? x : Y;
    // LN1 stats
    stats_kernel<<<4096, 256, 0, stream>>>(cur, T);
    // q,k,v = LN(cur) @ W^T + b   (LN fused into A-staging)
    gemm128_kernel<<<dim3(2, 256), 256, 0, stream>>>(cur, Wv + i*16384, 128, bv + i*128, T, ln1g + i*128, ln1b + i*128, nullptr, B2, 0);
    gemm128_kernel<<<dim3(2, 256), 256, 0, stream>>>(cur, Wq + i*16384, 128, bq + i*128, T, ln1g + i*128, ln1b + i*128, nullptr, B0, 0);
    gemm128_kernel<<<dim3(2, 256), 256, 0, stream>>>(cur, Wk + i*16384, 128, bk + i*128, T, ln1g + i*128, ln1b + i*128, nullptr, B1, 0);
    // context-attention softmax weights for q and k
    ctxw_kernel<<<dim3(16384, 2), 64, 0, stream>>>(B0, B1, wqw, wkw);
    // attn over T (builds cq/ck on the fly; output in-place over B0)
    attn1_kernel<<<512, 256, 0, stream>>>(B0, B1, B2, wqw, wkw, B0);
    // attn over M with scrambled write
    attn2_kernel<<<1024, 128, 0, stream>>>(B0, B1);
    // y = cur + xr @ Wo^T + bo
    gemm128_kernel<<<dim3(2, 256), 256, 0, stream>>>(B1, Wo + i*16384, 128, bo + i*128, nullptr, nullptr, nullptr, cur, Y, 0);
    // LN2 stats
    stats_kernel<<<4096, 256, 0, stream>>>(Y, T);
    // FFN in 4 chunks of 128 hidden dims; accumulate into B2, last chunk -> Y
    for (int c = 0; c < 4; c++) {
      gemm128_kernel<<<dim3(2, 256), 256, 0, stream>>>(Y, W1 + i*65536 + c*16384, 128, b1 + i*512 + c*128, T, ln2g + i*128, ln2b + i*128, nullptr, B0, 1);
      const float* rs = (c == 0) ? Y : B2;
      float* dst = (c == 3) ? Y : B2;
      gemm128_kernel<<<dim3(2, 256), 256, 0, stream>>>(B0, W2 + i*65536 + c*128, 512, (c == 0) ? (b2 + i*128) : nullptr, nullptr, nullptr, nullptr, rs, dst, 0);
    }
  }
  // final LN, in-place on d_out
  ln_kernel<<<4096, 256, 0, stream>>>(Y, lnfg, lnfb, Y);
}

// Round 3
// 821.475 us; speedup vs baseline: 1.1154x; 1.1154x over previous
//
#include <hip/hip_runtime.h>
#include <cstddef>
#include <cstdint>

// Shapes: B=4, M=16, T=256, D=128, H=8, CTX=16, L=2
static constexpr int D_ = 128;
static constexpr int NROW = 16384;               // B*M*T rows
static constexpr size_t S_ = (size_t)NROW * D_;  // elems per activation

typedef __attribute__((ext_vector_type(8))) short bf16x8;
typedef __attribute__((ext_vector_type(4))) float f32x4;
typedef __attribute__((ext_vector_type(8))) unsigned short ushortx8;

__device__ __forceinline__ unsigned short f2bf(float f) {
  unsigned int u = __float_as_uint(f);
  u += 0x7fff + ((u >> 16) & 1);
  return (unsigned short)(u >> 16);
}
__device__ __forceinline__ float bf2f(unsigned short h) {
  return __uint_as_float(((unsigned int)h) << 16);
}
__device__ __forceinline__ float wsum64(float s) {
#pragma unroll
  for (int off = 32; off >= 1; off >>= 1) s += __shfl_xor(s, off);
  return s;
}

// ---------------- per-row LN stats: st[row] = (mu, rstd) ----------------
__global__ __launch_bounds__(256) void stats_kernel(const float* __restrict__ X,
                                                    float2* __restrict__ st) {
  int wid = threadIdx.x >> 6, lane = threadIdx.x & 63;
  int row = (blockIdx.x << 2) + wid;
  float2 xv = *(const float2*)(X + (size_t)row * D_ + lane * 2);
  float s = wsum64(xv.x + xv.y);
  float sq = wsum64(xv.x * xv.x + xv.y * xv.y);
  float mu = s * (1.0f / 128.0f);
  float var = sq * (1.0f / 128.0f) - mu * mu;
  if (lane == 0) st[row] = make_float2(mu, rsqrtf(var + 1e-6f));
}

// ------- convert fp32 -> bf16, optionally applying LN (st + gamma/beta) -------
__global__ __launch_bounds__(256) void convln_kernel(
    const float* __restrict__ X, const float2* __restrict__ st,
    const float* __restrict__ g, const float* __restrict__ b,
    unsigned short* __restrict__ out) {
  size_t idx = ((size_t)blockIdx.x * 256 + threadIdx.x) * 8;
  int row = (int)(idx >> 7), col = (int)(idx & 127);
  float4 v0 = *(const float4*)(X + idx);
  float4 v1 = *(const float4*)(X + idx + 4);
  float mu = 0.f, rs = 1.f;
  if (st) { float2 s = st[row]; mu = s.x; rs = s.y; }
  float o[8] = {v0.x, v0.y, v0.z, v0.w, v1.x, v1.y, v1.z, v1.w};
  ushortx8 r;
#pragma unroll
  for (int j = 0; j < 8; j++) {
    float t = (o[j] - mu) * rs;
    if (g) t = t * g[col + j] + b[col + j];
    r[j] = f2bf(t);
  }
  *(ushortx8*)(out + idx) = r;
}

// ------- convert all 6 weight tensors (both layers) fp32 -> bf16 -------
__global__ __launch_bounds__(256) void wconv_kernel(
    const float* __restrict__ Wq, const float* __restrict__ Wk,
    const float* __restrict__ Wv, const float* __restrict__ Wo,
    const float* __restrict__ W1, const float* __restrict__ W2,
    unsigned short* __restrict__ out) {
  size_t i = ((size_t)blockIdx.x * 256 + threadIdx.x) * 8;
  const float* src; size_t off;
  if      (i < 32768)  { src = Wq; off = i; }
  else if (i < 65536)  { src = Wk; off = i - 32768; }
  else if (i < 98304)  { src = Wv; off = i - 65536; }
  else if (i < 131072) { src = Wo; off = i - 98304; }
  else if (i < 262144) { src = W1; off = i - 131072; }
  else                 { src = W2; off = i - 262144; }
  ushortx8 r;
#pragma unroll
  for (int j = 0; j < 8; j++) r[j] = f2bf(src[off + j]);
  *(ushortx8*)(out + i) = r;
}

// ------- bf16 MFMA GEMM: C[N,128] = A[N,128]bf16 @ W[128,ldw]bf16^T (+bias,relu,resid)
// Zero LDS: MFMA fragments are contiguous 16B runs of row-major bf16 -> direct global loads.
__global__ __launch_bounds__(64) void gemm_mfma_kernel(
    const unsigned short* __restrict__ A, const unsigned short* __restrict__ W,
    int ldw, const float* __restrict__ bias, const float* __restrict__ resid,
    float* __restrict__ Cf, unsigned short* __restrict__ Cb, int relu) {
  const int m0 = blockIdx.x * 32;
  const int l = threadIdx.x;
  const int lr = l & 15;
  const int lk = (l >> 4) * 8;
  f32x4 acc[2][8] = {};
  const unsigned short* Ap = A + (size_t)(m0 + lr) * 128 + lk;
  const unsigned short* Wp = W + (size_t)lr * ldw + lk;
#pragma unroll
  for (int k0 = 0; k0 < 128; k0 += 32) {
    bf16x8 a0 = *(const bf16x8*)(Ap + k0);
    bf16x8 a1 = *(const bf16x8*)(Ap + 16 * 128 + k0);
#pragma unroll
    for (int n = 0; n < 8; n++) {
      bf16x8 b = *(const bf16x8*)(Wp + (size_t)n * 16 * ldw + k0);
      acc[0][n] = __builtin_amdgcn_mfma_f32_16x16x32_bf16(a0, b, acc[0][n], 0, 0, 0);
      acc[1][n] = __builtin_amdgcn_mfma_f32_16x16x32_bf16(a1, b, acc[1][n], 0, 0, 0);
    }
  }
  const int rb = (l >> 4) * 4;
#pragma unroll
  for (int m = 0; m < 2; m++) {
#pragma unroll
    for (int n = 0; n < 8; n++) {
      int col = n * 16 + lr;
      float bv = bias ? bias[col] : 0.f;
#pragma unroll
      for (int j = 0; j < 4; j++) {
        int row = m0 + m * 16 + rb + j;
        float v = acc[m][n][j] + bv;
        if (relu) v = fmaxf(v, 0.f);
        if (resid) v += resid[(size_t)row * 128 + col];
        if (Cf) Cf[(size_t)row * 128 + col] = v;
        else Cb[(size_t)row * 128 + col] = f2bf(v);
      }
    }
  }
}

// ------- context-attention softmax weights per row (window 16, zero-pad score=0) -------
__global__ __launch_bounds__(64) void ctxw_kernel(
    const unsigned short* __restrict__ q, const unsigned short* __restrict__ k,
    float* __restrict__ wq, float* __restrict__ wk) {
  const unsigned short* src = blockIdx.y ? k : q;
  float* dst = blockIdx.y ? wk : wq;
  int row = blockIdx.x;
  int t = row & 255;
  int lane = threadIdx.x;
  unsigned int xv = *(const unsigned int*)(src + (size_t)row * 128 + lane * 2);
  float x0 = bf2f((unsigned short)(xv & 0xffff));
  float x1 = bf2f((unsigned short)(xv >> 16));
  float sc[16];
#pragma unroll
  for (int l = 0; l < 16; l++) {
    int ts = t - 15 + l;
    float d = 0.f;
    if (ts >= 0) {
      unsigned int wv = *(const unsigned int*)(src + (size_t)(row - 15 + l) * 128 + lane * 2);
      d = x0 * bf2f((unsigned short)(wv & 0xffff)) + x1 * bf2f((unsigned short)(wv >> 16));
    }
    sc[l] = wsum64(d) * 0.08838834764831845f;  // 1/sqrt(128)
  }
  float mx = sc[0];
#pragma unroll
  for (int l = 1; l < 16; l++) mx = fmaxf(mx, sc[l]);
  float den = 0.f;
#pragma unroll
  for (int l = 0; l < 16; l++) { sc[l] = __expf(sc[l] - mx); den += sc[l]; }
  float inv = 1.0f / den;
  float myv = sc[0];
#pragma unroll
  for (int l = 1; l < 16; l++) myv = (lane == l) ? sc[l] : myv;
  if (lane < 16) dst[(size_t)row * 16 + lane] = myv * inv;
}

// ------- attn1: build cq/ck from bf16 q/k + ctx weights; single-pass softmax
//         (no max subtraction: |s| <~ 0.3, shift-invariant) over 256 keys -------
__global__ __launch_bounds__(256) void attn1_kernel(
    const unsigned short* __restrict__ q, const unsigned short* __restrict__ k,
    const unsigned short* __restrict__ v, const float* __restrict__ wq,
    const float* __restrict__ wk, float* __restrict__ xa) {
  __shared__ float4 cks[256][4];
  __shared__ float4 vs[256][4];
  int bm = blockIdx.x >> 3, h = blockIdx.x & 7;
  int tid = threadIdx.x;
  const size_t rbase = (size_t)bm * 256;
  const int cbase = h * 16;
  const float* wqr = wq + (rbase + tid) * 16;
  const float* wkr = wk + (rbase + tid) * 16;
  float4 aq[4], ak[4];
#pragma unroll
  for (int c = 0; c < 4; c++) { aq[c] = make_float4(0,0,0,0); ak[c] = make_float4(0,0,0,0); }
#pragma unroll
  for (int l = 0; l < 16; l++) {
    int ts = tid - 15 + l;
    if (ts >= 0) {
      float wql = wqr[l], wkl = wkr[l];
      const unsigned short* qp = q + (rbase + ts) * 128 + cbase;
      const unsigned short* kp = k + (rbase + ts) * 128 + cbase;
#pragma unroll
      for (int c = 0; c < 4; c++) {
        uint2 qv = *(const uint2*)(qp + c * 4);
        float q0 = bf2f((unsigned short)(qv.x & 0xffff)), q1 = bf2f((unsigned short)(qv.x >> 16));
        float q2 = bf2f((unsigned short)(qv.y & 0xffff)), q3 = bf2f((unsigned short)(qv.y >> 16));
        aq[c].x = fmaf(wql, q0, aq[c].x); aq[c].y = fmaf(wql, q1, aq[c].y);
        aq[c].z = fmaf(wql, q2, aq[c].z); aq[c].w = fmaf(wql, q3, aq[c].w);
        uint2 kv = *(const uint2*)(kp + c * 4);
        float k0 = bf2f((unsigned short)(kv.x & 0xffff)), k1 = bf2f((unsigned short)(kv.x >> 16));
        float k2 = bf2f((unsigned short)(kv.y & 0xffff)), k3 = bf2f((unsigned short)(kv.y >> 16));
        ak[c].x = fmaf(wkl, k0, ak[c].x); ak[c].y = fmaf(wkl, k1, ak[c].y);
        ak[c].z = fmaf(wkl, k2, ak[c].z); ak[c].w = fmaf(wkl, k3, ak[c].w);
      }
    }
  }
#pragma unroll
  for (int c = 0; c < 4; c++) {
    cks[tid][c] = ak[c];
    uint2 vv = *(const uint2*)(v + (rbase + tid) * 128 + cbase + c * 4);
    vs[tid][c] = make_float4(bf2f((unsigned short)(vv.x & 0xffff)), bf2f((unsigned short)(vv.x >> 16)),
                             bf2f((unsigned short)(vv.y & 0xffff)), bf2f((unsigned short)(vv.y >> 16)));
  }
  __syncthreads();
  float lsum = 0.f;
  float4 a0 = {0,0,0,0}, a1 = {0,0,0,0}, a2 = {0,0,0,0}, a3 = {0,0,0,0};
  for (int kk = 0; kk < 256; kk++) {
    float4 c0 = cks[kk][0], c1 = cks[kk][1], c2 = cks[kk][2], c3 = cks[kk][3];
    float s = aq[0].x*c0.x + aq[0].y*c0.y + aq[0].z*c0.z + aq[0].w*c0.w +
              aq[1].x*c1.x + aq[1].y*c1.y + aq[1].z*c1.z + aq[1].w*c1.w +
              aq[2].x*c2.x + aq[2].y*c2.y + aq[2].z*c2.z + aq[2].w*c2.w +
              aq[3].x*c3.x + aq[3].y*c3.y + aq[3].z*c3.z + aq[3].w*c3.w;
    float p = __expf(s * 0.25f);
    lsum += p;
    float4 v0 = vs[kk][0], v1 = vs[kk][1], v2 = vs[kk][2], v3 = vs[kk][3];
    a0.x = fmaf(p, v0.x, a0.x); a0.y = fmaf(p, v0.y, a0.y);
    a0.z = fmaf(p, v0.z, a0.z); a0.w = fmaf(p, v0.w, a0.w);
    a1.x = fmaf(p, v1.x, a1.x); a1.y = fmaf(p, v1.y, a1.y);
    a1.z = fmaf(p, v1.z, a1.z); a1.w = fmaf(p, v1.w, a1.w);
    a2.x = fmaf(p, v2.x, a2.x); a2.y = fmaf(p, v2.y, a2.y);
    a2.z = fmaf(p, v2.z, a2.z); a2.w = fmaf(p, v2.w, a2.w);
    a3.x = fmaf(p, v3.x, a3.x); a3.y = fmaf(p, v3.y, a3.y);
    a3.z = fmaf(p, v3.z, a3.z); a3.w = fmaf(p, v3.w, a3.w);
  }
  float inv = 1.0f / lsum;
  float* out = xa + (rbase + tid) * 128 + cbase;
  a0.x*=inv; a0.y*=inv; a0.z*=inv; a0.w*=inv;
  a1.x*=inv; a1.y*=inv; a1.z*=inv; a1.w*=inv;
  a2.x*=inv; a2.y*=inv; a2.z*=inv; a2.w*=inv;
  a3.x*=inv; a3.y*=inv; a3.z*=inv; a3.w*=inv;
  *(float4*)(out + 0)  = a0;
  *(float4*)(out + 4)  = a1;
  *(float4*)(out + 8)  = a2;
  *(float4*)(out + 12) = a3;
}

// ------- attn2 over M=16 axis; writes scrambled layout g=q*4+b -------
__global__ __launch_bounds__(128) void attn2_kernel(
    const float* __restrict__ xa, float* __restrict__ xr) {
  __shared__ float xas[16][128];
  int b = blockIdx.x >> 8, t = blockIdx.x & 255;
  int tid = threadIdx.x;
#pragma unroll
  for (int j = 0; j < 4; j++) {
    int idx = tid + (j << 7);
    int r = idx >> 5, c4 = idx & 31;
    *(float4*)&xas[r][c4 * 4] =
        *(const float4*)(xa + ((size_t)((b * 16 + r) * 256 + t)) * 128 + c4 * 4);
  }
  __syncthreads();
  int h = tid >> 4, q = tid & 15;
  float xq[16];
#pragma unroll
  for (int d = 0; d < 16; d++) xq[d] = xas[q][h * 16 + d];
  float sc[16];
  float mx = -1e30f;
#pragma unroll
  for (int k = 0; k < 16; k++) {
    float s = 0.f;
#pragma unroll
    for (int d = 0; d < 16; d++) s += xq[d] * xas[k][h * 16 + d];
    s *= 0.25f;
    sc[k] = s;
    mx = fmaxf(mx, s);
  }
  float den = 0.f;
#pragma unroll
  for (int k = 0; k < 16; k++) { sc[k] = __expf(sc[k] - mx); den += sc[k]; }
  float inv = 1.0f / den;
  float out[16] = {};
#pragma unroll
  for (int k = 0; k < 16; k++) {
    float w = sc[k];
#pragma unroll
    for (int d = 0; d < 16; d++) out[d] += w * xas[k][h * 16 + d];
  }
  int g = q * 4 + b;
  float* dst = xr + ((size_t)(g * 256 + t)) * 128 + h * 16;
#pragma unroll
  for (int p = 0; p < 4; p++) {
    float4 o;
    o.x = out[p*4+0]*inv; o.y = out[p*4+1]*inv;
    o.z = out[p*4+2]*inv; o.w = out[p*4+3]*inv;
    *(float4*)(dst + p * 4) = o;
  }
}

// ---------------- full LayerNorm (final, in-place safe) ----------------
__global__ __launch_bounds__(256) void ln_kernel(
    const float* __restrict__ X, const float* __restrict__ g,
    const float* __restrict__ b, float* __restrict__ Y) {
  int wid = threadIdx.x >> 6, lane = threadIdx.x & 63;
  int row = (blockIdx.x << 2) + wid;
  float2 xv = *(const float2*)(X + (size_t)row * D_ + lane * 2);
  float s = wsum64(xv.x + xv.y);
  float sq = wsum64(xv.x * xv.x + xv.y * xv.y);
  float mu = s * (1.0f / 128.0f);
  float var = sq * (1.0f / 128.0f) - mu * mu;
  float rstd = rsqrtf(var + 1e-6f);
  float2 gv = *(const float2*)(g + lane * 2);
  float2 bv = *(const float2*)(b + lane * 2);
  float2 o;
  o.x = (xv.x - mu) * rstd * gv.x + bv.x;
  o.y = (xv.y - mu) * rstd * gv.y + bv.y;
  *(float2*)(Y + (size_t)row * D_ + lane * 2) = o;
}

extern "C" void kernel_launch(void* const* d_in, const int* in_sizes, int n_in,
                              void* d_out, int out_size, void* d_ws, size_t ws_size,
                              hipStream_t stream) {
  const float* x    = (const float*)d_in[0];
  const float* Wq   = (const float*)d_in[1];
  const float* bq   = (const float*)d_in[2];
  const float* Wk   = (const float*)d_in[3];
  const float* bk   = (const float*)d_in[4];
  const float* Wv   = (const float*)d_in[5];
  const float* bv   = (const float*)d_in[6];
  const float* Wo   = (const float*)d_in[7];
  const float* bo   = (const float*)d_in[8];
  const float* W1   = (const float*)d_in[9];
  const float* b1   = (const float*)d_in[10];
  const float* W2   = (const float*)d_in[11];
  const float* b2   = (const float*)d_in[12];
  const float* ln1g = (const float*)d_in[13];
  const float* ln1b = (const float*)d_in[14];
  const float* ln2g = (const float*)d_in[15];
  const float* ln2b = (const float*)d_in[16];
  const float* lnfg = (const float*)d_in[17];
  const float* lnfb = (const float*)d_in[18];

  // ws layout (~26.9 MB total):
  char* base = (char*)d_ws;
  float*          XA  = (float*)base;                              // 8 MB fp32 (attn1 out; FFN acc)
  unsigned short* Qb  = (unsigned short*)(base + (8u << 20));      // 4 MB bf16
  unsigned short* Kb  = (unsigned short*)(base + (12u << 20));     // 4 MB bf16
  float*          XR  = (float*)(base + (8u << 20));               // 8 MB fp32, aliases Qb+Kb (dead)
  unsigned short* Vb  = (unsigned short*)(base + (16u << 20));     // 4 MB bf16; reused as Mb
  unsigned short* Mb  = Vb;
  unsigned short* Ab  = (unsigned short*)(base + (20u << 20));     // 4 MB bf16 (LN'd / converted A)
  unsigned short* Wb  = (unsigned short*)(base + (24u << 20));     // 768 KB bf16 weights
  float*          wqw = (float*)(base + (24u << 20) + (768u << 10)); // 1 MB
  float*          wkw = wqw + (size_t)NROW * 16;                   // 1 MB
  float2*         st  = (float2*)(wkw + (size_t)NROW * 16);        // 128 KB
  float*          ACC = XA;
  float*          Y   = (float*)d_out;

  unsigned short* Wqb = Wb;            // 2*16384
  unsigned short* Wkb = Wb + 32768;
  unsigned short* Wvb = Wb + 65536;
  unsigned short* Wob = Wb + 98304;
  unsigned short* W1b = Wb + 131072;   // 2*65536
  unsigned short* W2b = Wb + 262144;

  // convert all weights to bf16 (deterministic each call)
  wconv_kernel<<<192, 256, 0, stream>>>(Wq, Wk, Wv, Wo, W1, W2, Wb);

  for (int i = 0; i < 2; i++) {
    const float* cur = (i == 0) ? x : Y;
    stats_kernel<<<4096, 256, 0, stream>>>(cur, st);
    convln_kernel<<<1024, 256, 0, stream>>>(cur, st, ln1g + i*128, ln1b + i*128, Ab);
    gemm_mfma_kernel<<<512, 64, 0, stream>>>(Ab, Wqb + i*16384, 128, bq + i*128, nullptr, nullptr, Qb, 0);
    gemm_mfma_kernel<<<512, 64, 0, stream>>>(Ab, Wkb + i*16384, 128, bk + i*128, nullptr, nullptr, Kb, 0);
    gemm_mfma_kernel<<<512, 64, 0, stream>>>(Ab, Wvb + i*16384, 128, bv + i*128, nullptr, nullptr, Vb, 0);
    ctxw_kernel<<<dim3(16384, 2), 64, 0, stream>>>(Qb, Kb, wqw, wkw);
    attn1_kernel<<<512, 256, 0, stream>>>(Qb, Kb, Vb, wqw, wkw, XA);
    attn2_kernel<<<1024, 128, 0, stream>>>(XA, XR);
    convln_kernel<<<1024, 256, 0, stream>>>(XR, nullptr, nullptr, nullptr, Ab);
    gemm_mfma_kernel<<<512, 64, 0, stream>>>(Ab, Wob + i*16384, 128, bo + i*128, cur, Y, nullptr, 0);
    stats_kernel<<<4096, 256, 0, stream>>>(Y, st);
    convln_kernel<<<1024, 256, 0, stream>>>(Y, st, ln2g + i*128, ln2b + i*128, Ab);
    for (int c = 0; c < 4; c++) {
      gemm_mfma_kernel<<<512, 64, 0, stream>>>(Ab, W1b + i*65536 + c*16384, 128,
                                               b1 + i*512 + c*128, nullptr, nullptr, Mb, 1);
      const float* rs = (c == 0) ? Y : ACC;
      float* dst = (c == 3) ? Y : ACC;
      gemm_mfma_kernel<<<512, 64, 0, stream>>>(Mb, W2b + i*65536 + c*128, 512,
                                               (c == 0) ? (b2 + i*128) : nullptr, rs, dst, nullptr, 0);
    }
  }
  ln_kernel<<<4096, 256, 0, stream>>>(Y, lnfg, lnfb, Y);
}

// Round 4
// 445.479 us; speedup vs baseline: 2.0569x; 1.8440x over previous
//
#include <hip/hip_runtime.h>
#include <cstddef>
#include <cstdint>

// Shapes: B=4, M=16, T=256, D=128, H=8, CTX=16, L=2
static constexpr int D_ = 128;
static constexpr int NROW = 16384;               // B*M*T rows
static constexpr size_t S_ = (size_t)NROW * D_;  // elems per activation

typedef __attribute__((ext_vector_type(8))) short bf16x8;
typedef __attribute__((ext_vector_type(4))) float f32x4;
typedef __attribute__((ext_vector_type(8))) unsigned short ushortx8;
typedef __attribute__((ext_vector_type(4))) unsigned short ushortx4;

__device__ __forceinline__ unsigned short f2bf(float f) {
  unsigned int u = __float_as_uint(f);
  u += 0x7fff + ((u >> 16) & 1);
  return (unsigned short)(u >> 16);
}
__device__ __forceinline__ float bf2f(unsigned short h) {
  return __uint_as_float(((unsigned int)h) << 16);
}
__device__ __forceinline__ float wsum64(float s) {
#pragma unroll
  for (int off = 32; off >= 1; off >>= 1) s += __shfl_xor(s, off);
  return s;
}

// ---- fused LN stats + normalize + bf16 convert (one pass) ----
__global__ __launch_bounds__(256) void lnconv_kernel(
    const float* __restrict__ X, const float* __restrict__ g,
    const float* __restrict__ b, unsigned short* __restrict__ out) {
  int wid = threadIdx.x >> 6, lane = threadIdx.x & 63;
  int row = (blockIdx.x << 2) + wid;
  float2 xv = *(const float2*)(X + (size_t)row * D_ + lane * 2);
  float s = wsum64(xv.x + xv.y);
  float sq = wsum64(xv.x * xv.x + xv.y * xv.y);
  float mu = s * (1.0f / 128.0f);
  float var = sq * (1.0f / 128.0f) - mu * mu;
  float rstd = rsqrtf(var + 1e-6f);
  float2 gv = *(const float2*)(g + lane * 2);
  float2 bv = *(const float2*)(b + lane * 2);
  unsigned int lo = f2bf((xv.x - mu) * rstd * gv.x + bv.x);
  unsigned int hi = f2bf((xv.y - mu) * rstd * gv.y + bv.y);
  *(unsigned int*)(out + (size_t)row * D_ + lane * 2) = lo | (hi << 16);
}

// ---- plain fp32 -> bf16 convert ----
__global__ __launch_bounds__(256) void conv_kernel(const float* __restrict__ X,
                                                   unsigned short* __restrict__ out) {
  size_t idx = ((size_t)blockIdx.x * 256 + threadIdx.x) * 8;
  float4 v0 = *(const float4*)(X + idx);
  float4 v1 = *(const float4*)(X + idx + 4);
  float o[8] = {v0.x, v0.y, v0.z, v0.w, v1.x, v1.y, v1.z, v1.w};
  ushortx8 r;
#pragma unroll
  for (int j = 0; j < 8; j++) r[j] = f2bf(o[j]);
  *(ushortx8*)(out + idx) = r;
}

// ---- weights fp32->bf16, packed per layer: [QKV(384x128)][Wo][W1][W2] ----
__global__ __launch_bounds__(256) void wconv_kernel(
    const float* __restrict__ Wq, const float* __restrict__ Wk,
    const float* __restrict__ Wv, const float* __restrict__ Wo,
    const float* __restrict__ W1, const float* __restrict__ W2,
    unsigned short* __restrict__ out) {
  size_t i = ((size_t)blockIdx.x * 256 + threadIdx.x) * 8;
  int layer = i >= 196608;
  size_t o = i - (size_t)layer * 196608;
  const float* src; size_t off;
  if      (o < 16384)  { src = Wq + layer * 16384; off = o; }
  else if (o < 32768)  { src = Wk + layer * 16384; off = o - 16384; }
  else if (o < 49152)  { src = Wv + layer * 16384; off = o - 32768; }
  else if (o < 65536)  { src = Wo + layer * 16384; off = o - 49152; }
  else if (o < 131072) { src = W1 + layer * 65536; off = o - 65536; }
  else                 { src = W2 + layer * 65536; off = o - 131072; }
  ushortx8 r;
#pragma unroll
  for (int j = 0; j < 8; j++) r[j] = f2bf(src[off + j]);
  *(ushortx8*)(out + i) = r;
}

// ---- pack biases fp32 per layer: [bq bk bv bo b1(512) b2] = 1152 floats ----
__global__ __launch_bounds__(256) void bconv_kernel(
    const float* __restrict__ bq, const float* __restrict__ bk,
    const float* __restrict__ bv, const float* __restrict__ bo,
    const float* __restrict__ b1, const float* __restrict__ b2,
    float* __restrict__ out) {
  int tid = threadIdx.x + blockIdx.x * 256;
  if (tid >= 2304) return;
  int layer = tid / 1152, o = tid % 1152;
  float v;
  if      (o < 128)  v = bq[layer * 128 + o];
  else if (o < 256)  v = bk[layer * 128 + o - 128];
  else if (o < 384)  v = bv[layer * 128 + o - 256];
  else if (o < 512)  v = bo[layer * 128 + o - 384];
  else if (o < 1024) v = b1[layer * 512 + o - 512];
  else               v = b2[layer * 128 + o - 1024];
  out[tid] = v;
}

// ---- bf16 MFMA GEMM, 4-wave blocks, 16-row wave tiles, y-batched ----
// dst elem offset = row*ldc + y*dstOff + col ; W slice = Wbase + y*128*ldw
__global__ __launch_bounds__(256) void gemm_kernel(
    const unsigned short* __restrict__ A, int lda,
    const unsigned short* __restrict__ Wbase, int ldw,
    const float* __restrict__ biasB, int biasStride,
    const float* __restrict__ resid,
    float* __restrict__ Cf, unsigned short* __restrict__ Cb,
    int ldc, int dstOff, int K, int relu) {
  const int y = blockIdx.y;
  const unsigned short* W = Wbase + (size_t)y * 128 * ldw;
  const float* bias = biasB + (size_t)y * biasStride;
  const int m0 = blockIdx.x * 64 + (threadIdx.x >> 6) * 16;
  const int l = threadIdx.x & 63;
  const int lr = l & 15, lk = (l >> 4) * 8;
  f32x4 acc[8] = {};
  const unsigned short* Ap = A + (size_t)(m0 + lr) * lda + lk;
  const unsigned short* Wp = W + (size_t)lr * ldw + lk;
#pragma unroll 4
  for (int k0 = 0; k0 < K; k0 += 32) {
    bf16x8 a = *(const bf16x8*)(Ap + k0);
#pragma unroll
    for (int n = 0; n < 8; ++n) {
      bf16x8 bfr = *(const bf16x8*)(Wp + (size_t)(n * 16) * ldw + k0);
      acc[n] = __builtin_amdgcn_mfma_f32_16x16x32_bf16(a, bfr, acc[n], 0, 0, 0);
    }
  }
  const int rb = (l >> 4) * 4;
#pragma unroll
  for (int n = 0; n < 8; ++n) {
    int col = n * 16 + lr;
    float bval = bias[col];
#pragma unroll
    for (int j = 0; j < 4; ++j) {
      int row = m0 + rb + j;
      float v = acc[n][j] + bval;
      if (relu) v = fmaxf(v, 0.f);
      if (resid) v += resid[(size_t)row * 128 + col];
      size_t off = (size_t)row * ldc + (size_t)y * dstOff + col;
      if (Cf) Cf[off] = v;
      else Cb[off] = f2bf(v);
    }
  }
}

// ---- context attention (scores+softmax+combine) per bm, in-place on q/k ----
__global__ __launch_bounds__(256) void ctx_combine_kernel(
    unsigned short* __restrict__ q, unsigned short* __restrict__ k) {
  __shared__ unsigned short xs[256][132];  // 264B rows: b64-aligned, 2-way banks
  unsigned short* buf = blockIdx.y ? k : q;
  const size_t rbase = (size_t)blockIdx.x * 256;
  const int t = threadIdx.x;
#pragma unroll
  for (int it = 0; it < 32; ++it) {
    int idx = it * 256 + t;
    int r = idx >> 5, c = (idx & 31) * 4;
    *(ushortx4*)&xs[r][c] = *(const ushortx4*)(buf + (rbase + r) * 128 + c);
  }
  __syncthreads();
  float sc[16];
#pragma unroll
  for (int l = 0; l < 16; ++l) sc[l] = 0.f;
  for (int ch = 0; ch < 8; ++ch) {
    float own[16];
#pragma unroll
    for (int j = 0; j < 4; ++j) {
      ushortx4 o = *(const ushortx4*)&xs[t][ch * 16 + j * 4];
      own[j*4+0] = bf2f(o[0]); own[j*4+1] = bf2f(o[1]);
      own[j*4+2] = bf2f(o[2]); own[j*4+3] = bf2f(o[3]);
    }
#pragma unroll
    for (int l = 0; l < 16; ++l) {
      int ts = t - 15 + l;
      if (ts >= 0) {
        float d = 0.f;
#pragma unroll
        for (int j = 0; j < 4; ++j) {
          ushortx4 w = *(const ushortx4*)&xs[ts][ch * 16 + j * 4];
          d += own[j*4+0] * bf2f(w[0]) + own[j*4+1] * bf2f(w[1]) +
               own[j*4+2] * bf2f(w[2]) + own[j*4+3] * bf2f(w[3]);
        }
        sc[l] += d;
      }
    }
  }
#pragma unroll
  for (int l = 0; l < 16; ++l) sc[l] *= 0.08838834764831845f;  // 1/sqrt(128); pad l stays 0
  float mx = sc[0];
#pragma unroll
  for (int l = 1; l < 16; ++l) mx = fmaxf(mx, sc[l]);
  float den = 0.f;
#pragma unroll
  for (int l = 0; l < 16; ++l) { sc[l] = __expf(sc[l] - mx); den += sc[l]; }
  float inv = 1.0f / den;
#pragma unroll
  for (int l = 0; l < 16; ++l) sc[l] *= inv;
  for (int ch = 0; ch < 8; ++ch) {
    float acc[16] = {};
#pragma unroll
    for (int l = 0; l < 16; ++l) {
      int ts = t - 15 + l;
      if (ts >= 0) {
        float wl = sc[l];
#pragma unroll
        for (int j = 0; j < 4; ++j) {
          ushortx4 w = *(const ushortx4*)&xs[ts][ch * 16 + j * 4];
          acc[j*4+0] = fmaf(wl, bf2f(w[0]), acc[j*4+0]);
          acc[j*4+1] = fmaf(wl, bf2f(w[1]), acc[j*4+1]);
          acc[j*4+2] = fmaf(wl, bf2f(w[2]), acc[j*4+2]);
          acc[j*4+3] = fmaf(wl, bf2f(w[3]), acc[j*4+3]);
        }
      }
    }
    ushortx8 o0, o1;
#pragma unroll
    for (int j = 0; j < 8; ++j) { o0[j] = f2bf(acc[j]); o1[j] = f2bf(acc[8 + j]); }
    *(ushortx8*)(buf + (rbase + t) * 128 + ch * 16) = o0;
    *(ushortx8*)(buf + (rbase + t) * 128 + ch * 16 + 8) = o1;
  }
}

// ---- attn1: block=(bm, head-pair); ck/v slices in LDS fp32; broadcast kk reads ----
__global__ __launch_bounds__(256) void attn1_kernel(
    const unsigned short* __restrict__ cq, const unsigned short* __restrict__ ck,
    const unsigned short* __restrict__ v, float* __restrict__ xa) {
  __shared__ float ks[256][36];
  __shared__ float vs[256][36];
  const int bm = blockIdx.x >> 2, hp = blockIdx.x & 3;
  const size_t rbase = (size_t)bm * 256;
  const int cbase = hp * 32;
  const int t = threadIdx.x;
#pragma unroll
  for (int it = 0; it < 4; ++it) {
    int idx = it * 256 + t;
    int r = idx >> 2, c = (idx & 3) * 8;
    ushortx8 kv = *(const ushortx8*)(ck + (rbase + r) * 128 + cbase + c);
    ushortx8 vv = *(const ushortx8*)(v + (rbase + r) * 128 + cbase + c);
    *(float4*)&ks[r][c]     = make_float4(bf2f(kv[0]), bf2f(kv[1]), bf2f(kv[2]), bf2f(kv[3]));
    *(float4*)&ks[r][c + 4] = make_float4(bf2f(kv[4]), bf2f(kv[5]), bf2f(kv[6]), bf2f(kv[7]));
    *(float4*)&vs[r][c]     = make_float4(bf2f(vv[0]), bf2f(vv[1]), bf2f(vv[2]), bf2f(vv[3]));
    *(float4*)&vs[r][c + 4] = make_float4(bf2f(vv[4]), bf2f(vv[5]), bf2f(vv[6]), bf2f(vv[7]));
  }
  float qr[32];
#pragma unroll
  for (int c8 = 0; c8 < 4; ++c8) {
    ushortx8 qv = *(const ushortx8*)(cq + (rbase + t) * 128 + cbase + c8 * 8);
#pragma unroll
    for (int j = 0; j < 8; ++j) qr[c8 * 8 + j] = bf2f(qv[j]);
  }
  __syncthreads();
  float lsum0 = 0.f, lsum1 = 0.f;
  float out[32] = {};
#pragma unroll 2
  for (int kk = 0; kk < 256; ++kk) {
    const float* kr = &ks[kk][0];
    float d0 = 0.f, d1 = 0.f, d2 = 0.f, d3 = 0.f;
    float e0 = 0.f, e1 = 0.f, e2 = 0.f, e3 = 0.f;
#pragma unroll
    for (int j = 0; j < 4; ++j) {
      d0 = fmaf(qr[j],      kr[j],      d0);
      d1 = fmaf(qr[4 + j],  kr[4 + j],  d1);
      d2 = fmaf(qr[8 + j],  kr[8 + j],  d2);
      d3 = fmaf(qr[12 + j], kr[12 + j], d3);
      e0 = fmaf(qr[16 + j], kr[16 + j], e0);
      e1 = fmaf(qr[20 + j], kr[20 + j], e1);
      e2 = fmaf(qr[24 + j], kr[24 + j], e2);
      e3 = fmaf(qr[28 + j], kr[28 + j], e3);
    }
    float s0 = (d0 + d1) + (d2 + d3);
    float s1 = (e0 + e1) + (e2 + e3);
    float p0 = __expf(s0 * 0.25f);
    float p1 = __expf(s1 * 0.25f);
    lsum0 += p0; lsum1 += p1;
    const float* vr = &vs[kk][0];
#pragma unroll
    for (int j = 0; j < 16; ++j) {
      out[j]      = fmaf(p0, vr[j],      out[j]);
      out[16 + j] = fmaf(p1, vr[16 + j], out[16 + j]);
    }
  }
  float i0 = 1.0f / lsum0, i1 = 1.0f / lsum1;
  float* dst = xa + (rbase + t) * 128 + cbase;
#pragma unroll
  for (int c4 = 0; c4 < 8; ++c4) {
    float sc = (c4 < 4) ? i0 : i1;
    float4 o;
    o.x = out[c4*4+0] * sc; o.y = out[c4*4+1] * sc;
    o.z = out[c4*4+2] * sc; o.w = out[c4*4+3] * sc;
    *(float4*)(dst + c4 * 4) = o;
  }
}

// ---- attn2 over M=16 axis; scrambled write g=q*4+b ----
__global__ __launch_bounds__(128) void attn2_kernel(
    const float* __restrict__ xa, float* __restrict__ xr) {
  __shared__ float xas[16][128];
  int b = blockIdx.x >> 8, t = blockIdx.x & 255;
  int tid = threadIdx.x;
#pragma unroll
  for (int j = 0; j < 4; j++) {
    int idx = tid + (j << 7);
    int r = idx >> 5, c4 = idx & 31;
    *(float4*)&xas[r][c4 * 4] =
        *(const float4*)(xa + ((size_t)((b * 16 + r) * 256 + t)) * 128 + c4 * 4);
  }
  __syncthreads();
  int h = tid >> 4, q = tid & 15;
  float xq[16];
#pragma unroll
  for (int d = 0; d < 16; d++) xq[d] = xas[q][h * 16 + d];
  float sc[16];
  float mx = -1e30f;
#pragma unroll
  for (int k = 0; k < 16; k++) {
    float s = 0.f;
#pragma unroll
    for (int d = 0; d < 16; d++) s += xq[d] * xas[k][h * 16 + d];
    s *= 0.25f;
    sc[k] = s;
    mx = fmaxf(mx, s);
  }
  float den = 0.f;
#pragma unroll
  for (int k = 0; k < 16; k++) { sc[k] = __expf(sc[k] - mx); den += sc[k]; }
  float inv = 1.0f / den;
  float out[16] = {};
#pragma unroll
  for (int k = 0; k < 16; k++) {
    float w = sc[k];
#pragma unroll
    for (int d = 0; d < 16; d++) out[d] += w * xas[k][h * 16 + d];
  }
  int g = q * 4 + b;
  float* dst = xr + ((size_t)(g * 256 + t)) * 128 + h * 16;
#pragma unroll
  for (int p = 0; p < 4; p++) {
    float4 o;
    o.x = out[p*4+0]*inv; o.y = out[p*4+1]*inv;
    o.z = out[p*4+2]*inv; o.w = out[p*4+3]*inv;
    *(float4*)(dst + p * 4) = o;
  }
}

// ---- final LayerNorm (in-place safe) ----
__global__ __launch_bounds__(256) void ln_kernel(
    const float* __restrict__ X, const float* __restrict__ g,
    const float* __restrict__ b, float* __restrict__ Y) {
  int wid = threadIdx.x >> 6, lane = threadIdx.x & 63;
  int row = (blockIdx.x << 2) + wid;
  float2 xv = *(const float2*)(X + (size_t)row * D_ + lane * 2);
  float s = wsum64(xv.x + xv.y);
  float sq = wsum64(xv.x * xv.x + xv.y * xv.y);
  float mu = s * (1.0f / 128.0f);
  float var = sq * (1.0f / 128.0f) - mu * mu;
  float rstd = rsqrtf(var + 1e-6f);
  float2 gv = *(const float2*)(g + lane * 2);
  float2 bv = *(const float2*)(b + lane * 2);
  float2 o;
  o.x = (xv.x - mu) * rstd * gv.x + bv.x;
  o.y = (xv.y - mu) * rstd * gv.y + bv.y;
  *(float2*)(Y + (size_t)row * D_ + lane * 2) = o;
}

extern "C" void kernel_launch(void* const* d_in, const int* in_sizes, int n_in,
                              void* d_out, int out_size, void* d_ws, size_t ws_size,
                              hipStream_t stream) {
  const float* x    = (const float*)d_in[0];
  const float* Wq   = (const float*)d_in[1];
  const float* bq   = (const float*)d_in[2];
  const float* Wk   = (const float*)d_in[3];
  const float* bk   = (const float*)d_in[4];
  const float* Wv   = (const float*)d_in[5];
  const float* bv   = (const float*)d_in[6];
  const float* Wo   = (const float*)d_in[7];
  const float* bo   = (const float*)d_in[8];
  const float* W1   = (const float*)d_in[9];
  const float* b1   = (const float*)d_in[10];
  const float* W2   = (const float*)d_in[11];
  const float* b2   = (const float*)d_in[12];
  const float* ln1g = (const float*)d_in[13];
  const float* ln1b = (const float*)d_in[14];
  const float* ln2g = (const float*)d_in[15];
  const float* ln2b = (const float*)d_in[16];
  const float* lnfg = (const float*)d_in[17];
  const float* lnfb = (const float*)d_in[18];

  // ws layout (24.76 MB):
  char* base = (char*)d_ws;
  float*          XA  = (float*)base;                          // [0,8M) fp32
  unsigned short* Qb  = (unsigned short*)(base + (8u  << 20)); // [8,12) bf16
  unsigned short* Kb  = (unsigned short*)(base + (12u << 20)); // [12,16) bf16
  unsigned short* Vb  = (unsigned short*)(base + (16u << 20)); // [16,20) bf16
  unsigned short* Ab  = (unsigned short*)(base + (20u << 20)); // [20,24) bf16
  float*          XR  = (float*)(base + (8u << 20));           // [8,16) fp32 (Qb/Kb dead)
  unsigned short* Mid = (unsigned short*)base;                 // [0,16) bf16 (XA/Qb/Kb dead)
  unsigned short* Wb  = (unsigned short*)(base + (24u << 20)); // 768 KB
  float*          Bs  = (float*)(base + (24u << 20) + 786432); // 9.2 KB
  float*          Y   = (float*)d_out;

  wconv_kernel<<<192, 256, 0, stream>>>(Wq, Wk, Wv, Wo, W1, W2, Wb);
  bconv_kernel<<<9, 256, 0, stream>>>(bq, bk, bv, bo, b1, b2, Bs);

  for (int i = 0; i < 2; ++i) {
    const float* cur = i ? Y : x;
    const unsigned short* Wl = Wb + (size_t)i * 196608;
    const float* Bl = Bs + i * 1152;
    // LN1 -> Ab
    lnconv_kernel<<<4096, 256, 0, stream>>>(cur, ln1g + i*128, ln1b + i*128, Ab);
    // QKV (one dispatch, y = which output)
    gemm_kernel<<<dim3(256, 3), 256, 0, stream>>>(Ab, 128, Wl, 128, Bl, 128,
                                                  nullptr, nullptr, Qb, 128, (int)S_, 128, 0);
    // context combine in-place on Qb, Kb
    ctx_combine_kernel<<<dim3(64, 2), 256, 0, stream>>>(Qb, Kb);
    // T x T attention
    attn1_kernel<<<256, 256, 0, stream>>>(Qb, Kb, Vb, XA);
    // M attention with scramble
    attn2_kernel<<<1024, 128, 0, stream>>>(XA, XR);
    conv_kernel<<<1024, 256, 0, stream>>>(XR, Ab);
    // Wo + residual -> Y
    gemm_kernel<<<dim3(256, 1), 256, 0, stream>>>(Ab, 128, Wl + 49152, 128, Bl + 384, 128,
                                                  cur, Y, nullptr, 128, 0, 128, 0);
    // LN2 -> Ab
    lnconv_kernel<<<4096, 256, 0, stream>>>(Y, ln2g + i*128, ln2b + i*128, Ab);
    // FFN: W1 (4 chunks in one dispatch) -> Mid[16384,512] bf16
    gemm_kernel<<<dim3(256, 4), 256, 0, stream>>>(Ab, 128, Wl + 65536, 128, Bl + 512, 128,
                                                  nullptr, nullptr, Mid, 512, 128, 128, 1);
    // W2 (K=512) + residual -> Y
    gemm_kernel<<<dim3(256, 1), 256, 0, stream>>>(Mid, 512, Wl + 131072, 512, Bl + 1024, 128,
                                                  Y, Y, nullptr, 128, 0, 512, 0);
  }
  ln_kernel<<<4096, 256, 0, stream>>>(Y, lnfg, lnfb, Y);
}

// Round 5
// 363.561 us; speedup vs baseline: 2.5203x; 1.2253x over previous
//
#include <hip/hip_runtime.h>
#include <cstddef>
#include <cstdint>

// Shapes: B=4, M=16, T=256, D=128, H=8, CTX=16, L=2
static constexpr int D_ = 128;
static constexpr int NROW = 16384;               // B*M*T rows
static constexpr size_t S_ = (size_t)NROW * D_;  // elems per activation

typedef __attribute__((ext_vector_type(8))) short bf16x8;
typedef __attribute__((ext_vector_type(4))) float f32x4;
typedef __attribute__((ext_vector_type(16))) float f32x16;
typedef __attribute__((ext_vector_type(8))) unsigned short ushortx8;
typedef __attribute__((ext_vector_type(4))) unsigned short ushortx4;

__device__ __forceinline__ unsigned short f2bf(float f) {
  unsigned int u = __float_as_uint(f);
  u += 0x7fff + ((u >> 16) & 1);
  return (unsigned short)(u >> 16);
}
__device__ __forceinline__ float bf2f(unsigned short h) {
  return __uint_as_float(((unsigned int)h) << 16);
}
__device__ __forceinline__ unsigned int cvt_pk_bf16(float lo, float hi) {
  unsigned int r;
  asm volatile("v_cvt_pk_bf16_f32 %0, %1, %2" : "=v"(r) : "v"(lo), "v"(hi));
  return r;  // low 16 = bf16(lo), high 16 = bf16(hi)
}
__device__ __forceinline__ float wsum64(float s) {
#pragma unroll
  for (int off = 32; off >= 1; off >>= 1) s += __shfl_xor(s, off);
  return s;
}

// ---- fused LN stats + normalize + bf16 convert (one pass) ----
__global__ __launch_bounds__(256) void lnconv_kernel(
    const float* __restrict__ X, const float* __restrict__ g,
    const float* __restrict__ b, unsigned short* __restrict__ out) {
  int wid = threadIdx.x >> 6, lane = threadIdx.x & 63;
  int row = (blockIdx.x << 2) + wid;
  float2 xv = *(const float2*)(X + (size_t)row * D_ + lane * 2);
  float s = wsum64(xv.x + xv.y);
  float sq = wsum64(xv.x * xv.x + xv.y * xv.y);
  float mu = s * (1.0f / 128.0f);
  float var = sq * (1.0f / 128.0f) - mu * mu;
  float rstd = rsqrtf(var + 1e-6f);
  float2 gv = *(const float2*)(g + lane * 2);
  float2 bv = *(const float2*)(b + lane * 2);
  unsigned int lo = f2bf((xv.x - mu) * rstd * gv.x + bv.x);
  unsigned int hi = f2bf((xv.y - mu) * rstd * gv.y + bv.y);
  *(unsigned int*)(out + (size_t)row * D_ + lane * 2) = lo | (hi << 16);
}

// ---- plain fp32 -> bf16 convert ----
__global__ __launch_bounds__(256) void conv_kernel(const float* __restrict__ X,
                                                   unsigned short* __restrict__ out) {
  size_t idx = ((size_t)blockIdx.x * 256 + threadIdx.x) * 8;
  float4 v0 = *(const float4*)(X + idx);
  float4 v1 = *(const float4*)(X + idx + 4);
  float o[8] = {v0.x, v0.y, v0.z, v0.w, v1.x, v1.y, v1.z, v1.w};
  ushortx8 r;
#pragma unroll
  for (int j = 0; j < 8; j++) r[j] = f2bf(o[j]);
  *(ushortx8*)(out + idx) = r;
}

// ---- weights fp32->bf16, packed per layer: [QKV(384x128)][Wo][W1][W2] ----
__global__ __launch_bounds__(256) void wconv_kernel(
    const float* __restrict__ Wq, const float* __restrict__ Wk,
    const float* __restrict__ Wv, const float* __restrict__ Wo,
    const float* __restrict__ W1, const float* __restrict__ W2,
    unsigned short* __restrict__ out) {
  size_t i = ((size_t)blockIdx.x * 256 + threadIdx.x) * 8;
  int layer = i >= 196608;
  size_t o = i - (size_t)layer * 196608;
  const float* src; size_t off;
  if      (o < 16384)  { src = Wq + layer * 16384; off = o; }
  else if (o < 32768)  { src = Wk + layer * 16384; off = o - 16384; }
  else if (o < 49152)  { src = Wv + layer * 16384; off = o - 32768; }
  else if (o < 65536)  { src = Wo + layer * 16384; off = o - 49152; }
  else if (o < 131072) { src = W1 + layer * 65536; off = o - 65536; }
  else                 { src = W2 + layer * 65536; off = o - 131072; }
  ushortx8 r;
#pragma unroll
  for (int j = 0; j < 8; j++) r[j] = f2bf(src[off + j]);
  *(ushortx8*)(out + i) = r;
}

// ---- pack biases fp32 per layer: [bq bk bv bo b1(512) b2] = 1152 floats ----
__global__ __launch_bounds__(256) void bconv_kernel(
    const float* __restrict__ bq, const float* __restrict__ bk,
    const float* __restrict__ bv, const float* __restrict__ bo,
    const float* __restrict__ b1, const float* __restrict__ b2,
    float* __restrict__ out) {
  int tid = threadIdx.x + blockIdx.x * 256;
  if (tid >= 2304) return;
  int layer = tid / 1152, o = tid % 1152;
  float v;
  if      (o < 128)  v = bq[layer * 128 + o];
  else if (o < 256)  v = bk[layer * 128 + o - 128];
  else if (o < 384)  v = bv[layer * 128 + o - 256];
  else if (o < 512)  v = bo[layer * 128 + o - 384];
  else if (o < 1024) v = b1[layer * 512 + o - 512];
  else               v = b2[layer * 128 + o - 1024];
  out[tid] = v;
}

// ---- bf16 MFMA GEMM, 4-wave blocks, 16-row wave tiles, y-batched ----
__global__ __launch_bounds__(256) void gemm_kernel(
    const unsigned short* __restrict__ A, int lda,
    const unsigned short* __restrict__ Wbase, int ldw,
    const float* __restrict__ biasB, int biasStride,
    const float* __restrict__ resid,
    float* __restrict__ Cf, unsigned short* __restrict__ Cb,
    int ldc, int dstOff, int K, int relu) {
  const int y = blockIdx.y;
  const unsigned short* W = Wbase + (size_t)y * 128 * ldw;
  const float* bias = biasB + (size_t)y * biasStride;
  const int m0 = blockIdx.x * 64 + (threadIdx.x >> 6) * 16;
  const int l = threadIdx.x & 63;
  const int lr = l & 15, lk = (l >> 4) * 8;
  f32x4 acc[8] = {};
  const unsigned short* Ap = A + (size_t)(m0 + lr) * lda + lk;
  const unsigned short* Wp = W + (size_t)lr * ldw + lk;
#pragma unroll 4
  for (int k0 = 0; k0 < K; k0 += 32) {
    bf16x8 a = *(const bf16x8*)(Ap + k0);
#pragma unroll
    for (int n = 0; n < 8; ++n) {
      bf16x8 bfr = *(const bf16x8*)(Wp + (size_t)(n * 16) * ldw + k0);
      acc[n] = __builtin_amdgcn_mfma_f32_16x16x32_bf16(a, bfr, acc[n], 0, 0, 0);
    }
  }
  const int rb = (l >> 4) * 4;
#pragma unroll
  for (int n = 0; n < 8; ++n) {
    int col = n * 16 + lr;
    float bval = bias[col];
#pragma unroll
    for (int j = 0; j < 4; ++j) {
      int row = m0 + rb + j;
      float v = acc[n][j] + bval;
      if (relu) v = fmaxf(v, 0.f);
      if (resid) v += resid[(size_t)row * 128 + col];
      size_t off = (size_t)row * ldc + (size_t)y * dstOff + col;
      if (Cf) Cf[off] = v;
      else Cb[off] = f2bf(v);
    }
  }
}

// ---- context attention (scores+softmax+combine) per bm, in-place on q/k ----
__global__ __launch_bounds__(256) void ctx_combine_kernel(
    unsigned short* __restrict__ q, unsigned short* __restrict__ k) {
  __shared__ unsigned short xs[256][132];
  unsigned short* buf = blockIdx.y ? k : q;
  const size_t rbase = (size_t)blockIdx.x * 256;
  const int t = threadIdx.x;
#pragma unroll
  for (int it = 0; it < 32; ++it) {
    int idx = it * 256 + t;
    int r = idx >> 5, c = (idx & 31) * 4;
    *(ushortx4*)&xs[r][c] = *(const ushortx4*)(buf + (rbase + r) * 128 + c);
  }
  __syncthreads();
  float sc[16];
#pragma unroll
  for (int l = 0; l < 16; ++l) sc[l] = 0.f;
  for (int ch = 0; ch < 8; ++ch) {
    float own[16];
#pragma unroll
    for (int j = 0; j < 4; ++j) {
      ushortx4 o = *(const ushortx4*)&xs[t][ch * 16 + j * 4];
      own[j*4+0] = bf2f(o[0]); own[j*4+1] = bf2f(o[1]);
      own[j*4+2] = bf2f(o[2]); own[j*4+3] = bf2f(o[3]);
    }
#pragma unroll
    for (int l = 0; l < 16; ++l) {
      int ts = t - 15 + l;
      if (ts >= 0) {
        float d = 0.f;
#pragma unroll
        for (int j = 0; j < 4; ++j) {
          ushortx4 w = *(const ushortx4*)&xs[ts][ch * 16 + j * 4];
          d += own[j*4+0] * bf2f(w[0]) + own[j*4+1] * bf2f(w[1]) +
               own[j*4+2] * bf2f(w[2]) + own[j*4+3] * bf2f(w[3]);
        }
        sc[l] += d;
      }
    }
  }
#pragma unroll
  for (int l = 0; l < 16; ++l) sc[l] *= 0.08838834764831845f;
  float mx = sc[0];
#pragma unroll
  for (int l = 1; l < 16; ++l) mx = fmaxf(mx, sc[l]);
  float den = 0.f;
#pragma unroll
  for (int l = 0; l < 16; ++l) { sc[l] = __expf(sc[l] - mx); den += sc[l]; }
  float inv = 1.0f / den;
#pragma unroll
  for (int l = 0; l < 16; ++l) sc[l] *= inv;
  for (int ch = 0; ch < 8; ++ch) {
    float acc[16] = {};
#pragma unroll
    for (int l = 0; l < 16; ++l) {
      int ts = t - 15 + l;
      if (ts >= 0) {
        float wl = sc[l];
#pragma unroll
        for (int j = 0; j < 4; ++j) {
          ushortx4 w = *(const ushortx4*)&xs[ts][ch * 16 + j * 4];
          acc[j*4+0] = fmaf(wl, bf2f(w[0]), acc[j*4+0]);
          acc[j*4+1] = fmaf(wl, bf2f(w[1]), acc[j*4+1]);
          acc[j*4+2] = fmaf(wl, bf2f(w[2]), acc[j*4+2]);
          acc[j*4+3] = fmaf(wl, bf2f(w[3]), acc[j*4+3]);
        }
      }
    }
    ushortx8 o0, o1;
#pragma unroll
    for (int j = 0; j < 8; ++j) { o0[j] = f2bf(acc[j]); o1[j] = f2bf(acc[8 + j]); }
    *(ushortx8*)(buf + (rbase + t) * 128 + ch * 16) = o0;
    *(ushortx8*)(buf + (rbase + t) * 128 + ch * 16 + 8) = o1;
  }
}

// ---- attn1 (MFMA): per (bm,h): S^T = CK·CQ^T via 32x32x16; P through LDS;
//      O = P·V via 16x16x32 with V^T staged in LDS. No max-subtraction. ----
static constexpr int PW = 272;  // LDS row stride (elems): mult of 8 for b128 alignment
__global__ __launch_bounds__(256) void attn1_kernel(
    const unsigned short* __restrict__ cq, const unsigned short* __restrict__ ck,
    const unsigned short* __restrict__ v, float* __restrict__ xa) {
  __shared__ unsigned short vt[16][PW];       // V^T head slice
  __shared__ unsigned short ps[4][32][PW];    // per-wave P strip (32 q rows)
  __shared__ float rsum[4][32];
  const int bm = blockIdx.x >> 3, h = blockIdx.x & 7;
  const size_t rbase = (size_t)bm * 256;
  const int cbase = h * 16;
  const int tid = threadIdx.x;
  {  // stage V^T (thread = key row)
    ushortx8 v0 = *(const ushortx8*)(v + (rbase + tid) * 128 + cbase);
    ushortx8 v1 = *(const ushortx8*)(v + (rbase + tid) * 128 + cbase + 8);
#pragma unroll
    for (int d = 0; d < 8; ++d) { vt[d][tid] = v0[d]; vt[8 + d][tid] = v1[d]; }
  }
  __syncthreads();
  const int wid = tid >> 6, lane = tid & 63;
  const int l31 = lane & 31, l15 = lane & 15;
  const int hi5 = lane >> 5, hi4 = lane >> 4;
#pragma unroll
  for (int qt = 0; qt < 2; ++qt) {
    const int q0 = (wid * 2 + qt) * 32;
    // B-frag (CQ) is constant across kt
    bf16x8 bq = *(const bf16x8*)(cq + (rbase + q0 + l31) * 128 + cbase + hi5 * 8);
    float lsum = 0.f;
#pragma unroll
    for (int kt = 0; kt < 8; ++kt) {
      bf16x8 ak = *(const bf16x8*)(ck + (rbase + kt * 32 + l31) * 128 + cbase + hi5 * 8);
      f32x16 z = {};
      f32x16 s = __builtin_amdgcn_mfma_f32_32x32x16_bf16(ak, bq, z, 0, 0, 0);
      float p[16];
#pragma unroll
      for (int r = 0; r < 16; ++r) { p[r] = __expf(s[r] * 0.25f); lsum += p[r]; }
#pragma unroll
      for (int r = 0; r < 16; r += 2) {
        unsigned int pk = cvt_pk_bf16(p[r], p[r + 1]);
        int key = kt * 32 + (r & 3) + 8 * (r >> 2) + 4 * hi5;
        *(unsigned int*)&ps[wid][l31][key] = pk;
      }
    }
    lsum += __shfl_xor(lsum, 32);
    if (lane < 32) rsum[wid][lane] = 1.0f / lsum;
#pragma unroll
    for (int m = 0; m < 2; ++m) {
      f32x4 o = {};
#pragma unroll
      for (int k2 = 0; k2 < 8; ++k2) {
        bf16x8 pa = *(const bf16x8*)&ps[wid][m * 16 + l15][k2 * 32 + hi4 * 8];
        bf16x8 vb = *(const bf16x8*)&vt[l15][k2 * 32 + hi4 * 8];
        o = __builtin_amdgcn_mfma_f32_16x16x32_bf16(pa, vb, o, 0, 0, 0);
      }
      float* dst = xa + (rbase + q0 + m * 16 + hi4 * 4) * 128 + cbase + l15;
#pragma unroll
      for (int j = 0; j < 4; ++j) {
        float inv = rsum[wid][m * 16 + hi4 * 4 + j];
        dst[(size_t)j * 128] = o[j] * inv;
      }
    }
  }
}

// ---- attn2 over M=16 axis; scrambled write g=q*4+b ----
__global__ __launch_bounds__(128) void attn2_kernel(
    const float* __restrict__ xa, float* __restrict__ xr) {
  __shared__ float xas[16][128];
  int b = blockIdx.x >> 8, t = blockIdx.x & 255;
  int tid = threadIdx.x;
#pragma unroll
  for (int j = 0; j < 4; j++) {
    int idx = tid + (j << 7);
    int r = idx >> 5, c4 = idx & 31;
    *(float4*)&xas[r][c4 * 4] =
        *(const float4*)(xa + ((size_t)((b * 16 + r) * 256 + t)) * 128 + c4 * 4);
  }
  __syncthreads();
  int h = tid >> 4, q = tid & 15;
  float xq[16];
#pragma unroll
  for (int d = 0; d < 16; d++) xq[d] = xas[q][h * 16 + d];
  float sc[16];
  float mx = -1e30f;
#pragma unroll
  for (int k = 0; k < 16; k++) {
    float s = 0.f;
#pragma unroll
    for (int d = 0; d < 16; d++) s += xq[d] * xas[k][h * 16 + d];
    s *= 0.25f;
    sc[k] = s;
    mx = fmaxf(mx, s);
  }
  float den = 0.f;
#pragma unroll
  for (int k = 0; k < 16; k++) { sc[k] = __expf(sc[k] - mx); den += sc[k]; }
  float inv = 1.0f / den;
  float out[16] = {};
#pragma unroll
  for (int k = 0; k < 16; k++) {
    float w = sc[k];
#pragma unroll
    for (int d = 0; d < 16; d++) out[d] += w * xas[k][h * 16 + d];
  }
  int g = q * 4 + b;
  float* dst = xr + ((size_t)(g * 256 + t)) * 128 + h * 16;
#pragma unroll
  for (int p = 0; p < 4; p++) {
    float4 o;
    o.x = out[p*4+0]*inv; o.y = out[p*4+1]*inv;
    o.z = out[p*4+2]*inv; o.w = out[p*4+3]*inv;
    *(float4*)(dst + p * 4) = o;
  }
}

// ---- final LayerNorm (in-place safe) ----
__global__ __launch_bounds__(256) void ln_kernel(
    const float* __restrict__ X, const float* __restrict__ g,
    const float* __restrict__ b, float* __restrict__ Y) {
  int wid = threadIdx.x >> 6, lane = threadIdx.x & 63;
  int row = (blockIdx.x << 2) + wid;
  float2 xv = *(const float2*)(X + (size_t)row * D_ + lane * 2);
  float s = wsum64(xv.x + xv.y);
  float sq = wsum64(xv.x * xv.x + xv.y * xv.y);
  float mu = s * (1.0f / 128.0f);
  float var = sq * (1.0f / 128.0f) - mu * mu;
  float rstd = rsqrtf(var + 1e-6f);
  float2 gv = *(const float2*)(g + lane * 2);
  float2 bv = *(const float2*)(b + lane * 2);
  float2 o;
  o.x = (xv.x - mu) * rstd * gv.x + bv.x;
  o.y = (xv.y - mu) * rstd * gv.y + bv.y;
  *(float2*)(Y + (size_t)row * D_ + lane * 2) = o;
}

extern "C" void kernel_launch(void* const* d_in, const int* in_sizes, int n_in,
                              void* d_out, int out_size, void* d_ws, size_t ws_size,
                              hipStream_t stream) {
  const float* x    = (const float*)d_in[0];
  const float* Wq   = (const float*)d_in[1];
  const float* bq   = (const float*)d_in[2];
  const float* Wk   = (const float*)d_in[3];
  const float* bk   = (const float*)d_in[4];
  const float* Wv   = (const float*)d_in[5];
  const float* bv   = (const float*)d_in[6];
  const float* Wo   = (const float*)d_in[7];
  const float* bo   = (const float*)d_in[8];
  const float* W1   = (const float*)d_in[9];
  const float* b1   = (const float*)d_in[10];
  const float* W2   = (const float*)d_in[11];
  const float* b2   = (const float*)d_in[12];
  const float* ln1g = (const float*)d_in[13];
  const float* ln1b = (const float*)d_in[14];
  const float* ln2g = (const float*)d_in[15];
  const float* ln2b = (const float*)d_in[16];
  const float* lnfg = (const float*)d_in[17];
  const float* lnfb = (const float*)d_in[18];

  // ws layout (24.76 MB):
  char* base = (char*)d_ws;
  float*          XA  = (float*)base;                          // [0,8M) fp32
  unsigned short* Qb  = (unsigned short*)(base + (8u  << 20)); // [8,12) bf16
  unsigned short* Kb  = (unsigned short*)(base + (12u << 20)); // [12,16) bf16
  unsigned short* Vb  = (unsigned short*)(base + (16u << 20)); // [16,20) bf16
  unsigned short* Ab  = (unsigned short*)(base + (20u << 20)); // [20,24) bf16
  float*          XR  = (float*)(base + (8u << 20));           // [8,16) fp32 (Qb/Kb dead)
  unsigned short* Mid = (unsigned short*)base;                 // [0,16) bf16 (XA/Qb/Kb dead)
  unsigned short* Wb  = (unsigned short*)(base + (24u << 20)); // 768 KB
  float*          Bs  = (float*)(base + (24u << 20) + 786432); // 9.2 KB
  float*          Y   = (float*)d_out;

  wconv_kernel<<<192, 256, 0, stream>>>(Wq, Wk, Wv, Wo, W1, W2, Wb);
  bconv_kernel<<<9, 256, 0, stream>>>(bq, bk, bv, bo, b1, b2, Bs);

  for (int i = 0; i < 2; ++i) {
    const float* cur = i ? Y : x;
    const unsigned short* Wl = Wb + (size_t)i * 196608;
    const float* Bl = Bs + i * 1152;
    lnconv_kernel<<<4096, 256, 0, stream>>>(cur, ln1g + i*128, ln1b + i*128, Ab);
    gemm_kernel<<<dim3(256, 3), 256, 0, stream>>>(Ab, 128, Wl, 128, Bl, 128,
                                                  nullptr, nullptr, Qb, 128, (int)S_, 128, 0);
    ctx_combine_kernel<<<dim3(64, 2), 256, 0, stream>>>(Qb, Kb);
    attn1_kernel<<<512, 256, 0, stream>>>(Qb, Kb, Vb, XA);
    attn2_kernel<<<1024, 128, 0, stream>>>(XA, XR);
    conv_kernel<<<1024, 256, 0, stream>>>(XR, Ab);
    gemm_kernel<<<dim3(256, 1), 256, 0, stream>>>(Ab, 128, Wl + 49152, 128, Bl + 384, 128,
                                                  cur, Y, nullptr, 128, 0, 128, 0);
    lnconv_kernel<<<4096, 256, 0, stream>>>(Y, ln2g + i*128, ln2b + i*128, Ab);
    gemm_kernel<<<dim3(256, 4), 256, 0, stream>>>(Ab, 128, Wl + 65536, 128, Bl + 512, 128,
                                                  nullptr, nullptr, Mid, 512, 128, 128, 1);
    gemm_kernel<<<dim3(256, 1), 256, 0, stream>>>(Mid, 512, Wl + 131072, 512, Bl + 1024, 128,
                                                  Y, Y, nullptr, 128, 0, 512, 0);
  }
  ln_kernel<<<4096, 256, 0, stream>>>(Y, lnfg, lnfb, Y);
}

// Round 6
// 316.317 us; speedup vs baseline: 2.8968x; 1.1494x over previous
//
#include <hip/hip_runtime.h>
#include <cstddef>
#include <cstdint>

// Shapes: B=4, M=16, T=256, D=128, H=8, CTX=16, L=2
static constexpr int D_ = 128;
static constexpr int NROW = 16384;               // B*M*T rows
static constexpr size_t S_ = (size_t)NROW * D_;  // elems per activation

typedef __attribute__((ext_vector_type(8))) short bf16x8;
typedef __attribute__((ext_vector_type(4))) float f32x4;
typedef __attribute__((ext_vector_type(16))) float f32x16;
typedef __attribute__((ext_vector_type(8))) unsigned short ushortx8;
typedef __attribute__((ext_vector_type(4))) unsigned short ushortx4;

__device__ __forceinline__ unsigned short f2bf(float f) {
  unsigned int u = __float_as_uint(f);
  u += 0x7fff + ((u >> 16) & 1);
  return (unsigned short)(u >> 16);
}
__device__ __forceinline__ float bf2f(unsigned short h) {
  return __uint_as_float(((unsigned int)h) << 16);
}
__device__ __forceinline__ unsigned int cvt_pk_bf16(float lo, float hi) {
  unsigned int r;
  asm volatile("v_cvt_pk_bf16_f32 %0, %1, %2" : "=v"(r) : "v"(lo), "v"(hi));
  return r;
}
__device__ __forceinline__ float wsum64(float s) {
#pragma unroll
  for (int off = 32; off >= 1; off >>= 1) s += __shfl_xor(s, off);
  return s;
}

// ---- fused LN stats + normalize + bf16 convert (layer-0 input only) ----
__global__ __launch_bounds__(256) void lnconv_kernel(
    const float* __restrict__ X, const float* __restrict__ g,
    const float* __restrict__ b, unsigned short* __restrict__ out) {
  int wid = threadIdx.x >> 6, lane = threadIdx.x & 63;
  int row = (blockIdx.x << 2) + wid;
  float2 xv = *(const float2*)(X + (size_t)row * D_ + lane * 2);
  float s = wsum64(xv.x + xv.y);
  float sq = wsum64(xv.x * xv.x + xv.y * xv.y);
  float mu = s * (1.0f / 128.0f);
  float var = sq * (1.0f / 128.0f) - mu * mu;
  float rstd = rsqrtf(var + 1e-6f);
  float2 gv = *(const float2*)(g + lane * 2);
  float2 bv = *(const float2*)(b + lane * 2);
  unsigned int lo = f2bf((xv.x - mu) * rstd * gv.x + bv.x);
  unsigned int hi = f2bf((xv.y - mu) * rstd * gv.y + bv.y);
  *(unsigned int*)(out + (size_t)row * D_ + lane * 2) = lo | (hi << 16);
}

// ---- weights fp32->bf16, packed per layer: [QKV(384x128)][Wo][W1][W2] ----
__global__ __launch_bounds__(256) void wconv_kernel(
    const float* __restrict__ Wq, const float* __restrict__ Wk,
    const float* __restrict__ Wv, const float* __restrict__ Wo,
    const float* __restrict__ W1, const float* __restrict__ W2,
    unsigned short* __restrict__ out) {
  size_t i = ((size_t)blockIdx.x * 256 + threadIdx.x) * 8;
  int layer = i >= 196608;
  size_t o = i - (size_t)layer * 196608;
  const float* src; size_t off;
  if      (o < 16384)  { src = Wq + layer * 16384; off = o; }
  else if (o < 32768)  { src = Wk + layer * 16384; off = o - 16384; }
  else if (o < 49152)  { src = Wv + layer * 16384; off = o - 32768; }
  else if (o < 65536)  { src = Wo + layer * 16384; off = o - 49152; }
  else if (o < 131072) { src = W1 + layer * 65536; off = o - 65536; }
  else                 { src = W2 + layer * 65536; off = o - 131072; }
  ushortx8 r;
#pragma unroll
  for (int j = 0; j < 8; j++) r[j] = f2bf(src[off + j]);
  *(ushortx8*)(out + i) = r;
}

// ---- pack biases fp32 per layer: [bq bk bv bo b1(512) b2] = 1152 floats ----
__global__ __launch_bounds__(256) void bconv_kernel(
    const float* __restrict__ bq, const float* __restrict__ bk,
    const float* __restrict__ bv, const float* __restrict__ bo,
    const float* __restrict__ b1, const float* __restrict__ b2,
    float* __restrict__ out) {
  int tid = threadIdx.x + blockIdx.x * 256;
  if (tid >= 2304) return;
  int layer = tid / 1152, o = tid % 1152;
  float v;
  if      (o < 128)  v = bq[layer * 128 + o];
  else if (o < 256)  v = bk[layer * 128 + o - 128];
  else if (o < 384)  v = bv[layer * 128 + o - 256];
  else if (o < 512)  v = bo[layer * 128 + o - 384];
  else if (o < 1024) v = b1[layer * 512 + o - 512];
  else               v = b2[layer * 128 + o - 1024];
  out[tid] = v;
}

// ---- bf16 MFMA GEMM + optional fused row-LayerNorm epilogue ----
// lnMode 0: raw (Cf fp32 or Cb bf16). 1: Cf=raw fp32 AND Cb=LN'd bf16. 2: Cf=LN'd fp32.
__global__ __launch_bounds__(256) void gemm_kernel(
    const unsigned short* __restrict__ A, int lda,
    const unsigned short* __restrict__ Wbase, int ldw,
    const float* __restrict__ biasB, int biasStride,
    const float* __restrict__ resid,
    float* __restrict__ Cf, unsigned short* __restrict__ Cb,
    int ldc, int dstOff, int K, int relu,
    const float* __restrict__ lnG, const float* __restrict__ lnB, int lnMode) {
  const int y = blockIdx.y;
  const unsigned short* W = Wbase + (size_t)y * 128 * ldw;
  const float* bias = biasB + (size_t)y * biasStride;
  const int m0 = blockIdx.x * 64 + (threadIdx.x >> 6) * 16;
  const int l = threadIdx.x & 63;
  const int lr = l & 15, lk = (l >> 4) * 8;
  f32x4 acc[8] = {};
  const unsigned short* Ap = A + (size_t)(m0 + lr) * lda + lk;
  const unsigned short* Wp = W + (size_t)lr * ldw + lk;
#pragma unroll 4
  for (int k0 = 0; k0 < K; k0 += 32) {
    bf16x8 a = *(const bf16x8*)(Ap + k0);
#pragma unroll
    for (int n = 0; n < 8; ++n) {
      bf16x8 bfr = *(const bf16x8*)(Wp + (size_t)(n * 16) * ldw + k0);
      acc[n] = __builtin_amdgcn_mfma_f32_16x16x32_bf16(a, bfr, acc[n], 0, 0, 0);
    }
  }
  const int rb = (l >> 4) * 4;
  // finalize values (bias, relu, residual) in-place in acc
#pragma unroll
  for (int n = 0; n < 8; ++n) {
    int col = n * 16 + lr;
    float bval = bias[col];
#pragma unroll
    for (int j = 0; j < 4; ++j) {
      float v = acc[n][j] + bval;
      if (relu) v = fmaxf(v, 0.f);
      if (resid) v += resid[(size_t)(m0 + rb + j) * 128 + col];
      acc[n][j] = v;
    }
  }
  if (lnMode == 0) {
#pragma unroll
    for (int n = 0; n < 8; ++n) {
      int col = n * 16 + lr;
#pragma unroll
      for (int j = 0; j < 4; ++j) {
        size_t off = (size_t)(m0 + rb + j) * ldc + (size_t)y * dstOff + col;
        if (Cf) Cf[off] = acc[n][j];
        else Cb[off] = f2bf(acc[n][j]);
      }
    }
  } else {
    // row stats: cols of row (rb+j) live in the 16 lanes sharing hi4 (xor offsets <16)
    float s[4] = {}, sq[4] = {};
#pragma unroll
    for (int n = 0; n < 8; ++n)
#pragma unroll
      for (int j = 0; j < 4; ++j) {
        s[j] += acc[n][j];
        sq[j] = fmaf(acc[n][j], acc[n][j], sq[j]);
      }
#pragma unroll
    for (int off = 1; off < 16; off <<= 1)
#pragma unroll
      for (int j = 0; j < 4; ++j) {
        s[j] += __shfl_xor(s[j], off);
        sq[j] += __shfl_xor(sq[j], off);
      }
    float mu[4], rstd[4];
#pragma unroll
    for (int j = 0; j < 4; ++j) {
      mu[j] = s[j] * (1.0f / 128.0f);
      float var = sq[j] * (1.0f / 128.0f) - mu[j] * mu[j];
      rstd[j] = rsqrtf(var + 1e-6f);
    }
#pragma unroll
    for (int n = 0; n < 8; ++n) {
      int col = n * 16 + lr;
      float g = lnG[col], bb = lnB[col];
#pragma unroll
      for (int j = 0; j < 4; ++j) {
        int row = m0 + rb + j;
        float t = (acc[n][j] - mu[j]) * rstd[j] * g + bb;
        if (lnMode == 1) {
          Cf[(size_t)row * 128 + col] = acc[n][j];
          Cb[(size_t)row * 128 + col] = f2bf(t);
        } else {
          Cf[(size_t)row * 128 + col] = t;
        }
      }
    }
  }
}

// ---- context attention: per (bm, src, 64-query chunk); fp32 LDS window, 2 lanes/query ----
static constexpr int CTXLD = 130;  // even: b64-aligned float2, bank step 2 -> <=4-way
__global__ __launch_bounds__(128) void ctx_kernel(
    const unsigned short* __restrict__ qin, const unsigned short* __restrict__ kin,
    unsigned short* __restrict__ cqo, unsigned short* __restrict__ cko) {
  __shared__ float xs[79 * CTXLD];  // rows t0-15 .. t0+63, zero-filled pad
  const unsigned short* src = blockIdx.y ? kin : qin;
  unsigned short* dst = blockIdx.y ? cko : cqo;
  const size_t rbase = (size_t)blockIdx.x * 256;
  const int t0 = blockIdx.z * 64;
  const int tid = threadIdx.x;
#pragma unroll
  for (int it = 0; it < 10; ++it) {
    int idx = it * 128 + tid;
    int i = idx >> 4, c8 = (idx & 15) * 8;
    if (i < 79) {
      int rg = t0 - 15 + i;
      float f[8];
      if (rg >= 0) {
        ushortx8 wv = *(const ushortx8*)(src + (rbase + rg) * 128 + c8);
#pragma unroll
        for (int j = 0; j < 8; ++j) f[j] = bf2f(wv[j]);
      } else {
#pragma unroll
        for (int j = 0; j < 8; ++j) f[j] = 0.f;
      }
#pragma unroll
      for (int j = 0; j < 8; j += 2)
        *(float2*)&xs[i * CTXLD + c8 + j] = make_float2(f[j], f[j + 1]);
    }
  }
  __syncthreads();
  const int ql = tid >> 1, h = tid & 1;
  const int cb = h * 64;
  float ow[64];
#pragma unroll
  for (int c = 0; c < 64; c += 2) {
    float2 w = *(const float2*)&xs[(ql + 15) * CTXLD + cb + c];
    ow[c] = w.x; ow[c + 1] = w.y;
  }
  float p[16];
#pragma unroll
  for (int l = 0; l < 16; ++l) {
    const float* row = &xs[(ql + l) * CTXLD + cb];
    float d = 0.f;
#pragma unroll
    for (int c = 0; c < 64; c += 2) {
      float2 w = *(const float2*)(row + c);
      d = fmaf(ow[c], w.x, d);
      d = fmaf(ow[c + 1], w.y, d);
    }
    p[l] = d;
  }
  float den = 0.f;
#pragma unroll
  for (int l = 0; l < 16; ++l) {
    float sc = p[l] + __shfl_xor(p[l], 1);        // full 128-dot from lane pair
    p[l] = __expf(sc * 0.08838834764831845f);     // pad rows: dot=0 -> exp(0)=1
    den += p[l];
  }
  float o[64];
#pragma unroll
  for (int c = 0; c < 64; ++c) o[c] = 0.f;
#pragma unroll
  for (int l = 0; l < 16; ++l) {
    float pl = p[l];
    const float* row = &xs[(ql + l) * CTXLD + cb];
#pragma unroll
    for (int c = 0; c < 64; c += 2) {
      float2 w = *(const float2*)(row + c);
      o[c] = fmaf(pl, w.x, o[c]);
      o[c + 1] = fmaf(pl, w.y, o[c + 1]);
    }
  }
  float inv = 1.0f / den;
  unsigned short* op = dst + (rbase + t0 + ql) * 128 + cb;
#pragma unroll
  for (int c8 = 0; c8 < 8; ++c8) {
    ushortx8 r;
#pragma unroll
    for (int j = 0; j < 8; ++j) r[j] = f2bf(o[c8 * 8 + j] * inv);
    *(ushortx8*)(op + c8 * 8) = r;
  }
}

// ---- attn1 (MFMA): S^T = CK·CQ^T (32x32x16); P via LDS; O = P·V (16x16x32).
//      Writes bf16 IN-PLACE over V (block-exclusive (bm,h) slice). ----
static constexpr int PW = 272;
__global__ __launch_bounds__(256) void attn1_kernel(
    const unsigned short* __restrict__ cq, const unsigned short* __restrict__ ck,
    unsigned short* __restrict__ v) {
  __shared__ unsigned short vt[16][PW];
  __shared__ unsigned short ps[4][32][PW];
  __shared__ float rsum[4][32];
  const int bm = blockIdx.x >> 3, h = blockIdx.x & 7;
  const size_t rbase = (size_t)bm * 256;
  const int cbase = h * 16;
  const int tid = threadIdx.x;
  {
    ushortx8 v0 = *(const ushortx8*)(v + (rbase + tid) * 128 + cbase);
    ushortx8 v1 = *(const ushortx8*)(v + (rbase + tid) * 128 + cbase + 8);
#pragma unroll
    for (int d = 0; d < 8; ++d) { vt[d][tid] = v0[d]; vt[8 + d][tid] = v1[d]; }
  }
  __syncthreads();
  const int wid = tid >> 6, lane = tid & 63;
  const int l31 = lane & 31, l15 = lane & 15;
  const int hi5 = lane >> 5, hi4 = lane >> 4;
#pragma unroll
  for (int qt = 0; qt < 2; ++qt) {
    const int q0 = (wid * 2 + qt) * 32;
    bf16x8 bq = *(const bf16x8*)(cq + (rbase + q0 + l31) * 128 + cbase + hi5 * 8);
    float lsum = 0.f;
#pragma unroll
    for (int kt = 0; kt < 8; ++kt) {
      bf16x8 ak = *(const bf16x8*)(ck + (rbase + kt * 32 + l31) * 128 + cbase + hi5 * 8);
      f32x16 z = {};
      f32x16 s = __builtin_amdgcn_mfma_f32_32x32x16_bf16(ak, bq, z, 0, 0, 0);
      float p[16];
#pragma unroll
      for (int r = 0; r < 16; ++r) { p[r] = __expf(s[r] * 0.25f); lsum += p[r]; }
#pragma unroll
      for (int r = 0; r < 16; r += 2) {
        unsigned int pk = cvt_pk_bf16(p[r], p[r + 1]);
        int key = kt * 32 + (r & 3) + 8 * (r >> 2) + 4 * hi5;
        *(unsigned int*)&ps[wid][l31][key] = pk;
      }
    }
    lsum += __shfl_xor(lsum, 32);
    if (lane < 32) rsum[wid][lane] = 1.0f / lsum;
#pragma unroll
    for (int m = 0; m < 2; ++m) {
      f32x4 o = {};
#pragma unroll
      for (int k2 = 0; k2 < 8; ++k2) {
        bf16x8 pa = *(const bf16x8*)&ps[wid][m * 16 + l15][k2 * 32 + hi4 * 8];
        bf16x8 vb = *(const bf16x8*)&vt[l15][k2 * 32 + hi4 * 8];
        o = __builtin_amdgcn_mfma_f32_16x16x32_bf16(pa, vb, o, 0, 0, 0);
      }
      unsigned short* dst = v + (rbase + q0 + m * 16 + hi4 * 4) * 128 + cbase + l15;
#pragma unroll
      for (int j = 0; j < 4; ++j) {
        float inv = rsum[wid][m * 16 + hi4 * 4 + j];
        dst[(size_t)j * 128] = f2bf(o[j] * inv);
      }
    }
  }
}

// ---- attn2 over M=16 axis (bf16 in/out); scrambled write g=q*4+b ----
__global__ __launch_bounds__(128) void attn2_kernel(
    const unsigned short* __restrict__ xa, unsigned short* __restrict__ xr) {
  __shared__ float xas[16][128];
  int b = blockIdx.x >> 8, t = blockIdx.x & 255;
  int tid = threadIdx.x;
#pragma unroll
  for (int jj = 0; jj < 2; ++jj) {
    int idx = tid + (jj << 7);
    int r = idx >> 4, c8 = (idx & 15) * 8;
    ushortx8 vv = *(const ushortx8*)(xa + ((size_t)((b * 16 + r) * 256 + t)) * 128 + c8);
#pragma unroll
    for (int j = 0; j < 8; ++j) xas[r][c8 + j] = bf2f(vv[j]);
  }
  __syncthreads();
  int h = tid >> 4, q = tid & 15;
  float xq[16];
#pragma unroll
  for (int d = 0; d < 16; d++) xq[d] = xas[q][h * 16 + d];
  float sc[16];
  float mx = -1e30f;
#pragma unroll
  for (int k = 0; k < 16; k++) {
    float s = 0.f;
#pragma unroll
    for (int d = 0; d < 16; d++) s += xq[d] * xas[k][h * 16 + d];
    s *= 0.25f;
    sc[k] = s;
    mx = fmaxf(mx, s);
  }
  float den = 0.f;
#pragma unroll
  for (int k = 0; k < 16; k++) { sc[k] = __expf(sc[k] - mx); den += sc[k]; }
  float inv = 1.0f / den;
  float out[16] = {};
#pragma unroll
  for (int k = 0; k < 16; k++) {
    float w = sc[k];
#pragma unroll
    for (int d = 0; d < 16; d++) out[d] += w * xas[k][h * 16 + d];
  }
  int g = q * 4 + b;
  unsigned short* dstp = xr + ((size_t)(g * 256 + t)) * 128 + h * 16;
  ushortx8 r0;
#pragma unroll
  for (int j = 0; j < 8; ++j) r0[j] = f2bf(out[j] * inv);
  *(ushortx8*)dstp = r0;
#pragma unroll
  for (int j = 0; j < 8; ++j) r0[j] = f2bf(out[8 + j] * inv);
  *(ushortx8*)(dstp + 8) = r0;
}

extern "C" void kernel_launch(void* const* d_in, const int* in_sizes, int n_in,
                              void* d_out, int out_size, void* d_ws, size_t ws_size,
                              hipStream_t stream) {
  const float* x    = (const float*)d_in[0];
  const float* Wq   = (const float*)d_in[1];
  const float* bq   = (const float*)d_in[2];
  const float* Wk   = (const float*)d_in[3];
  const float* bk   = (const float*)d_in[4];
  const float* Wv   = (const float*)d_in[5];
  const float* bv   = (const float*)d_in[6];
  const float* Wo   = (const float*)d_in[7];
  const float* bo   = (const float*)d_in[8];
  const float* W1   = (const float*)d_in[9];
  const float* b1   = (const float*)d_in[10];
  const float* W2   = (const float*)d_in[11];
  const float* b2   = (const float*)d_in[12];
  const float* ln1g = (const float*)d_in[13];
  const float* ln1b = (const float*)d_in[14];
  const float* ln2g = (const float*)d_in[15];
  const float* ln2b = (const float*)d_in[16];
  const float* lnfg = (const float*)d_in[17];
  const float* lnfb = (const float*)d_in[18];

  // ws layout (24.76 MB), all bf16 activations:
  char* base = (char*)d_ws;
  unsigned short* CQb = (unsigned short*)base;                 // [0,4M)
  unsigned short* CKb = (unsigned short*)(base + (4u  << 20)); // [4,8)
  unsigned short* Qb  = (unsigned short*)(base + (8u  << 20)); // [8,12)
  unsigned short* Kb  = (unsigned short*)(base + (12u << 20)); // [12,16)
  unsigned short* Vb  = (unsigned short*)(base + (16u << 20)); // [16,20)  (attn1 out in-place)
  unsigned short* Ab  = (unsigned short*)(base + (20u << 20)); // [20,24)
  unsigned short* Mid = (unsigned short*)base;                 // [0,16) FFN hidden (CQ/CK/Q/K dead)
  unsigned short* Wb  = (unsigned short*)(base + (24u << 20)); // 768 KB
  float*          Bs  = (float*)(base + (24u << 20) + 786432); // 9.2 KB
  float*          Y   = (float*)d_out;

  wconv_kernel<<<192, 256, 0, stream>>>(Wq, Wk, Wv, Wo, W1, W2, Wb);
  bconv_kernel<<<9, 256, 0, stream>>>(bq, bk, bv, bo, b1, b2, Bs);
  lnconv_kernel<<<4096, 256, 0, stream>>>(x, ln1g, ln1b, Ab);  // layer-0 LN1 only

  for (int i = 0; i < 2; ++i) {
    const float* rin = i ? Y : x;
    const unsigned short* Wl = Wb + (size_t)i * 196608;
    const float* Bl = Bs + i * 1152;
    // QKV
    gemm_kernel<<<dim3(256, 3), 256, 0, stream>>>(Ab, 128, Wl, 128, Bl, 128,
        nullptr, nullptr, Qb, 128, (int)S_, 128, 0, nullptr, nullptr, 0);
    // context combine -> CQ, CK
    ctx_kernel<<<dim3(64, 2, 4), 128, 0, stream>>>(Qb, Kb, CQb, CKb);
    // T x T attention (writes bf16 in-place over Vb)
    attn1_kernel<<<512, 256, 0, stream>>>(CQb, CKb, Vb);
    // M attention with scramble -> Ab
    attn2_kernel<<<1024, 128, 0, stream>>>(Vb, Ab);
    // Wo + residual -> Y (raw) and Ab = LN2(Y) bf16   [in-place Cb=Ab is block-safe]
    gemm_kernel<<<dim3(256, 1), 256, 0, stream>>>(Ab, 128, Wl + 49152, 128, Bl + 384, 128,
        rin, Y, Ab, 128, 0, 128, 0, ln2g + i * 128, ln2b + i * 128, 1);
    // FFN W1 (4 chunks) -> Mid[16384,512] bf16, relu
    gemm_kernel<<<dim3(256, 4), 256, 0, stream>>>(Ab, 128, Wl + 65536, 128, Bl + 512, 128,
        nullptr, nullptr, Mid, 512, 128, 128, 1, nullptr, nullptr, 0);
    // FFN W2 (K=512) + residual -> Y ; fused next-LN
    if (i == 0) {
      gemm_kernel<<<dim3(256, 1), 256, 0, stream>>>(Mid, 512, Wl + 131072, 512, Bl + 1024, 128,
          Y, Y, Ab, 128, 0, 512, 0, ln1g + 128, ln1b + 128, 1);   // Ab = LN1_layer1(Y)
    } else {
      gemm_kernel<<<dim3(256, 1), 256, 0, stream>>>(Mid, 512, Wl + 131072, 512, Bl + 1024, 128,
          Y, Y, nullptr, 128, 0, 512, 0, lnfg, lnfb, 2);          // d_out = LN_f(Y)
    }
  }
}

// Round 7
// 274.656 us; speedup vs baseline: 3.3362x; 1.1517x over previous
//
#include <hip/hip_runtime.h>
#include <cstddef>
#include <cstdint>

// Shapes: B=4, M=16, T=256, D=128, H=8, CTX=16, L=2
static constexpr int D_ = 128;
static constexpr int NROW = 16384;               // B*M*T rows
static constexpr size_t S_ = (size_t)NROW * D_;  // elems per activation

typedef __attribute__((ext_vector_type(8))) short bf16x8;
typedef __attribute__((ext_vector_type(4))) float f32x4;
typedef __attribute__((ext_vector_type(16))) float f32x16;
typedef __attribute__((ext_vector_type(8))) unsigned short ushortx8;
typedef __attribute__((ext_vector_type(4))) unsigned short ushortx4;

__device__ __forceinline__ unsigned short f2bf(float f) {
  unsigned int u = __float_as_uint(f);
  u += 0x7fff + ((u >> 16) & 1);
  return (unsigned short)(u >> 16);
}
__device__ __forceinline__ float bf2f(unsigned short h) {
  return __uint_as_float(((unsigned int)h) << 16);
}
__device__ __forceinline__ unsigned int cvt_pk_bf16(float lo, float hi) {
  unsigned int r;
  asm volatile("v_cvt_pk_bf16_f32 %0, %1, %2" : "=v"(r) : "v"(lo), "v"(hi));
  return r;
}
__device__ __forceinline__ float wsum64(float s) {
#pragma unroll
  for (int off = 32; off >= 1; off >>= 1) s += __shfl_xor(s, off);
  return s;
}

// ---- fused LN stats + normalize + bf16 convert (layer-0 input only) ----
__global__ __launch_bounds__(256) void lnconv_kernel(
    const float* __restrict__ X, const float* __restrict__ g,
    const float* __restrict__ b, unsigned short* __restrict__ out) {
  int wid = threadIdx.x >> 6, lane = threadIdx.x & 63;
  int row = (blockIdx.x << 2) + wid;
  float2 xv = *(const float2*)(X + (size_t)row * D_ + lane * 2);
  float s = wsum64(xv.x + xv.y);
  float sq = wsum64(xv.x * xv.x + xv.y * xv.y);
  float mu = s * (1.0f / 128.0f);
  float var = sq * (1.0f / 128.0f) - mu * mu;
  float rstd = rsqrtf(var + 1e-6f);
  float2 gv = *(const float2*)(g + lane * 2);
  float2 bv = *(const float2*)(b + lane * 2);
  unsigned int lo = f2bf((xv.x - mu) * rstd * gv.x + bv.x);
  unsigned int hi = f2bf((xv.y - mu) * rstd * gv.y + bv.y);
  *(unsigned int*)(out + (size_t)row * D_ + lane * 2) = lo | (hi << 16);
}

// ---- weights fp32->bf16, packed per layer: [QKV(384x128)][Wo][W1][W2] ----
__global__ __launch_bounds__(256) void wconv_kernel(
    const float* __restrict__ Wq, const float* __restrict__ Wk,
    const float* __restrict__ Wv, const float* __restrict__ Wo,
    const float* __restrict__ W1, const float* __restrict__ W2,
    unsigned short* __restrict__ out) {
  size_t i = ((size_t)blockIdx.x * 256 + threadIdx.x) * 8;
  int layer = i >= 196608;
  size_t o = i - (size_t)layer * 196608;
  const float* src; size_t off;
  if      (o < 16384)  { src = Wq + layer * 16384; off = o; }
  else if (o < 32768)  { src = Wk + layer * 16384; off = o - 16384; }
  else if (o < 49152)  { src = Wv + layer * 16384; off = o - 32768; }
  else if (o < 65536)  { src = Wo + layer * 16384; off = o - 49152; }
  else if (o < 131072) { src = W1 + layer * 65536; off = o - 65536; }
  else                 { src = W2 + layer * 65536; off = o - 131072; }
  ushortx8 r;
#pragma unroll
  for (int j = 0; j < 8; j++) r[j] = f2bf(src[off + j]);
  *(ushortx8*)(out + i) = r;
}

// ---- pack biases fp32 per layer: [bq bk bv bo b1(512) b2] = 1152 floats ----
__global__ __launch_bounds__(256) void bconv_kernel(
    const float* __restrict__ bq, const float* __restrict__ bk,
    const float* __restrict__ bv, const float* __restrict__ bo,
    const float* __restrict__ b1, const float* __restrict__ b2,
    float* __restrict__ out) {
  int tid = threadIdx.x + blockIdx.x * 256;
  if (tid >= 2304) return;
  int layer = tid / 1152, o = tid % 1152;
  float v;
  if      (o < 128)  v = bq[layer * 128 + o];
  else if (o < 256)  v = bk[layer * 128 + o - 128];
  else if (o < 384)  v = bv[layer * 128 + o - 256];
  else if (o < 512)  v = bo[layer * 128 + o - 384];
  else if (o < 1024) v = b1[layer * 512 + o - 512];
  else               v = b2[layer * 128 + o - 1024];
  out[tid] = v;
}

// ---- bf16 MFMA GEMM v2: 512 thr / 8 waves; block 64 rows x 128 cols;
//      wave 16 rows x 64 cols; whole 128-K slab of loads hoisted to regs
//      (20 b128 in flight) before the MFMA burst. Optional fused LN epilogue
//      (cross-wave pair reduction via 1KB LDS + barrier). ----
// lnMode 0: raw (Cf fp32 or Cb bf16). 1: Cf=raw fp32 AND Cb=LN'd bf16. 2: Cf=LN'd fp32.
__global__ __launch_bounds__(512) void gemm_kernel(
    const unsigned short* __restrict__ A, int lda,
    const unsigned short* __restrict__ Wbase, int ldw,
    const float* __restrict__ biasB, int biasStride,
    const float* __restrict__ resid,
    float* __restrict__ Cf, unsigned short* __restrict__ Cb,
    int ldc, int dstOff, int K, int relu,
    const float* __restrict__ lnG, const float* __restrict__ lnB, int lnMode) {
  __shared__ float lnred[8][16][2];
  const int y = blockIdx.y;
  const unsigned short* W = Wbase + (size_t)y * 128 * ldw;
  const float* bias = biasB + (size_t)y * biasStride;
  const int w = threadIdx.x >> 6;
  const int l = threadIdx.x & 63;
  const int r0 = blockIdx.x * 64 + (w >> 1) * 16;
  const int c0 = (w & 1) * 64;
  const int lr = l & 15, lk = (l >> 4) * 8;
  f32x4 acc[4] = {};
  const unsigned short* Ap = A + (size_t)(r0 + lr) * lda + lk;
  const unsigned short* Wp = W + (size_t)(c0 + lr) * ldw + lk;
#pragma unroll 1
  for (int kb = 0; kb < K; kb += 128) {
    bf16x8 aF[4];
    bf16x8 wF[4][4];
#pragma unroll
    for (int kt = 0; kt < 4; ++kt) {
      int k0 = kb + kt * 32;
      aF[kt] = *(const bf16x8*)(Ap + k0);
#pragma unroll
      for (int n = 0; n < 4; ++n)
        wF[kt][n] = *(const bf16x8*)(Wp + (size_t)(n * 16) * ldw + k0);
    }
#pragma unroll
    for (int kt = 0; kt < 4; ++kt)
#pragma unroll
      for (int n = 0; n < 4; ++n)
        acc[n] = __builtin_amdgcn_mfma_f32_16x16x32_bf16(aF[kt], wF[kt][n], acc[n], 0, 0, 0);
  }
  const int rb = (l >> 4) * 4;
  // finalize: bias, relu, residual
#pragma unroll
  for (int n = 0; n < 4; ++n) {
    int col = c0 + n * 16 + lr;
    float bval = bias[col];
#pragma unroll
    for (int j = 0; j < 4; ++j) {
      float v = acc[n][j] + bval;
      if (relu) v = fmaxf(v, 0.f);
      if (resid) v += resid[(size_t)(r0 + rb + j) * 128 + col];
      acc[n][j] = v;
    }
  }
  if (lnMode == 0) {
#pragma unroll
    for (int n = 0; n < 4; ++n) {
      int col = c0 + n * 16 + lr;
#pragma unroll
      for (int j = 0; j < 4; ++j) {
        size_t off = (size_t)(r0 + rb + j) * ldc + (size_t)y * dstOff + col;
        if (Cf) Cf[off] = acc[n][j];
        else Cb[off] = f2bf(acc[n][j]);
      }
    }
  } else {
    // partial row stats over this wave's 64 cols
    float s[4] = {}, sq[4] = {};
#pragma unroll
    for (int n = 0; n < 4; ++n)
#pragma unroll
      for (int j = 0; j < 4; ++j) {
        s[j] += acc[n][j];
        sq[j] = fmaf(acc[n][j], acc[n][j], sq[j]);
      }
#pragma unroll
    for (int off = 1; off < 16; off <<= 1)
#pragma unroll
      for (int j = 0; j < 4; ++j) {
        s[j] += __shfl_xor(s[j], off);
        sq[j] += __shfl_xor(sq[j], off);
      }
    if (lr == 0) {
#pragma unroll
      for (int j = 0; j < 4; ++j) {
        lnred[w][rb + j][0] = s[j];
        lnred[w][rb + j][1] = sq[j];
      }
    }
    __syncthreads();
    float mu[4], rstd[4];
#pragma unroll
    for (int j = 0; j < 4; ++j) {
      float st = s[j] + lnred[w ^ 1][rb + j][0];
      float sqt = sq[j] + lnred[w ^ 1][rb + j][1];
      mu[j] = st * (1.0f / 128.0f);
      float var = sqt * (1.0f / 128.0f) - mu[j] * mu[j];
      rstd[j] = rsqrtf(var + 1e-6f);
    }
#pragma unroll
    for (int n = 0; n < 4; ++n) {
      int col = c0 + n * 16 + lr;
      float g = lnG[col], bb = lnB[col];
#pragma unroll
      for (int j = 0; j < 4; ++j) {
        int row = r0 + rb + j;
        float t = (acc[n][j] - mu[j]) * rstd[j] * g + bb;
        if (lnMode == 1) {
          Cf[(size_t)row * 128 + col] = acc[n][j];
          Cb[(size_t)row * 128 + col] = f2bf(t);
        } else {
          Cf[(size_t)row * 128 + col] = t;
        }
      }
    }
  }
}

// ---- context attention: per (bm, src, 64-query chunk); fp32 LDS window, 2 lanes/query ----
static constexpr int CTXLD = 130;  // even: b64-aligned float2, bank step 2 -> <=4-way
__global__ __launch_bounds__(128) void ctx_kernel(
    const unsigned short* __restrict__ qin, const unsigned short* __restrict__ kin,
    unsigned short* __restrict__ cqo, unsigned short* __restrict__ cko) {
  __shared__ float xs[79 * CTXLD];  // rows t0-15 .. t0+63, zero-filled pad
  const unsigned short* src = blockIdx.y ? kin : qin;
  unsigned short* dst = blockIdx.y ? cko : cqo;
  const size_t rbase = (size_t)blockIdx.x * 256;
  const int t0 = blockIdx.z * 64;
  const int tid = threadIdx.x;
#pragma unroll
  for (int it = 0; it < 10; ++it) {
    int idx = it * 128 + tid;
    int i = idx >> 4, c8 = (idx & 15) * 8;
    if (i < 79) {
      int rg = t0 - 15 + i;
      float f[8];
      if (rg >= 0) {
        ushortx8 wv = *(const ushortx8*)(src + (rbase + rg) * 128 + c8);
#pragma unroll
        for (int j = 0; j < 8; ++j) f[j] = bf2f(wv[j]);
      } else {
#pragma unroll
        for (int j = 0; j < 8; ++j) f[j] = 0.f;
      }
#pragma unroll
      for (int j = 0; j < 8; j += 2)
        *(float2*)&xs[i * CTXLD + c8 + j] = make_float2(f[j], f[j + 1]);
    }
  }
  __syncthreads();
  const int ql = tid >> 1, h = tid & 1;
  const int cb = h * 64;
  float ow[64];
#pragma unroll
  for (int c = 0; c < 64; c += 2) {
    float2 w = *(const float2*)&xs[(ql + 15) * CTXLD + cb + c];
    ow[c] = w.x; ow[c + 1] = w.y;
  }
  float p[16];
#pragma unroll
  for (int l = 0; l < 16; ++l) {
    const float* row = &xs[(ql + l) * CTXLD + cb];
    float d = 0.f;
#pragma unroll
    for (int c = 0; c < 64; c += 2) {
      float2 w = *(const float2*)(row + c);
      d = fmaf(ow[c], w.x, d);
      d = fmaf(ow[c + 1], w.y, d);
    }
    p[l] = d;
  }
  float den = 0.f;
#pragma unroll
  for (int l = 0; l < 16; ++l) {
    float sc = p[l] + __shfl_xor(p[l], 1);
    p[l] = __expf(sc * 0.08838834764831845f);
    den += p[l];
  }
  float o[64];
#pragma unroll
  for (int c = 0; c < 64; ++c) o[c] = 0.f;
#pragma unroll
  for (int l = 0; l < 16; ++l) {
    float pl = p[l];
    const float* row = &xs[(ql + l) * CTXLD + cb];
#pragma unroll
    for (int c = 0; c < 64; c += 2) {
      float2 w = *(const float2*)(row + c);
      o[c] = fmaf(pl, w.x, o[c]);
      o[c + 1] = fmaf(pl, w.y, o[c + 1]);
    }
  }
  float inv = 1.0f / den;
  unsigned short* op = dst + (rbase + t0 + ql) * 128 + cb;
#pragma unroll
  for (int c8 = 0; c8 < 8; ++c8) {
    ushortx8 r;
#pragma unroll
    for (int j = 0; j < 8; ++j) r[j] = f2bf(o[c8 * 8 + j] * inv);
    *(ushortx8*)(op + c8 * 8) = r;
  }
}

// ---- attn1 (MFMA): S^T = CK·CQ^T (32x32x16); P via LDS; O = P·V (16x16x32).
//      Writes bf16 IN-PLACE over V (block-exclusive (bm,h) slice). ----
static constexpr int PW = 272;
__global__ __launch_bounds__(256) void attn1_kernel(
    const unsigned short* __restrict__ cq, const unsigned short* __restrict__ ck,
    unsigned short* __restrict__ v) {
  __shared__ unsigned short vt[16][PW];
  __shared__ unsigned short ps[4][32][PW];
  __shared__ float rsum[4][32];
  const int bm = blockIdx.x >> 3, h = blockIdx.x & 7;
  const size_t rbase = (size_t)bm * 256;
  const int cbase = h * 16;
  const int tid = threadIdx.x;
  {
    ushortx8 v0 = *(const ushortx8*)(v + (rbase + tid) * 128 + cbase);
    ushortx8 v1 = *(const ushortx8*)(v + (rbase + tid) * 128 + cbase + 8);
#pragma unroll
    for (int d = 0; d < 8; ++d) { vt[d][tid] = v0[d]; vt[8 + d][tid] = v1[d]; }
  }
  __syncthreads();
  const int wid = tid >> 6, lane = tid & 63;
  const int l31 = lane & 31, l15 = lane & 15;
  const int hi5 = lane >> 5, hi4 = lane >> 4;
#pragma unroll
  for (int qt = 0; qt < 2; ++qt) {
    const int q0 = (wid * 2 + qt) * 32;
    bf16x8 bq = *(const bf16x8*)(cq + (rbase + q0 + l31) * 128 + cbase + hi5 * 8);
    float lsum = 0.f;
#pragma unroll
    for (int kt = 0; kt < 8; ++kt) {
      bf16x8 ak = *(const bf16x8*)(ck + (rbase + kt * 32 + l31) * 128 + cbase + hi5 * 8);
      f32x16 z = {};
      f32x16 s = __builtin_amdgcn_mfma_f32_32x32x16_bf16(ak, bq, z, 0, 0, 0);
      float p[16];
#pragma unroll
      for (int r = 0; r < 16; ++r) { p[r] = __expf(s[r] * 0.25f); lsum += p[r]; }
#pragma unroll
      for (int r = 0; r < 16; r += 2) {
        unsigned int pk = cvt_pk_bf16(p[r], p[r + 1]);
        int key = kt * 32 + (r & 3) + 8 * (r >> 2) + 4 * hi5;
        *(unsigned int*)&ps[wid][l31][key] = pk;
      }
    }
    lsum += __shfl_xor(lsum, 32);
    if (lane < 32) rsum[wid][lane] = 1.0f / lsum;
#pragma unroll
    for (int m = 0; m < 2; ++m) {
      f32x4 o = {};
#pragma unroll
      for (int k2 = 0; k2 < 8; ++k2) {
        bf16x8 pa = *(const bf16x8*)&ps[wid][m * 16 + l15][k2 * 32 + hi4 * 8];
        bf16x8 vb = *(const bf16x8*)&vt[l15][k2 * 32 + hi4 * 8];
        o = __builtin_amdgcn_mfma_f32_16x16x32_bf16(pa, vb, o, 0, 0, 0);
      }
      unsigned short* dst = v + (rbase + q0 + m * 16 + hi4 * 4) * 128 + cbase + l15;
#pragma unroll
      for (int j = 0; j < 4; ++j) {
        float inv = rsum[wid][m * 16 + hi4 * 4 + j];
        dst[(size_t)j * 128] = f2bf(o[j] * inv);
      }
    }
  }
}

// ---- attn2 over M=16 axis (bf16 in/out); scrambled write g=q*4+b ----
__global__ __launch_bounds__(128) void attn2_kernel(
    const unsigned short* __restrict__ xa, unsigned short* __restrict__ xr) {
  __shared__ float xas[16][128];
  int b = blockIdx.x >> 8, t = blockIdx.x & 255;
  int tid = threadIdx.x;
#pragma unroll
  for (int jj = 0; jj < 2; ++jj) {
    int idx = tid + (jj << 7);
    int r = idx >> 4, c8 = (idx & 15) * 8;
    ushortx8 vv = *(const ushortx8*)(xa + ((size_t)((b * 16 + r) * 256 + t)) * 128 + c8);
#pragma unroll
    for (int j = 0; j < 8; ++j) xas[r][c8 + j] = bf2f(vv[j]);
  }
  __syncthreads();
  int h = tid >> 4, q = tid & 15;
  float xq[16];
#pragma unroll
  for (int d = 0; d < 16; d++) xq[d] = xas[q][h * 16 + d];
  float sc[16];
  float mx = -1e30f;
#pragma unroll
  for (int k = 0; k < 16; k++) {
    float s = 0.f;
#pragma unroll
    for (int d = 0; d < 16; d++) s += xq[d] * xas[k][h * 16 + d];
    s *= 0.25f;
    sc[k] = s;
    mx = fmaxf(mx, s);
  }
  float den = 0.f;
#pragma unroll
  for (int k = 0; k < 16; k++) { sc[k] = __expf(sc[k] - mx); den += sc[k]; }
  float inv = 1.0f / den;
  float out[16] = {};
#pragma unroll
  for (int k = 0; k < 16; k++) {
    float w = sc[k];
#pragma unroll
    for (int d = 0; d < 16; d++) out[d] += w * xas[k][h * 16 + d];
  }
  int g = q * 4 + b;
  unsigned short* dstp = xr + ((size_t)(g * 256 + t)) * 128 + h * 16;
  ushortx8 r0;
#pragma unroll
  for (int j = 0; j < 8; ++j) r0[j] = f2bf(out[j] * inv);
  *(ushortx8*)dstp = r0;
#pragma unroll
  for (int j = 0; j < 8; ++j) r0[j] = f2bf(out[8 + j] * inv);
  *(ushortx8*)(dstp + 8) = r0;
}

extern "C" void kernel_launch(void* const* d_in, const int* in_sizes, int n_in,
                              void* d_out, int out_size, void* d_ws, size_t ws_size,
                              hipStream_t stream) {
  const float* x    = (const float*)d_in[0];
  const float* Wq   = (const float*)d_in[1];
  const float* bq   = (const float*)d_in[2];
  const float* Wk   = (const float*)d_in[3];
  const float* bk   = (const float*)d_in[4];
  const float* Wv   = (const float*)d_in[5];
  const float* bv   = (const float*)d_in[6];
  const float* Wo   = (const float*)d_in[7];
  const float* bo   = (const float*)d_in[8];
  const float* W1   = (const float*)d_in[9];
  const float* b1   = (const float*)d_in[10];
  const float* W2   = (const float*)d_in[11];
  const float* b2   = (const float*)d_in[12];
  const float* ln1g = (const float*)d_in[13];
  const float* ln1b = (const float*)d_in[14];
  const float* ln2g = (const float*)d_in[15];
  const float* ln2b = (const float*)d_in[16];
  const float* lnfg = (const float*)d_in[17];
  const float* lnfb = (const float*)d_in[18];

  // ws layout (24.76 MB), all bf16 activations:
  char* base = (char*)d_ws;
  unsigned short* CQb = (unsigned short*)base;                 // [0,4M)
  unsigned short* CKb = (unsigned short*)(base + (4u  << 20)); // [4,8)
  unsigned short* Qb  = (unsigned short*)(base + (8u  << 20)); // [8,12)
  unsigned short* Kb  = (unsigned short*)(base + (12u << 20)); // [12,16)
  unsigned short* Vb  = (unsigned short*)(base + (16u << 20)); // [16,20)  (attn1 out in-place)
  unsigned short* Ab  = (unsigned short*)(base + (20u << 20)); // [20,24)
  unsigned short* Mid = (unsigned short*)base;                 // [0,16) FFN hidden (CQ/CK/Q/K dead)
  unsigned short* Wb  = (unsigned short*)(base + (24u << 20)); // 768 KB
  float*          Bs  = (float*)(base + (24u << 20) + 786432); // 9.2 KB
  float*          Y   = (float*)d_out;

  wconv_kernel<<<192, 256, 0, stream>>>(Wq, Wk, Wv, Wo, W1, W2, Wb);
  bconv_kernel<<<9, 256, 0, stream>>>(bq, bk, bv, bo, b1, b2, Bs);
  lnconv_kernel<<<4096, 256, 0, stream>>>(x, ln1g, ln1b, Ab);  // layer-0 LN1 only

  for (int i = 0; i < 2; ++i) {
    const float* rin = i ? Y : x;
    const unsigned short* Wl = Wb + (size_t)i * 196608;
    const float* Bl = Bs + i * 1152;
    // QKV
    gemm_kernel<<<dim3(256, 3), 512, 0, stream>>>(Ab, 128, Wl, 128, Bl, 128,
        nullptr, nullptr, Qb, 128, (int)S_, 128, 0, nullptr, nullptr, 0);
    // context combine -> CQ, CK
    ctx_kernel<<<dim3(64, 2, 4), 128, 0, stream>>>(Qb, Kb, CQb, CKb);
    // T x T attention (writes bf16 in-place over Vb)
    attn1_kernel<<<512, 256, 0, stream>>>(CQb, CKb, Vb);
    // M attention with scramble -> Ab
    attn2_kernel<<<1024, 128, 0, stream>>>(Vb, Ab);
    // Wo + residual -> Y (raw) and Ab = LN2(Y) bf16
    gemm_kernel<<<dim3(256, 1), 512, 0, stream>>>(Ab, 128, Wl + 49152, 128, Bl + 384, 128,
        rin, Y, Ab, 128, 0, 128, 0, ln2g + i * 128, ln2b + i * 128, 1);
    // FFN W1 (4 chunks) -> Mid[16384,512] bf16, relu
    gemm_kernel<<<dim3(256, 4), 512, 0, stream>>>(Ab, 128, Wl + 65536, 128, Bl + 512, 128,
        nullptr, nullptr, Mid, 512, 128, 128, 1, nullptr, nullptr, 0);
    // FFN W2 (K=512) + residual -> Y ; fused next-LN
    if (i == 0) {
      gemm_kernel<<<dim3(256, 1), 512, 0, stream>>>(Mid, 512, Wl + 131072, 512, Bl + 1024, 128,
          Y, Y, Ab, 128, 0, 512, 0, ln1g + 128, ln1b + 128, 1);   // Ab = LN1_layer1(Y)
    } else {
      gemm_kernel<<<dim3(256, 1), 512, 0, stream>>>(Mid, 512, Wl + 131072, 512, Bl + 1024, 128,
          Y, Y, nullptr, 128, 0, 512, 0, lnfg, lnfb, 2);          // d_out = LN_f(Y)
    }
  }
}

// Round 8
// 274.248 us; speedup vs baseline: 3.3411x; 1.0015x over previous
//
#include <hip/hip_runtime.h>
#include <cstddef>
#include <cstdint>

// Shapes: B=4, M=16, T=256, D=128, H=8, CTX=16, L=2
static constexpr int D_ = 128;
static constexpr int NROW = 16384;               // B*M*T rows
static constexpr size_t S_ = (size_t)NROW * D_;  // elems per activation

typedef __attribute__((ext_vector_type(8))) short bf16x8;
typedef __attribute__((ext_vector_type(4))) float f32x4;
typedef __attribute__((ext_vector_type(16))) float f32x16;
typedef __attribute__((ext_vector_type(8))) unsigned short ushortx8;
typedef __attribute__((ext_vector_type(4))) unsigned short ushortx4;

__device__ __forceinline__ unsigned short f2bf(float f) {
  unsigned int u = __float_as_uint(f);
  u += 0x7fff + ((u >> 16) & 1);
  return (unsigned short)(u >> 16);
}
__device__ __forceinline__ float bf2f(unsigned short h) {
  return __uint_as_float(((unsigned int)h) << 16);
}
__device__ __forceinline__ unsigned int cvt_pk_bf16(float lo, float hi) {
  unsigned int r;
  asm volatile("v_cvt_pk_bf16_f32 %0, %1, %2" : "=v"(r) : "v"(lo), "v"(hi));
  return r;
}
__device__ __forceinline__ float wsum64(float s) {
#pragma unroll
  for (int off = 32; off >= 1; off >>= 1) s += __shfl_xor(s, off);
  return s;
}

// ---- fused LN stats + normalize + bf16 convert (layer-0 input only) ----
__global__ __launch_bounds__(256) void lnconv_kernel(
    const float* __restrict__ X, const float* __restrict__ g,
    const float* __restrict__ b, unsigned short* __restrict__ out) {
  int wid = threadIdx.x >> 6, lane = threadIdx.x & 63;
  int row = (blockIdx.x << 2) + wid;
  float2 xv = *(const float2*)(X + (size_t)row * D_ + lane * 2);
  float s = wsum64(xv.x + xv.y);
  float sq = wsum64(xv.x * xv.x + xv.y * xv.y);
  float mu = s * (1.0f / 128.0f);
  float var = sq * (1.0f / 128.0f) - mu * mu;
  float rstd = rsqrtf(var + 1e-6f);
  float2 gv = *(const float2*)(g + lane * 2);
  float2 bv = *(const float2*)(b + lane * 2);
  unsigned int lo = f2bf((xv.x - mu) * rstd * gv.x + bv.x);
  unsigned int hi = f2bf((xv.y - mu) * rstd * gv.y + bv.y);
  *(unsigned int*)(out + (size_t)row * D_ + lane * 2) = lo | (hi << 16);
}

// ---- weights fp32->bf16, packed per layer: [QKV(384x128)][Wo][W1][W2] ----
__global__ __launch_bounds__(256) void wconv_kernel(
    const float* __restrict__ Wq, const float* __restrict__ Wk,
    const float* __restrict__ Wv, const float* __restrict__ Wo,
    const float* __restrict__ W1, const float* __restrict__ W2,
    unsigned short* __restrict__ out) {
  size_t i = ((size_t)blockIdx.x * 256 + threadIdx.x) * 8;
  int layer = i >= 196608;
  size_t o = i - (size_t)layer * 196608;
  const float* src; size_t off;
  if      (o < 16384)  { src = Wq + layer * 16384; off = o; }
  else if (o < 32768)  { src = Wk + layer * 16384; off = o - 16384; }
  else if (o < 49152)  { src = Wv + layer * 16384; off = o - 32768; }
  else if (o < 65536)  { src = Wo + layer * 16384; off = o - 49152; }
  else if (o < 131072) { src = W1 + layer * 65536; off = o - 65536; }
  else                 { src = W2 + layer * 65536; off = o - 131072; }
  ushortx8 r;
#pragma unroll
  for (int j = 0; j < 8; j++) r[j] = f2bf(src[off + j]);
  *(ushortx8*)(out + i) = r;
}

// ---- pack biases fp32 per layer: [bq bk bv bo b1(512) b2] = 1152 floats ----
__global__ __launch_bounds__(256) void bconv_kernel(
    const float* __restrict__ bq, const float* __restrict__ bk,
    const float* __restrict__ bv, const float* __restrict__ bo,
    const float* __restrict__ b1, const float* __restrict__ b2,
    float* __restrict__ out) {
  int tid = threadIdx.x + blockIdx.x * 256;
  if (tid >= 2304) return;
  int layer = tid / 1152, o = tid % 1152;
  float v;
  if      (o < 128)  v = bq[layer * 128 + o];
  else if (o < 256)  v = bk[layer * 128 + o - 128];
  else if (o < 384)  v = bv[layer * 128 + o - 256];
  else if (o < 512)  v = bo[layer * 128 + o - 384];
  else if (o < 1024) v = b1[layer * 512 + o - 512];
  else               v = b2[layer * 128 + o - 1024];
  out[tid] = v;
}

// ---- bf16 MFMA GEMM v3 (templated tile): 512 thr / 8 waves.
// Block: 16*ROWW rows x E cols, E = NT*16*(8/ROWW). Wave: 16 rows x NT*16 cols.
// One dispatch per logical GEMM (no y-replication of A reads).
// qkvSplit: route col -> buffer Cb + (col>>7)*S_ (Q/K/V contiguous, ldc 128).
// lnMode (requires COLW==2): 1: Cf=raw fp32 AND Cb=LN'd bf16. 2: Cf=LN'd fp32.
template <int NT, int ROWW>
__global__ __launch_bounds__(512) void gemm_kernel(
    const unsigned short* __restrict__ A, int lda,
    const unsigned short* __restrict__ W, int ldw,
    const float* __restrict__ bias,
    const float* __restrict__ resid,
    float* __restrict__ Cf, unsigned short* __restrict__ Cb,
    int ldc, int K, int relu, int qkvSplit,
    const float* __restrict__ lnG, const float* __restrict__ lnB, int lnMode) {
  constexpr int COLW = 8 / ROWW;
  __shared__ float lnred[8][16][2];
  const int w = threadIdx.x >> 6;
  const int l = threadIdx.x & 63;
  const int rw = w / COLW, cw = w % COLW;
  const int r0 = blockIdx.x * (16 * ROWW) + rw * 16;
  const int c0 = cw * (NT * 16);
  const int lr = l & 15, lk = (l >> 4) * 8;
  f32x4 acc[NT] = {};
  const unsigned short* Ap = A + (size_t)(r0 + lr) * lda + lk;
  const unsigned short* Wp = W + (size_t)(c0 + lr) * ldw + lk;
  for (int kb = 0; kb < K; kb += 128) {
    bf16x8 aF[4];
    bf16x8 wF[4][NT];
#pragma unroll
    for (int kt = 0; kt < 4; ++kt) {
      int k0 = kb + kt * 32;
      aF[kt] = *(const bf16x8*)(Ap + k0);
#pragma unroll
      for (int n = 0; n < NT; ++n)
        wF[kt][n] = *(const bf16x8*)(Wp + (size_t)(n * 16) * ldw + k0);
    }
#pragma unroll
    for (int kt = 0; kt < 4; ++kt)
#pragma unroll
      for (int n = 0; n < NT; ++n)
        acc[n] = __builtin_amdgcn_mfma_f32_16x16x32_bf16(aF[kt], wF[kt][n], acc[n], 0, 0, 0);
  }
  const int rb = (l >> 4) * 4;
  // finalize: bias, relu, residual
#pragma unroll
  for (int n = 0; n < NT; ++n) {
    int col = c0 + n * 16 + lr;
    float bval = bias[col];
#pragma unroll
    for (int j = 0; j < 4; ++j) {
      float v = acc[n][j] + bval;
      if (relu) v = fmaxf(v, 0.f);
      if (resid) v += resid[(size_t)(r0 + rb + j) * 128 + col];
      acc[n][j] = v;
    }
  }
  if (lnMode == 0) {
    if (qkvSplit) {
#pragma unroll
      for (int n = 0; n < NT; ++n) {
        int col = c0 + n * 16 + lr;
        unsigned short* dst = Cb + (size_t)(col >> 7) * S_ + (col & 127);
#pragma unroll
        for (int j = 0; j < 4; ++j)
          dst[(size_t)(r0 + rb + j) * 128] = f2bf(acc[n][j]);
      }
    } else {
#pragma unroll
      for (int n = 0; n < NT; ++n) {
        int col = c0 + n * 16 + lr;
#pragma unroll
        for (int j = 0; j < 4; ++j) {
          size_t off = (size_t)(r0 + rb + j) * ldc + col;
          if (Cf) Cf[off] = acc[n][j];
          else Cb[off] = f2bf(acc[n][j]);
        }
      }
    }
  } else {
    // fused LayerNorm epilogue (COLW==2 only): row split across wave pair w^1
    float s[4] = {}, sq[4] = {};
#pragma unroll
    for (int n = 0; n < NT; ++n)
#pragma unroll
      for (int j = 0; j < 4; ++j) {
        s[j] += acc[n][j];
        sq[j] = fmaf(acc[n][j], acc[n][j], sq[j]);
      }
#pragma unroll
    for (int off = 1; off < 16; off <<= 1)
#pragma unroll
      for (int j = 0; j < 4; ++j) {
        s[j] += __shfl_xor(s[j], off);
        sq[j] += __shfl_xor(sq[j], off);
      }
    if (lr == 0) {
#pragma unroll
      for (int j = 0; j < 4; ++j) {
        lnred[w][rb + j][0] = s[j];
        lnred[w][rb + j][1] = sq[j];
      }
    }
    __syncthreads();
    float mu[4], rstd[4];
#pragma unroll
    for (int j = 0; j < 4; ++j) {
      float st = s[j] + lnred[w ^ 1][rb + j][0];
      float sqt = sq[j] + lnred[w ^ 1][rb + j][1];
      mu[j] = st * (1.0f / 128.0f);
      float var = sqt * (1.0f / 128.0f) - mu[j] * mu[j];
      rstd[j] = rsqrtf(var + 1e-6f);
    }
#pragma unroll
    for (int n = 0; n < NT; ++n) {
      int col = c0 + n * 16 + lr;
      float g = lnG[col], bb = lnB[col];
#pragma unroll
      for (int j = 0; j < 4; ++j) {
        int row = r0 + rb + j;
        float t = (acc[n][j] - mu[j]) * rstd[j] * g + bb;
        if (lnMode == 1) {
          Cf[(size_t)row * 128 + col] = acc[n][j];
          Cb[(size_t)row * 128 + col] = f2bf(t);
        } else {
          Cf[(size_t)row * 128 + col] = t;
        }
      }
    }
  }
}

// ---- context attention: per (bm, src, 64-query chunk); fp32 LDS window, 2 lanes/query ----
static constexpr int CTXLD = 130;  // even: b64-aligned float2, bank step 2 -> <=4-way
__global__ __launch_bounds__(128) void ctx_kernel(
    const unsigned short* __restrict__ qin, const unsigned short* __restrict__ kin,
    unsigned short* __restrict__ cqo, unsigned short* __restrict__ cko) {
  __shared__ float xs[79 * CTXLD];  // rows t0-15 .. t0+63, zero-filled pad
  const unsigned short* src = blockIdx.y ? kin : qin;
  unsigned short* dst = blockIdx.y ? cko : cqo;
  const size_t rbase = (size_t)blockIdx.x * 256;
  const int t0 = blockIdx.z * 64;
  const int tid = threadIdx.x;
#pragma unroll
  for (int it = 0; it < 10; ++it) {
    int idx = it * 128 + tid;
    int i = idx >> 4, c8 = (idx & 15) * 8;
    if (i < 79) {
      int rg = t0 - 15 + i;
      float f[8];
      if (rg >= 0) {
        ushortx8 wv = *(const ushortx8*)(src + (rbase + rg) * 128 + c8);
#pragma unroll
        for (int j = 0; j < 8; ++j) f[j] = bf2f(wv[j]);
      } else {
#pragma unroll
        for (int j = 0; j < 8; ++j) f[j] = 0.f;
      }
#pragma unroll
      for (int j = 0; j < 8; j += 2)
        *(float2*)&xs[i * CTXLD + c8 + j] = make_float2(f[j], f[j + 1]);
    }
  }
  __syncthreads();
  const int ql = tid >> 1, h = tid & 1;
  const int cb = h * 64;
  float ow[64];
#pragma unroll
  for (int c = 0; c < 64; c += 2) {
    float2 w = *(const float2*)&xs[(ql + 15) * CTXLD + cb + c];
    ow[c] = w.x; ow[c + 1] = w.y;
  }
  float p[16];
#pragma unroll
  for (int l = 0; l < 16; ++l) {
    const float* row = &xs[(ql + l) * CTXLD + cb];
    float d = 0.f;
#pragma unroll
    for (int c = 0; c < 64; c += 2) {
      float2 w = *(const float2*)(row + c);
      d = fmaf(ow[c], w.x, d);
      d = fmaf(ow[c + 1], w.y, d);
    }
    p[l] = d;
  }
  float den = 0.f;
#pragma unroll
  for (int l = 0; l < 16; ++l) {
    float sc = p[l] + __shfl_xor(p[l], 1);
    p[l] = __expf(sc * 0.08838834764831845f);
    den += p[l];
  }
  float o[64];
#pragma unroll
  for (int c = 0; c < 64; ++c) o[c] = 0.f;
#pragma unroll
  for (int l = 0; l < 16; ++l) {
    float pl = p[l];
    const float* row = &xs[(ql + l) * CTXLD + cb];
#pragma unroll
    for (int c = 0; c < 64; c += 2) {
      float2 w = *(const float2*)(row + c);
      o[c] = fmaf(pl, w.x, o[c]);
      o[c + 1] = fmaf(pl, w.y, o[c + 1]);
    }
  }
  float inv = 1.0f / den;
  unsigned short* op = dst + (rbase + t0 + ql) * 128 + cb;
#pragma unroll
  for (int c8 = 0; c8 < 8; ++c8) {
    ushortx8 r;
#pragma unroll
    for (int j = 0; j < 8; ++j) r[j] = f2bf(o[c8 * 8 + j] * inv);
    *(ushortx8*)(op + c8 * 8) = r;
  }
}

// ---- attn1 (MFMA): S^T = CK·CQ^T (32x32x16); P via LDS; O = P·V (16x16x32).
//      Writes bf16 IN-PLACE over V (block-exclusive (bm,h) slice). ----
static constexpr int PW = 272;
__global__ __launch_bounds__(256) void attn1_kernel(
    const unsigned short* __restrict__ cq, const unsigned short* __restrict__ ck,
    unsigned short* __restrict__ v) {
  __shared__ unsigned short vt[16][PW];
  __shared__ unsigned short ps[4][32][PW];
  __shared__ float rsum[4][32];
  const int bm = blockIdx.x >> 3, h = blockIdx.x & 7;
  const size_t rbase = (size_t)bm * 256;
  const int cbase = h * 16;
  const int tid = threadIdx.x;
  {
    ushortx8 v0 = *(const ushortx8*)(v + (rbase + tid) * 128 + cbase);
    ushortx8 v1 = *(const ushortx8*)(v + (rbase + tid) * 128 + cbase + 8);
#pragma unroll
    for (int d = 0; d < 8; ++d) { vt[d][tid] = v0[d]; vt[8 + d][tid] = v1[d]; }
  }
  __syncthreads();
  const int wid = tid >> 6, lane = tid & 63;
  const int l31 = lane & 31, l15 = lane & 15;
  const int hi5 = lane >> 5, hi4 = lane >> 4;
#pragma unroll
  for (int qt = 0; qt < 2; ++qt) {
    const int q0 = (wid * 2 + qt) * 32;
    bf16x8 bq = *(const bf16x8*)(cq + (rbase + q0 + l31) * 128 + cbase + hi5 * 8);
    float lsum = 0.f;
#pragma unroll
    for (int kt = 0; kt < 8; ++kt) {
      bf16x8 ak = *(const bf16x8*)(ck + (rbase + kt * 32 + l31) * 128 + cbase + hi5 * 8);
      f32x16 z = {};
      f32x16 s = __builtin_amdgcn_mfma_f32_32x32x16_bf16(ak, bq, z, 0, 0, 0);
      float p[16];
#pragma unroll
      for (int r = 0; r < 16; ++r) { p[r] = __expf(s[r] * 0.25f); lsum += p[r]; }
#pragma unroll
      for (int r = 0; r < 16; r += 2) {
        unsigned int pk = cvt_pk_bf16(p[r], p[r + 1]);
        int key = kt * 32 + (r & 3) + 8 * (r >> 2) + 4 * hi5;
        *(unsigned int*)&ps[wid][l31][key] = pk;
      }
    }
    lsum += __shfl_xor(lsum, 32);
    if (lane < 32) rsum[wid][lane] = 1.0f / lsum;
#pragma unroll
    for (int m = 0; m < 2; ++m) {
      f32x4 o = {};
#pragma unroll
      for (int k2 = 0; k2 < 8; ++k2) {
        bf16x8 pa = *(const bf16x8*)&ps[wid][m * 16 + l15][k2 * 32 + hi4 * 8];
        bf16x8 vb = *(const bf16x8*)&vt[l15][k2 * 32 + hi4 * 8];
        o = __builtin_amdgcn_mfma_f32_16x16x32_bf16(pa, vb, o, 0, 0, 0);
      }
      unsigned short* dst = v + (rbase + q0 + m * 16 + hi4 * 4) * 128 + cbase + l15;
#pragma unroll
      for (int j = 0; j < 4; ++j) {
        float inv = rsum[wid][m * 16 + hi4 * 4 + j];
        dst[(size_t)j * 128] = f2bf(o[j] * inv);
      }
    }
  }
}

// ---- attn2 over M=16 axis (bf16 in/out); scrambled write g=q*4+b ----
__global__ __launch_bounds__(128) void attn2_kernel(
    const unsigned short* __restrict__ xa, unsigned short* __restrict__ xr) {
  __shared__ float xas[16][128];
  int b = blockIdx.x >> 8, t = blockIdx.x & 255;
  int tid = threadIdx.x;
#pragma unroll
  for (int jj = 0; jj < 2; ++jj) {
    int idx = tid + (jj << 7);
    int r = idx >> 4, c8 = (idx & 15) * 8;
    ushortx8 vv = *(const ushortx8*)(xa + ((size_t)((b * 16 + r) * 256 + t)) * 128 + c8);
#pragma unroll
    for (int j = 0; j < 8; ++j) xas[r][c8 + j] = bf2f(vv[j]);
  }
  __syncthreads();
  int h = tid >> 4, q = tid & 15;
  float xq[16];
#pragma unroll
  for (int d = 0; d < 16; d++) xq[d] = xas[q][h * 16 + d];
  float sc[16];
  float mx = -1e30f;
#pragma unroll
  for (int k = 0; k < 16; k++) {
    float s = 0.f;
#pragma unroll
    for (int d = 0; d < 16; d++) s += xq[d] * xas[k][h * 16 + d];
    s *= 0.25f;
    sc[k] = s;
    mx = fmaxf(mx, s);
  }
  float den = 0.f;
#pragma unroll
  for (int k = 0; k < 16; k++) { sc[k] = __expf(sc[k] - mx); den += sc[k]; }
  float inv = 1.0f / den;
  float out[16] = {};
#pragma unroll
  for (int k = 0; k < 16; k++) {
    float w = sc[k];
#pragma unroll
    for (int d = 0; d < 16; d++) out[d] += w * xas[k][h * 16 + d];
  }
  int g = q * 4 + b;
  unsigned short* dstp = xr + ((size_t)(g * 256 + t)) * 128 + h * 16;
  ushortx8 r0;
#pragma unroll
  for (int j = 0; j < 8; ++j) r0[j] = f2bf(out[j] * inv);
  *(ushortx8*)dstp = r0;
#pragma unroll
  for (int j = 0; j < 8; ++j) r0[j] = f2bf(out[8 + j] * inv);
  *(ushortx8*)(dstp + 8) = r0;
}

extern "C" void kernel_launch(void* const* d_in, const int* in_sizes, int n_in,
                              void* d_out, int out_size, void* d_ws, size_t ws_size,
                              hipStream_t stream) {
  const float* x    = (const float*)d_in[0];
  const float* Wq   = (const float*)d_in[1];
  const float* bq   = (const float*)d_in[2];
  const float* Wk   = (const float*)d_in[3];
  const float* bk   = (const float*)d_in[4];
  const float* Wv   = (const float*)d_in[5];
  const float* bv   = (const float*)d_in[6];
  const float* Wo   = (const float*)d_in[7];
  const float* bo   = (const float*)d_in[8];
  const float* W1   = (const float*)d_in[9];
  const float* b1   = (const float*)d_in[10];
  const float* W2   = (const float*)d_in[11];
  const float* b2   = (const float*)d_in[12];
  const float* ln1g = (const float*)d_in[13];
  const float* ln1b = (const float*)d_in[14];
  const float* ln2g = (const float*)d_in[15];
  const float* ln2b = (const float*)d_in[16];
  const float* lnfg = (const float*)d_in[17];
  const float* lnfb = (const float*)d_in[18];

  // ws layout (24.76 MB), all bf16 activations:
  char* base = (char*)d_ws;
  unsigned short* CQb = (unsigned short*)base;                 // [0,4M)
  unsigned short* CKb = (unsigned short*)(base + (4u  << 20)); // [4,8)
  unsigned short* Qb  = (unsigned short*)(base + (8u  << 20)); // [8,12)  Q|K|V contiguous
  unsigned short* Kb  = (unsigned short*)(base + (12u << 20)); // [12,16)
  unsigned short* Vb  = (unsigned short*)(base + (16u << 20)); // [16,20)  (attn1 out in-place)
  unsigned short* Ab  = (unsigned short*)(base + (20u << 20)); // [20,24)
  unsigned short* Mid = (unsigned short*)base;                 // [0,16) FFN hidden (CQ/CK/Q/K dead)
  unsigned short* Wb  = (unsigned short*)(base + (24u << 20)); // 768 KB
  float*          Bs  = (float*)(base + (24u << 20) + 786432); // 9.2 KB
  float*          Y   = (float*)d_out;

  wconv_kernel<<<192, 256, 0, stream>>>(Wq, Wk, Wv, Wo, W1, W2, Wb);
  bconv_kernel<<<9, 256, 0, stream>>>(bq, bk, bv, bo, b1, b2, Bs);
  lnconv_kernel<<<4096, 256, 0, stream>>>(x, ln1g, ln1b, Ab);  // layer-0 LN1 only

  for (int i = 0; i < 2; ++i) {
    const float* rin = i ? Y : x;
    const unsigned short* Wl = Wb + (size_t)i * 196608;
    const float* Bl = Bs + i * 1152;
    // QKV: single 16384x384x128 GEMM, epilogue splits cols to Qb/Kb/Vb
    gemm_kernel<6, 2><<<512, 512, 0, stream>>>(Ab, 128, Wl, 128, Bl,
        nullptr, nullptr, Qb, 128, 128, 0, 1, nullptr, nullptr, 0);
    // context combine -> CQ, CK
    ctx_kernel<<<dim3(64, 2, 4), 128, 0, stream>>>(Qb, Kb, CQb, CKb);
    // T x T attention (writes bf16 in-place over Vb)
    attn1_kernel<<<512, 256, 0, stream>>>(CQb, CKb, Vb);
    // M attention with scramble -> Ab
    attn2_kernel<<<1024, 128, 0, stream>>>(Vb, Ab);
    // Wo + residual -> Y (raw) and Ab = LN2(Y) bf16
    gemm_kernel<4, 4><<<256, 512, 0, stream>>>(Ab, 128, Wl + 49152, 128, Bl + 384,
        rin, Y, Ab, 128, 128, 0, 0, ln2g + i * 128, ln2b + i * 128, 1);
    // FFN W1: single 16384x512x128 GEMM -> Mid bf16, relu
    gemm_kernel<8, 2><<<512, 512, 0, stream>>>(Ab, 128, Wl + 65536, 128, Bl + 512,
        nullptr, nullptr, Mid, 512, 128, 1, 0, nullptr, nullptr, 0);
    // FFN W2 (K=512) + residual -> Y ; fused next-LN
    if (i == 0) {
      gemm_kernel<4, 4><<<256, 512, 0, stream>>>(Mid, 512, Wl + 131072, 512, Bl + 1024,
          Y, Y, Ab, 128, 512, 0, 0, ln1g + 128, ln1b + 128, 1);   // Ab = LN1_layer1(Y)
    } else {
      gemm_kernel<4, 4><<<256, 512, 0, stream>>>(Mid, 512, Wl + 131072, 512, Bl + 1024,
          Y, Y, nullptr, 128, 512, 0, 0, lnfg, lnfb, 2);          // d_out = LN_f(Y)
    }
  }
}

// Round 9
// 228.668 us; speedup vs baseline: 4.0071x; 1.1993x over previous
//
#include <hip/hip_runtime.h>
#include <cstddef>
#include <cstdint>

// Shapes: B=4, M=16, T=256, D=128, H=8, CTX=16, L=2
static constexpr int D_ = 128;
static constexpr int NROW = 16384;               // B*M*T rows
static constexpr size_t S_ = (size_t)NROW * D_;  // elems per activation

typedef __attribute__((ext_vector_type(8))) short bf16x8;
typedef __attribute__((ext_vector_type(4))) float f32x4;
typedef __attribute__((ext_vector_type(16))) float f32x16;
typedef __attribute__((ext_vector_type(8))) unsigned short ushortx8;
typedef __attribute__((ext_vector_type(4))) unsigned short ushortx4;

__device__ __forceinline__ unsigned short f2bf(float f) {
  unsigned int u = __float_as_uint(f);
  u += 0x7fff + ((u >> 16) & 1);
  return (unsigned short)(u >> 16);
}
__device__ __forceinline__ float bf2f(unsigned short h) {
  return __uint_as_float(((unsigned int)h) << 16);
}
__device__ __forceinline__ unsigned int cvt_pk_bf16(float lo, float hi) {
  unsigned int r;
  asm volatile("v_cvt_pk_bf16_f32 %0, %1, %2" : "=v"(r) : "v"(lo), "v"(hi));
  return r;
}
__device__ __forceinline__ float wsum64(float s) {
#pragma unroll
  for (int off = 32; off >= 1; off >>= 1) s += __shfl_xor(s, off);
  return s;
}

// ---- fused LN stats + normalize + bf16 convert (layer-0 input only) ----
__global__ __launch_bounds__(256) void lnconv_kernel(
    const float* __restrict__ X, const float* __restrict__ g,
    const float* __restrict__ b, unsigned short* __restrict__ out) {
  int wid = threadIdx.x >> 6, lane = threadIdx.x & 63;
  int row = (blockIdx.x << 2) + wid;
  float2 xv = *(const float2*)(X + (size_t)row * D_ + lane * 2);
  float s = wsum64(xv.x + xv.y);
  float sq = wsum64(xv.x * xv.x + xv.y * xv.y);
  float mu = s * (1.0f / 128.0f);
  float var = sq * (1.0f / 128.0f) - mu * mu;
  float rstd = rsqrtf(var + 1e-6f);
  float2 gv = *(const float2*)(g + lane * 2);
  float2 bv = *(const float2*)(b + lane * 2);
  unsigned int lo = f2bf((xv.x - mu) * rstd * gv.x + bv.x);
  unsigned int hi = f2bf((xv.y - mu) * rstd * gv.y + bv.y);
  *(unsigned int*)(out + (size_t)row * D_ + lane * 2) = lo | (hi << 16);
}

// ---- weights fp32->bf16, packed per layer: [QKV(384x128)][Wo][W1][W2] ----
__global__ __launch_bounds__(256) void wconv_kernel(
    const float* __restrict__ Wq, const float* __restrict__ Wk,
    const float* __restrict__ Wv, const float* __restrict__ Wo,
    const float* __restrict__ W1, const float* __restrict__ W2,
    unsigned short* __restrict__ out) {
  size_t i = ((size_t)blockIdx.x * 256 + threadIdx.x) * 8;
  int layer = i >= 196608;
  size_t o = i - (size_t)layer * 196608;
  const float* src; size_t off;
  if      (o < 16384)  { src = Wq + layer * 16384; off = o; }
  else if (o < 32768)  { src = Wk + layer * 16384; off = o - 16384; }
  else if (o < 49152)  { src = Wv + layer * 16384; off = o - 32768; }
  else if (o < 65536)  { src = Wo + layer * 16384; off = o - 49152; }
  else if (o < 131072) { src = W1 + layer * 65536; off = o - 65536; }
  else                 { src = W2 + layer * 65536; off = o - 131072; }
  ushortx8 r;
#pragma unroll
  for (int j = 0; j < 8; j++) r[j] = f2bf(src[off + j]);
  *(ushortx8*)(out + i) = r;
}

// ---- pack biases fp32 per layer: [bq bk bv bo b1(512) b2] = 1152 floats ----
__global__ __launch_bounds__(256) void bconv_kernel(
    const float* __restrict__ bq, const float* __restrict__ bk,
    const float* __restrict__ bv, const float* __restrict__ bo,
    const float* __restrict__ b1, const float* __restrict__ b2,
    float* __restrict__ out) {
  int tid = threadIdx.x + blockIdx.x * 256;
  if (tid >= 2304) return;
  int layer = tid / 1152, o = tid % 1152;
  float v;
  if      (o < 128)  v = bq[layer * 128 + o];
  else if (o < 256)  v = bk[layer * 128 + o - 128];
  else if (o < 384)  v = bv[layer * 128 + o - 256];
  else if (o < 512)  v = bo[layer * 128 + o - 384];
  else if (o < 1024) v = b1[layer * 512 + o - 512];
  else               v = b2[layer * 128 + o - 1024];
  out[tid] = v;
}

// ---- bf16 MFMA GEMM (QKV only): block 32r x 384c, 8 waves 16r x 96c ----
template <int NT, int ROWW>
__global__ __launch_bounds__(512) void gemm_kernel(
    const unsigned short* __restrict__ A, int lda,
    const unsigned short* __restrict__ W, int ldw,
    const float* __restrict__ bias,
    unsigned short* __restrict__ Cb, int K) {
  constexpr int COLW = 8 / ROWW;
  const int w = threadIdx.x >> 6;
  const int l = threadIdx.x & 63;
  const int rw = w / COLW, cw = w % COLW;
  const int r0 = blockIdx.x * (16 * ROWW) + rw * 16;
  const int c0 = cw * (NT * 16);
  const int lr = l & 15, lk = (l >> 4) * 8;
  f32x4 acc[NT] = {};
  const unsigned short* Ap = A + (size_t)(r0 + lr) * lda + lk;
  const unsigned short* Wp = W + (size_t)(c0 + lr) * ldw + lk;
  for (int kb = 0; kb < K; kb += 128) {
    bf16x8 aF[4];
    bf16x8 wF[4][NT];
#pragma unroll
    for (int kt = 0; kt < 4; ++kt) {
      int k0 = kb + kt * 32;
      aF[kt] = *(const bf16x8*)(Ap + k0);
#pragma unroll
      for (int n = 0; n < NT; ++n)
        wF[kt][n] = *(const bf16x8*)(Wp + (size_t)(n * 16) * ldw + k0);
    }
#pragma unroll
    for (int kt = 0; kt < 4; ++kt)
#pragma unroll
      for (int n = 0; n < NT; ++n)
        acc[n] = __builtin_amdgcn_mfma_f32_16x16x32_bf16(aF[kt], wF[kt][n], acc[n], 0, 0, 0);
  }
  const int rb = (l >> 4) * 4;
#pragma unroll
  for (int n = 0; n < NT; ++n) {
    int col = c0 + n * 16 + lr;
    float bval = bias[col];
    unsigned short* dst = Cb + (size_t)(col >> 7) * S_ + (col & 127);
#pragma unroll
    for (int j = 0; j < 4; ++j)
      dst[(size_t)(r0 + rb + j) * 128] = f2bf(acc[n][j] + bval);
  }
}

// ---- fused half-layer: Wo + rin -> LN2 -> W1+relu -> W2 + resid -> next-LN ----
// Block: 64 rows, 8 waves (4 rowgroups x 2 colgroups of 64). H/Mid in LDS.
// finalMode 0: Yout=Ynew fp32, AbOut=LN_next(Ynew) bf16.  1: Yout=LN_f(Ynew) fp32.
static constexpr int LDH = 136;  // pad: stride 272B, 16B-aligned, 2-way banks only
__global__ __launch_bounds__(512) void ffn_kernel(
    const unsigned short* __restrict__ Abuf,  // attn2 out bf16
    const unsigned short* __restrict__ Wo_, const unsigned short* __restrict__ W1_,
    const unsigned short* __restrict__ W2_, const float* __restrict__ Bl,
    const float* __restrict__ rin,
    const float* __restrict__ ln2G, const float* __restrict__ ln2B,
    const float* __restrict__ lnxG, const float* __restrict__ lnxB,
    float* __restrict__ Yout, unsigned short* __restrict__ AbOut, int finalMode) {
  __shared__ unsigned short Hs[64][LDH];
  __shared__ unsigned short Mid[64][LDH];
  __shared__ float lnred[8][16][2];
  const int w = threadIdx.x >> 6, l = threadIdx.x & 63;
  const int rw = w >> 1, cw = w & 1;
  const int r0 = blockIdx.x * 64;
  const int c0 = cw * 64;
  const int lr = l & 15, lk = (l >> 4) * 8, rb = (l >> 4) * 4;
  const int rloc = rw * 16;  // wave's local row base

  // ---- Phase 1: Wo GEMM (K=128) + bo + rin -> yreg ----
  f32x4 acc[4] = {};
  {
    const unsigned short* Ap = Abuf + (size_t)(r0 + rloc + lr) * 128 + lk;
    const unsigned short* Wp = Wo_ + (size_t)(c0 + lr) * 128 + lk;
    bf16x8 aF[4], wF[4][4];
#pragma unroll
    for (int kt = 0; kt < 4; ++kt) {
      aF[kt] = *(const bf16x8*)(Ap + kt * 32);
#pragma unroll
      for (int n = 0; n < 4; ++n)
        wF[kt][n] = *(const bf16x8*)(Wp + (size_t)(n * 16) * 128 + kt * 32);
    }
#pragma unroll
    for (int kt = 0; kt < 4; ++kt)
#pragma unroll
      for (int n = 0; n < 4; ++n)
        acc[n] = __builtin_amdgcn_mfma_f32_16x16x32_bf16(aF[kt], wF[kt][n], acc[n], 0, 0, 0);
  }
  float yreg[4][4];
  const float* bo = Bl + 384;
#pragma unroll
  for (int n = 0; n < 4; ++n) {
    int col = c0 + n * 16 + lr;
    float bval = bo[col];
#pragma unroll
    for (int j = 0; j < 4; ++j)
      yreg[n][j] = acc[n][j] + bval + rin[(size_t)(r0 + rloc + rb + j) * 128 + col];
  }
  // ---- Phase 2: LN2 -> Hs ----
  {
    float s[4] = {}, sq[4] = {};
#pragma unroll
    for (int n = 0; n < 4; ++n)
#pragma unroll
      for (int j = 0; j < 4; ++j) { s[j] += yreg[n][j]; sq[j] = fmaf(yreg[n][j], yreg[n][j], sq[j]); }
#pragma unroll
    for (int off = 1; off < 16; off <<= 1)
#pragma unroll
      for (int j = 0; j < 4; ++j) { s[j] += __shfl_xor(s[j], off); sq[j] += __shfl_xor(sq[j], off); }
    if (lr == 0)
#pragma unroll
      for (int j = 0; j < 4; ++j) { lnred[w][rb + j][0] = s[j]; lnred[w][rb + j][1] = sq[j]; }
    __syncthreads();
#pragma unroll
    for (int n = 0; n < 4; ++n) {
      int col = c0 + n * 16 + lr;
      float g = ln2G[col], bb = ln2B[col];
#pragma unroll
      for (int j = 0; j < 4; ++j) {
        float st = s[j] + lnred[w ^ 1][rb + j][0];
        float sqt = sq[j] + lnred[w ^ 1][rb + j][1];
        float mu = st * (1.0f / 128.0f);
        float rstd = rsqrtf(sqt * (1.0f / 128.0f) - mu * mu + 1e-6f);
        Hs[rloc + rb + j][col] = f2bf((yreg[n][j] - mu) * rstd * g + bb);
      }
    }
  }
  __syncthreads();
  // ---- Phase 3: W1 chunks (relu) -> Mid ; W2 partial -> acc2 ----
  f32x4 acc2[4] = {};
#pragma unroll 1
  for (int c = 0; c < 4; ++c) {
    f32x4 accm[4] = {};
    {
      const unsigned short* Wp = W1_ + (size_t)(c * 128 + c0 + lr) * 128 + lk;
      bf16x8 aF[4], wF[4][4];
#pragma unroll
      for (int kt = 0; kt < 4; ++kt) {
        aF[kt] = *(const bf16x8*)&Hs[rloc + lr][kt * 32 + lk];
#pragma unroll
        for (int n = 0; n < 4; ++n)
          wF[kt][n] = *(const bf16x8*)(Wp + (size_t)(n * 16) * 128 + kt * 32);
      }
#pragma unroll
      for (int kt = 0; kt < 4; ++kt)
#pragma unroll
        for (int n = 0; n < 4; ++n)
          accm[n] = __builtin_amdgcn_mfma_f32_16x16x32_bf16(aF[kt], wF[kt][n], accm[n], 0, 0, 0);
    }
    const float* b1c = Bl + 512 + c * 128;
#pragma unroll
    for (int n = 0; n < 4; ++n) {
      int col = c0 + n * 16 + lr;
      float bval = b1c[col];
#pragma unroll
      for (int j = 0; j < 4; ++j)
        Mid[rloc + rb + j][col] = f2bf(fmaxf(accm[n][j] + bval, 0.f));
    }
    __syncthreads();
    {
      const unsigned short* Wp = W2_ + (size_t)(c0 + lr) * 512 + c * 128 + lk;
      bf16x8 aF[4], wF[4][4];
#pragma unroll
      for (int kt = 0; kt < 4; ++kt) {
        aF[kt] = *(const bf16x8*)&Mid[rloc + lr][kt * 32 + lk];
#pragma unroll
        for (int n = 0; n < 4; ++n)
          wF[kt][n] = *(const bf16x8*)(Wp + (size_t)(n * 16) * 512 + kt * 32);
      }
#pragma unroll
      for (int kt = 0; kt < 4; ++kt)
#pragma unroll
        for (int n = 0; n < 4; ++n)
          acc2[n] = __builtin_amdgcn_mfma_f32_16x16x32_bf16(aF[kt], wF[kt][n], acc2[n], 0, 0, 0);
    }
    __syncthreads();
  }
  // ---- Final: b2 + residual(yreg) -> LN-next ----
  const float* b2 = Bl + 1024;
  float vfin[4][4];
  float s[4] = {}, sq[4] = {};
#pragma unroll
  for (int n = 0; n < 4; ++n) {
    int col = c0 + n * 16 + lr;
    float bval = b2[col];
#pragma unroll
    for (int j = 0; j < 4; ++j) {
      float v = acc2[n][j] + bval + yreg[n][j];
      vfin[n][j] = v;
      s[j] += v;
      sq[j] = fmaf(v, v, sq[j]);
    }
  }
#pragma unroll
  for (int off = 1; off < 16; off <<= 1)
#pragma unroll
    for (int j = 0; j < 4; ++j) { s[j] += __shfl_xor(s[j], off); sq[j] += __shfl_xor(sq[j], off); }
  if (lr == 0)
#pragma unroll
    for (int j = 0; j < 4; ++j) { lnred[w][rb + j][0] = s[j]; lnred[w][rb + j][1] = sq[j]; }
  __syncthreads();
#pragma unroll
  for (int n = 0; n < 4; ++n) {
    int col = c0 + n * 16 + lr;
    float g = lnxG[col], bb = lnxB[col];
#pragma unroll
    for (int j = 0; j < 4; ++j) {
      int row = r0 + rloc + rb + j;
      float st = s[j] + lnred[w ^ 1][rb + j][0];
      float sqt = sq[j] + lnred[w ^ 1][rb + j][1];
      float mu = st * (1.0f / 128.0f);
      float rstd = rsqrtf(sqt * (1.0f / 128.0f) - mu * mu + 1e-6f);
      float t = (vfin[n][j] - mu) * rstd * g + bb;
      if (finalMode == 0) {
        Yout[(size_t)row * 128 + col] = vfin[n][j];
        AbOut[(size_t)row * 128 + col] = f2bf(t);
      } else {
        Yout[(size_t)row * 128 + col] = t;
      }
    }
  }
}

// ---- context attention: per (bm, src, 64-query chunk); fp32 LDS window, 2 lanes/query ----
static constexpr int CTXLD = 130;
__global__ __launch_bounds__(128) void ctx_kernel(
    const unsigned short* __restrict__ qin, const unsigned short* __restrict__ kin,
    unsigned short* __restrict__ cqo, unsigned short* __restrict__ cko) {
  __shared__ float xs[79 * CTXLD];
  const unsigned short* src = blockIdx.y ? kin : qin;
  unsigned short* dst = blockIdx.y ? cko : cqo;
  const size_t rbase = (size_t)blockIdx.x * 256;
  const int t0 = blockIdx.z * 64;
  const int tid = threadIdx.x;
#pragma unroll
  for (int it = 0; it < 10; ++it) {
    int idx = it * 128 + tid;
    int i = idx >> 4, c8 = (idx & 15) * 8;
    if (i < 79) {
      int rg = t0 - 15 + i;
      float f[8];
      if (rg >= 0) {
        ushortx8 wv = *(const ushortx8*)(src + (rbase + rg) * 128 + c8);
#pragma unroll
        for (int j = 0; j < 8; ++j) f[j] = bf2f(wv[j]);
      } else {
#pragma unroll
        for (int j = 0; j < 8; ++j) f[j] = 0.f;
      }
#pragma unroll
      for (int j = 0; j < 8; j += 2)
        *(float2*)&xs[i * CTXLD + c8 + j] = make_float2(f[j], f[j + 1]);
    }
  }
  __syncthreads();
  const int ql = tid >> 1, h = tid & 1;
  const int cb = h * 64;
  float ow[64];
#pragma unroll
  for (int c = 0; c < 64; c += 2) {
    float2 w = *(const float2*)&xs[(ql + 15) * CTXLD + cb + c];
    ow[c] = w.x; ow[c + 1] = w.y;
  }
  float p[16];
#pragma unroll
  for (int l = 0; l < 16; ++l) {
    const float* row = &xs[(ql + l) * CTXLD + cb];
    float d = 0.f;
#pragma unroll
    for (int c = 0; c < 64; c += 2) {
      float2 w = *(const float2*)(row + c);
      d = fmaf(ow[c], w.x, d);
      d = fmaf(ow[c + 1], w.y, d);
    }
    p[l] = d;
  }
  float den = 0.f;
#pragma unroll
  for (int l = 0; l < 16; ++l) {
    float sc = p[l] + __shfl_xor(p[l], 1);
    p[l] = __expf(sc * 0.08838834764831845f);
    den += p[l];
  }
  float o[64];
#pragma unroll
  for (int c = 0; c < 64; ++c) o[c] = 0.f;
#pragma unroll
  for (int l = 0; l < 16; ++l) {
    float pl = p[l];
    const float* row = &xs[(ql + l) * CTXLD + cb];
#pragma unroll
    for (int c = 0; c < 64; c += 2) {
      float2 w = *(const float2*)(row + c);
      o[c] = fmaf(pl, w.x, o[c]);
      o[c + 1] = fmaf(pl, w.y, o[c + 1]);
    }
  }
  float inv = 1.0f / den;
  unsigned short* op = dst + (rbase + t0 + ql) * 128 + cb;
#pragma unroll
  for (int c8 = 0; c8 < 8; ++c8) {
    ushortx8 r;
#pragma unroll
    for (int j = 0; j < 8; ++j) r[j] = f2bf(o[c8 * 8 + j] * inv);
    *(ushortx8*)(op + c8 * 8) = r;
  }
}

// ---- attn1 (MFMA): S^T = CK·CQ^T (32x32x16); P via LDS; O = P·V (16x16x32) ----
static constexpr int PW = 272;
__global__ __launch_bounds__(256) void attn1_kernel(
    const unsigned short* __restrict__ cq, const unsigned short* __restrict__ ck,
    unsigned short* __restrict__ v) {
  __shared__ unsigned short vt[16][PW];
  __shared__ unsigned short ps[4][32][PW];
  __shared__ float rsum[4][32];
  const int bm = blockIdx.x >> 3, h = blockIdx.x & 7;
  const size_t rbase = (size_t)bm * 256;
  const int cbase = h * 16;
  const int tid = threadIdx.x;
  {
    ushortx8 v0 = *(const ushortx8*)(v + (rbase + tid) * 128 + cbase);
    ushortx8 v1 = *(const ushortx8*)(v + (rbase + tid) * 128 + cbase + 8);
#pragma unroll
    for (int d = 0; d < 8; ++d) { vt[d][tid] = v0[d]; vt[8 + d][tid] = v1[d]; }
  }
  __syncthreads();
  const int wid = tid >> 6, lane = tid & 63;
  const int l31 = lane & 31, l15 = lane & 15;
  const int hi5 = lane >> 5, hi4 = lane >> 4;
#pragma unroll
  for (int qt = 0; qt < 2; ++qt) {
    const int q0 = (wid * 2 + qt) * 32;
    bf16x8 bq = *(const bf16x8*)(cq + (rbase + q0 + l31) * 128 + cbase + hi5 * 8);
    float lsum = 0.f;
#pragma unroll
    for (int kt = 0; kt < 8; ++kt) {
      bf16x8 ak = *(const bf16x8*)(ck + (rbase + kt * 32 + l31) * 128 + cbase + hi5 * 8);
      f32x16 z = {};
      f32x16 s = __builtin_amdgcn_mfma_f32_32x32x16_bf16(ak, bq, z, 0, 0, 0);
      float p[16];
#pragma unroll
      for (int r = 0; r < 16; ++r) { p[r] = __expf(s[r] * 0.25f); lsum += p[r]; }
#pragma unroll
      for (int r = 0; r < 16; r += 2) {
        unsigned int pk = cvt_pk_bf16(p[r], p[r + 1]);
        int key = kt * 32 + (r & 3) + 8 * (r >> 2) + 4 * hi5;
        *(unsigned int*)&ps[wid][l31][key] = pk;
      }
    }
    lsum += __shfl_xor(lsum, 32);
    if (lane < 32) rsum[wid][lane] = 1.0f / lsum;
#pragma unroll
    for (int m = 0; m < 2; ++m) {
      f32x4 o = {};
#pragma unroll
      for (int k2 = 0; k2 < 8; ++k2) {
        bf16x8 pa = *(const bf16x8*)&ps[wid][m * 16 + l15][k2 * 32 + hi4 * 8];
        bf16x8 vb = *(const bf16x8*)&vt[l15][k2 * 32 + hi4 * 8];
        o = __builtin_amdgcn_mfma_f32_16x16x32_bf16(pa, vb, o, 0, 0, 0);
      }
      unsigned short* dst = v + (rbase + q0 + m * 16 + hi4 * 4) * 128 + cbase + l15;
#pragma unroll
      for (int j = 0; j < 4; ++j) {
        float inv = rsum[wid][m * 16 + hi4 * 4 + j];
        dst[(size_t)j * 128] = f2bf(o[j] * inv);
      }
    }
  }
}

// ---- attn2 over M=16 axis (bf16 in/out); scrambled write g=q*4+b ----
__global__ __launch_bounds__(128) void attn2_kernel(
    const unsigned short* __restrict__ xa, unsigned short* __restrict__ xr) {
  __shared__ float xas[16][128];
  int b = blockIdx.x >> 8, t = blockIdx.x & 255;
  int tid = threadIdx.x;
#pragma unroll
  for (int jj = 0; jj < 2; ++jj) {
    int idx = tid + (jj << 7);
    int r = idx >> 4, c8 = (idx & 15) * 8;
    ushortx8 vv = *(const ushortx8*)(xa + ((size_t)((b * 16 + r) * 256 + t)) * 128 + c8);
#pragma unroll
    for (int j = 0; j < 8; ++j) xas[r][c8 + j] = bf2f(vv[j]);
  }
  __syncthreads();
  int h = tid >> 4, q = tid & 15;
  float xq[16];
#pragma unroll
  for (int d = 0; d < 16; d++) xq[d] = xas[q][h * 16 + d];
  float sc[16];
  float mx = -1e30f;
#pragma unroll
  for (int k = 0; k < 16; k++) {
    float s = 0.f;
#pragma unroll
    for (int d = 0; d < 16; d++) s += xq[d] * xas[k][h * 16 + d];
    s *= 0.25f;
    sc[k] = s;
    mx = fmaxf(mx, s);
  }
  float den = 0.f;
#pragma unroll
  for (int k = 0; k < 16; k++) { sc[k] = __expf(sc[k] - mx); den += sc[k]; }
  float inv = 1.0f / den;
  float out[16] = {};
#pragma unroll
  for (int k = 0; k < 16; k++) {
    float w = sc[k];
#pragma unroll
    for (int d = 0; d < 16; d++) out[d] += w * xas[k][h * 16 + d];
  }
  int g = q * 4 + b;
  unsigned short* dstp = xr + ((size_t)(g * 256 + t)) * 128 + h * 16;
  ushortx8 r0;
#pragma unroll
  for (int j = 0; j < 8; ++j) r0[j] = f2bf(out[j] * inv);
  *(ushortx8*)dstp = r0;
#pragma unroll
  for (int j = 0; j < 8; ++j) r0[j] = f2bf(out[8 + j] * inv);
  *(ushortx8*)(dstp + 8) = r0;
}

extern "C" void kernel_launch(void* const* d_in, const int* in_sizes, int n_in,
                              void* d_out, int out_size, void* d_ws, size_t ws_size,
                              hipStream_t stream) {
  const float* x    = (const float*)d_in[0];
  const float* Wq   = (const float*)d_in[1];
  const float* bq   = (const float*)d_in[2];
  const float* Wk   = (const float*)d_in[3];
  const float* bk   = (const float*)d_in[4];
  const float* Wv   = (const float*)d_in[5];
  const float* bv   = (const float*)d_in[6];
  const float* Wo   = (const float*)d_in[7];
  const float* bo   = (const float*)d_in[8];
  const float* W1   = (const float*)d_in[9];
  const float* b1   = (const float*)d_in[10];
  const float* W2   = (const float*)d_in[11];
  const float* b2   = (const float*)d_in[12];
  const float* ln1g = (const float*)d_in[13];
  const float* ln1b = (const float*)d_in[14];
  const float* ln2g = (const float*)d_in[15];
  const float* ln2b = (const float*)d_in[16];
  const float* lnfg = (const float*)d_in[17];
  const float* lnfb = (const float*)d_in[18];

  // ws layout (24.76 MB), all bf16 activations:
  char* base = (char*)d_ws;
  unsigned short* CQb = (unsigned short*)base;                 // [0,4M)
  unsigned short* CKb = (unsigned short*)(base + (4u  << 20)); // [4,8)
  unsigned short* Qb  = (unsigned short*)(base + (8u  << 20)); // [8,12)  Q|K|V contiguous
  unsigned short* Kb  = (unsigned short*)(base + (12u << 20)); // [12,16)
  unsigned short* Vb  = (unsigned short*)(base + (16u << 20)); // [16,20)  (attn1 out in-place)
  unsigned short* Ab  = (unsigned short*)(base + (20u << 20)); // [20,24)
  unsigned short* Wb  = (unsigned short*)(base + (24u << 20)); // 768 KB
  float*          Bs  = (float*)(base + (24u << 20) + 786432); // 9.2 KB
  float*          Y   = (float*)d_out;

  wconv_kernel<<<192, 256, 0, stream>>>(Wq, Wk, Wv, Wo, W1, W2, Wb);
  bconv_kernel<<<9, 256, 0, stream>>>(bq, bk, bv, bo, b1, b2, Bs);
  lnconv_kernel<<<4096, 256, 0, stream>>>(x, ln1g, ln1b, Ab);  // layer-0 LN1 only

  for (int i = 0; i < 2; ++i) {
    const float* rin = i ? Y : x;
    const unsigned short* Wl = Wb + (size_t)i * 196608;
    const float* Bl = Bs + i * 1152;
    // QKV: single 16384x384x128 GEMM, epilogue splits cols to Qb/Kb/Vb
    gemm_kernel<6, 2><<<512, 512, 0, stream>>>(Ab, 128, Wl, 128, Bl, Qb, 128);
    // context combine -> CQ, CK
    ctx_kernel<<<dim3(64, 2, 4), 128, 0, stream>>>(Qb, Kb, CQb, CKb);
    // T x T attention (writes bf16 in-place over Vb)
    attn1_kernel<<<512, 256, 0, stream>>>(CQb, CKb, Vb);
    // M attention with scramble -> Ab
    attn2_kernel<<<1024, 128, 0, stream>>>(Vb, Ab);
    // fused: Wo + rin -> LN2 -> W1+relu -> W2 + resid -> next-LN
    if (i == 0) {
      ffn_kernel<<<256, 512, 0, stream>>>(Ab, Wl + 49152, Wl + 65536, Wl + 131072, Bl,
          rin, ln2g, ln2b, ln1g + 128, ln1b + 128, Y, Ab, 0);
    } else {
      ffn_kernel<<<256, 512, 0, stream>>>(Ab, Wl + 49152, Wl + 65536, Wl + 131072, Bl,
          rin, ln2g + 128, ln2b + 128, lnfg, lnfb, Y, nullptr, 1);
    }
  }
}

// Round 10
// 187.720 us; speedup vs baseline: 4.8812x; 1.2181x over previous
//
#include <hip/hip_runtime.h>
#include <cstddef>
#include <cstdint>

// Shapes: B=4, M=16, T=256, D=128, H=8, CTX=16, L=2
static constexpr int D_ = 128;
static constexpr int NROW = 16384;               // B*M*T rows
static constexpr size_t S_ = (size_t)NROW * D_;  // elems per activation

typedef __attribute__((ext_vector_type(8))) short bf16x8;
typedef __attribute__((ext_vector_type(4))) float f32x4;
typedef __attribute__((ext_vector_type(16))) float f32x16;
typedef __attribute__((ext_vector_type(8))) unsigned short ushortx8;
typedef __attribute__((ext_vector_type(4))) unsigned short ushortx4;

__device__ __forceinline__ unsigned short f2bf(float f) {
  unsigned int u = __float_as_uint(f);
  u += 0x7fff + ((u >> 16) & 1);
  return (unsigned short)(u >> 16);
}
__device__ __forceinline__ float bf2f(unsigned short h) {
  return __uint_as_float(((unsigned int)h) << 16);
}
__device__ __forceinline__ unsigned int cvt_pk_bf16(float lo, float hi) {
  unsigned int r;
  asm volatile("v_cvt_pk_bf16_f32 %0, %1, %2" : "=v"(r) : "v"(lo), "v"(hi));
  return r;
}
__device__ __forceinline__ float wsum64(float s) {
#pragma unroll
  for (int off = 32; off >= 1; off >>= 1) s += __shfl_xor(s, off);
  return s;
}

// ---- fused LN stats + normalize + bf16 convert (layer-0 input only) ----
__global__ __launch_bounds__(256) void lnconv_kernel(
    const float* __restrict__ X, const float* __restrict__ g,
    const float* __restrict__ b, unsigned short* __restrict__ out) {
  int wid = threadIdx.x >> 6, lane = threadIdx.x & 63;
  int row = (blockIdx.x << 2) + wid;
  float2 xv = *(const float2*)(X + (size_t)row * D_ + lane * 2);
  float s = wsum64(xv.x + xv.y);
  float sq = wsum64(xv.x * xv.x + xv.y * xv.y);
  float mu = s * (1.0f / 128.0f);
  float var = sq * (1.0f / 128.0f) - mu * mu;
  float rstd = rsqrtf(var + 1e-6f);
  float2 gv = *(const float2*)(g + lane * 2);
  float2 bv = *(const float2*)(b + lane * 2);
  unsigned int lo = f2bf((xv.x - mu) * rstd * gv.x + bv.x);
  unsigned int hi = f2bf((xv.y - mu) * rstd * gv.y + bv.y);
  *(unsigned int*)(out + (size_t)row * D_ + lane * 2) = lo | (hi << 16);
}

// ---- weights fp32->bf16, packed per layer: [QKV(384x128)][Wo][W1][W2] ----
__global__ __launch_bounds__(256) void wconv_kernel(
    const float* __restrict__ Wq, const float* __restrict__ Wk,
    const float* __restrict__ Wv, const float* __restrict__ Wo,
    const float* __restrict__ W1, const float* __restrict__ W2,
    unsigned short* __restrict__ out) {
  size_t i = ((size_t)blockIdx.x * 256 + threadIdx.x) * 8;
  int layer = i >= 196608;
  size_t o = i - (size_t)layer * 196608;
  const float* src; size_t off;
  if      (o < 16384)  { src = Wq + layer * 16384; off = o; }
  else if (o < 32768)  { src = Wk + layer * 16384; off = o - 16384; }
  else if (o < 49152)  { src = Wv + layer * 16384; off = o - 32768; }
  else if (o < 65536)  { src = Wo + layer * 16384; off = o - 49152; }
  else if (o < 131072) { src = W1 + layer * 65536; off = o - 65536; }
  else                 { src = W2 + layer * 65536; off = o - 131072; }
  ushortx8 r;
#pragma unroll
  for (int j = 0; j < 8; j++) r[j] = f2bf(src[off + j]);
  *(ushortx8*)(out + i) = r;
}

// ---- pack biases fp32 per layer: [bq bk bv bo b1(512) b2] = 1152 floats ----
__global__ __launch_bounds__(256) void bconv_kernel(
    const float* __restrict__ bq, const float* __restrict__ bk,
    const float* __restrict__ bv, const float* __restrict__ bo,
    const float* __restrict__ b1, const float* __restrict__ b2,
    float* __restrict__ out) {
  int tid = threadIdx.x + blockIdx.x * 256;
  if (tid >= 2304) return;
  int layer = tid / 1152, o = tid % 1152;
  float v;
  if      (o < 128)  v = bq[layer * 128 + o];
  else if (o < 256)  v = bk[layer * 128 + o - 128];
  else if (o < 384)  v = bv[layer * 128 + o - 256];
  else if (o < 512)  v = bo[layer * 128 + o - 384];
  else if (o < 1024) v = b1[layer * 512 + o - 512];
  else               v = b2[layer * 128 + o - 1024];
  out[tid] = v;
}

// ---- bf16 MFMA GEMM (QKV): block 32r x 384c, 8 waves 16r x 96c ----
template <int NT, int ROWW>
__global__ __launch_bounds__(512, 2) void gemm_kernel(
    const unsigned short* __restrict__ A, int lda,
    const unsigned short* __restrict__ W, int ldw,
    const float* __restrict__ bias,
    unsigned short* __restrict__ Cb, int K) {
  constexpr int COLW = 8 / ROWW;
  const int w = threadIdx.x >> 6;
  const int l = threadIdx.x & 63;
  const int rw = w / COLW, cw = w % COLW;
  const int r0 = blockIdx.x * (16 * ROWW) + rw * 16;
  const int c0 = cw * (NT * 16);
  const int lr = l & 15, lk = (l >> 4) * 8;
  f32x4 acc[NT] = {};
  const unsigned short* Ap = A + (size_t)(r0 + lr) * lda + lk;
  const unsigned short* Wp = W + (size_t)(c0 + lr) * ldw + lk;
  for (int kb = 0; kb < K; kb += 128) {
    bf16x8 aF[4];
    bf16x8 wF[4][NT];
#pragma unroll
    for (int kt = 0; kt < 4; ++kt) {
      int k0 = kb + kt * 32;
      aF[kt] = *(const bf16x8*)(Ap + k0);
#pragma unroll
      for (int n = 0; n < NT; ++n)
        wF[kt][n] = *(const bf16x8*)(Wp + (size_t)(n * 16) * ldw + k0);
    }
#pragma unroll
    for (int kt = 0; kt < 4; ++kt)
#pragma unroll
      for (int n = 0; n < NT; ++n)
        acc[n] = __builtin_amdgcn_mfma_f32_16x16x32_bf16(aF[kt], wF[kt][n], acc[n], 0, 0, 0);
  }
  const int rb = (l >> 4) * 4;
#pragma unroll
  for (int n = 0; n < NT; ++n) {
    int col = c0 + n * 16 + lr;
    float bval = bias[col];
    unsigned short* dst = Cb + (size_t)(col >> 7) * S_ + (col & 127);
#pragma unroll
    for (int j = 0; j < 4; ++j)
      dst[(size_t)(r0 + rb + j) * 128] = f2bf(acc[n][j] + bval);
  }
}

// ---- fused half-layer v2: column-split waves (64r x 16c), LDS-staged A,
//      unique weight loads, software-pipelined W1/W2 chunks. ----
static constexpr int LDH = 136;
__global__ __launch_bounds__(512, 2) void ffn_kernel(
    const unsigned short* __restrict__ Abuf,
    const unsigned short* __restrict__ Wo_, const unsigned short* __restrict__ W1_,
    const unsigned short* __restrict__ W2_, const float* __restrict__ Bl,
    const float* __restrict__ rin,
    const float* __restrict__ ln2G, const float* __restrict__ ln2B,
    const float* __restrict__ lnxG, const float* __restrict__ lnxB,
    float* __restrict__ Yout, unsigned short* __restrict__ AbOut, int finalMode) {
  __shared__ unsigned short As[64][LDH];
  __shared__ unsigned short Hs[64][LDH];
  __shared__ unsigned short Mid[64][LDH];
  __shared__ float2 lnred[64][8];
  const int tid = threadIdx.x;
  const int w = tid >> 6, l = tid & 63;
  const int r0 = blockIdx.x * 64;
  const int lr = l & 15, lk = (l >> 4) * 8, rb = (l >> 4) * 4;
  const int col = w * 16 + lr;  // this lane's output column (all phases)

  // prologue: issue weight loads for Wo + chunk0 of W1/W2 (L2-hot, block-unique)
  bf16x8 wof[4], w1f[4], w2f[4];
#pragma unroll
  for (int kt = 0; kt < 4; ++kt) {
    wof[kt] = *(const bf16x8*)(Wo_ + (size_t)col * 128 + kt * 32 + lk);
    w1f[kt] = *(const bf16x8*)(W1_ + (size_t)col * 128 + kt * 32 + lk);
    w2f[kt] = *(const bf16x8*)(W2_ + (size_t)col * 512 + kt * 32 + lk);
  }
  // stage A (attn2 out, bf16) into LDS, coalesced
#pragma unroll
  for (int itr = 0; itr < 2; ++itr) {
    int idx = itr * 512 + tid;
    int r = idx >> 4, c8 = (idx & 15) * 8;
    *(ushortx8*)&As[r][c8] = *(const ushortx8*)(Abuf + (size_t)(r0 + r) * 128 + c8);
  }
  __syncthreads();

  // ---- Phase 1: Wo GEMM (K=128) + bo + rin -> yreg ----
  f32x4 acc1[4] = {};
#pragma unroll
  for (int kt = 0; kt < 4; ++kt)
#pragma unroll
    for (int m = 0; m < 4; ++m) {
      bf16x8 a = *(const bf16x8*)&As[m * 16 + lr][kt * 32 + lk];
      acc1[m] = __builtin_amdgcn_mfma_f32_16x16x32_bf16(a, wof[kt], acc1[m], 0, 0, 0);
    }
  float yreg[4][4];
  {
    float bval = Bl[384 + col];
#pragma unroll
    for (int m = 0; m < 4; ++m)
#pragma unroll
      for (int j = 0; j < 4; ++j)
        yreg[m][j] = acc1[m][j] + bval + rin[(size_t)(r0 + m * 16 + rb + j) * 128 + col];
  }
  // ---- Phase 2: LN2 (block-wide row stats) -> Hs ----
  {
    float s[4][4], sq[4][4];
#pragma unroll
    for (int m = 0; m < 4; ++m)
#pragma unroll
      for (int j = 0; j < 4; ++j) { s[m][j] = yreg[m][j]; sq[m][j] = yreg[m][j] * yreg[m][j]; }
#pragma unroll
    for (int off = 1; off < 16; off <<= 1)
#pragma unroll
      for (int m = 0; m < 4; ++m)
#pragma unroll
        for (int j = 0; j < 4; ++j) {
          s[m][j] += __shfl_xor(s[m][j], off);
          sq[m][j] += __shfl_xor(sq[m][j], off);
        }
    if (lr == 0)
#pragma unroll
      for (int m = 0; m < 4; ++m)
#pragma unroll
        for (int j = 0; j < 4; ++j)
          lnred[m * 16 + rb + j][w] = make_float2(s[m][j], sq[m][j]);
    __syncthreads();
    if (tid < 64) {
      float ts = 0.f, tq = 0.f;
#pragma unroll
      for (int k = 0; k < 8; ++k) { float2 p = lnred[tid][k]; ts += p.x; tq += p.y; }
      float mu = ts * (1.0f / 128.0f);
      float rstd = rsqrtf(tq * (1.0f / 128.0f) - mu * mu + 1e-6f);
      lnred[tid][0] = make_float2(mu, rstd);
    }
    __syncthreads();
    float g = ln2G[col], bb = ln2B[col];
#pragma unroll
    for (int m = 0; m < 4; ++m)
#pragma unroll
      for (int j = 0; j < 4; ++j) {
        float2 st = lnred[m * 16 + rb + j][0];
        Hs[m * 16 + rb + j][col] = f2bf((yreg[m][j] - st.x) * st.y * g + bb);
      }
  }
  __syncthreads();
  // ---- Phase 3: 4 chunks of W1(relu)->Mid->W2, next-chunk weights prefetched ----
  f32x4 acc2[4] = {};
#pragma unroll
  for (int c = 0; c < 4; ++c) {
    bf16x8 w1n[4], w2n[4];
    if (c < 3) {
#pragma unroll
      for (int kt = 0; kt < 4; ++kt) {
        w1n[kt] = *(const bf16x8*)(W1_ + (size_t)((c + 1) * 128 + col) * 128 + kt * 32 + lk);
        w2n[kt] = *(const bf16x8*)(W2_ + (size_t)col * 512 + (c + 1) * 128 + kt * 32 + lk);
      }
    }
    f32x4 accm[4] = {};
#pragma unroll
    for (int kt = 0; kt < 4; ++kt)
#pragma unroll
      for (int m = 0; m < 4; ++m) {
        bf16x8 a = *(const bf16x8*)&Hs[m * 16 + lr][kt * 32 + lk];
        accm[m] = __builtin_amdgcn_mfma_f32_16x16x32_bf16(a, w1f[kt], accm[m], 0, 0, 0);
      }
    float b1v = Bl[512 + c * 128 + col];
#pragma unroll
    for (int m = 0; m < 4; ++m)
#pragma unroll
      for (int j = 0; j < 4; ++j)
        Mid[m * 16 + rb + j][col] = f2bf(fmaxf(accm[m][j] + b1v, 0.f));
    __syncthreads();
#pragma unroll
    for (int kt = 0; kt < 4; ++kt)
#pragma unroll
      for (int m = 0; m < 4; ++m) {
        bf16x8 a = *(const bf16x8*)&Mid[m * 16 + lr][kt * 32 + lk];
        acc2[m] = __builtin_amdgcn_mfma_f32_16x16x32_bf16(a, w2f[kt], acc2[m], 0, 0, 0);
      }
    __syncthreads();
    if (c < 3) {
#pragma unroll
      for (int kt = 0; kt < 4; ++kt) { w1f[kt] = w1n[kt]; w2f[kt] = w2n[kt]; }
    }
  }
  // ---- Final: b2 + residual(yreg) -> next-LN -> write ----
  float vfin[4][4];
  {
    float bval = Bl[1024 + col];
    float s[4][4], sq[4][4];
#pragma unroll
    for (int m = 0; m < 4; ++m)
#pragma unroll
      for (int j = 0; j < 4; ++j) {
        float v = acc2[m][j] + bval + yreg[m][j];
        vfin[m][j] = v;
        s[m][j] = v;
        sq[m][j] = v * v;
      }
#pragma unroll
    for (int off = 1; off < 16; off <<= 1)
#pragma unroll
      for (int m = 0; m < 4; ++m)
#pragma unroll
        for (int j = 0; j < 4; ++j) {
          s[m][j] += __shfl_xor(s[m][j], off);
          sq[m][j] += __shfl_xor(sq[m][j], off);
        }
    if (lr == 0)
#pragma unroll
      for (int m = 0; m < 4; ++m)
#pragma unroll
        for (int j = 0; j < 4; ++j)
          lnred[m * 16 + rb + j][w] = make_float2(s[m][j], sq[m][j]);
    __syncthreads();
    if (tid < 64) {
      float ts = 0.f, tq = 0.f;
#pragma unroll
      for (int k = 0; k < 8; ++k) { float2 p = lnred[tid][k]; ts += p.x; tq += p.y; }
      float mu = ts * (1.0f / 128.0f);
      float rstd = rsqrtf(tq * (1.0f / 128.0f) - mu * mu + 1e-6f);
      lnred[tid][0] = make_float2(mu, rstd);
    }
    __syncthreads();
    float g = lnxG[col], bb = lnxB[col];
#pragma unroll
    for (int m = 0; m < 4; ++m)
#pragma unroll
      for (int j = 0; j < 4; ++j) {
        int row = r0 + m * 16 + rb + j;
        float2 st = lnred[m * 16 + rb + j][0];
        float t = (vfin[m][j] - st.x) * st.y * g + bb;
        if (finalMode == 0) {
          Yout[(size_t)row * 128 + col] = vfin[m][j];
          AbOut[(size_t)row * 128 + col] = f2bf(t);
        } else {
          Yout[(size_t)row * 128 + col] = t;
        }
      }
  }
}

// ---- context attention: per (bm, src, 64-query chunk); fp32 LDS window ----
static constexpr int CTXLD = 130;
__global__ __launch_bounds__(128) void ctx_kernel(
    const unsigned short* __restrict__ qin, const unsigned short* __restrict__ kin,
    unsigned short* __restrict__ cqo, unsigned short* __restrict__ cko) {
  __shared__ float xs[79 * CTXLD];
  const unsigned short* src = blockIdx.y ? kin : qin;
  unsigned short* dst = blockIdx.y ? cko : cqo;
  const size_t rbase = (size_t)blockIdx.x * 256;
  const int t0 = blockIdx.z * 64;
  const int tid = threadIdx.x;
#pragma unroll
  for (int it = 0; it < 10; ++it) {
    int idx = it * 128 + tid;
    int i = idx >> 4, c8 = (idx & 15) * 8;
    if (i < 79) {
      int rg = t0 - 15 + i;
      float f[8];
      if (rg >= 0) {
        ushortx8 wv = *(const ushortx8*)(src + (rbase + rg) * 128 + c8);
#pragma unroll
        for (int j = 0; j < 8; ++j) f[j] = bf2f(wv[j]);
      } else {
#pragma unroll
        for (int j = 0; j < 8; ++j) f[j] = 0.f;
      }
#pragma unroll
      for (int j = 0; j < 8; j += 2)
        *(float2*)&xs[i * CTXLD + c8 + j] = make_float2(f[j], f[j + 1]);
    }
  }
  __syncthreads();
  const int ql = tid >> 1, h = tid & 1;
  const int cb = h * 64;
  float ow[64];
#pragma unroll
  for (int c = 0; c < 64; c += 2) {
    float2 w = *(const float2*)&xs[(ql + 15) * CTXLD + cb + c];
    ow[c] = w.x; ow[c + 1] = w.y;
  }
  float p[16];
#pragma unroll
  for (int l = 0; l < 16; ++l) {
    const float* row = &xs[(ql + l) * CTXLD + cb];
    float d = 0.f;
#pragma unroll
    for (int c = 0; c < 64; c += 2) {
      float2 w = *(const float2*)(row + c);
      d = fmaf(ow[c], w.x, d);
      d = fmaf(ow[c + 1], w.y, d);
    }
    p[l] = d;
  }
  float den = 0.f;
#pragma unroll
  for (int l = 0; l < 16; ++l) {
    float sc = p[l] + __shfl_xor(p[l], 1);
    p[l] = __expf(sc * 0.08838834764831845f);
    den += p[l];
  }
  float o[64];
#pragma unroll
  for (int c = 0; c < 64; ++c) o[c] = 0.f;
#pragma unroll
  for (int l = 0; l < 16; ++l) {
    float pl = p[l];
    const float* row = &xs[(ql + l) * CTXLD + cb];
#pragma unroll
    for (int c = 0; c < 64; c += 2) {
      float2 w = *(const float2*)(row + c);
      o[c] = fmaf(pl, w.x, o[c]);
      o[c + 1] = fmaf(pl, w.y, o[c + 1]);
    }
  }
  float inv = 1.0f / den;
  unsigned short* op = dst + (rbase + t0 + ql) * 128 + cb;
#pragma unroll
  for (int c8 = 0; c8 < 8; ++c8) {
    ushortx8 r;
#pragma unroll
    for (int j = 0; j < 8; ++j) r[j] = f2bf(o[c8 * 8 + j] * inv);
    *(ushortx8*)(op + c8 * 8) = r;
  }
}

// ---- attn1 (MFMA): S^T = CK·CQ^T (32x32x16); P via LDS; O = P·V (16x16x32) ----
static constexpr int PW = 272;
__global__ __launch_bounds__(256) void attn1_kernel(
    const unsigned short* __restrict__ cq, const unsigned short* __restrict__ ck,
    unsigned short* __restrict__ v) {
  __shared__ unsigned short vt[16][PW];
  __shared__ unsigned short ps[4][32][PW];
  __shared__ float rsum[4][32];
  const int bm = blockIdx.x >> 3, h = blockIdx.x & 7;
  const size_t rbase = (size_t)bm * 256;
  const int cbase = h * 16;
  const int tid = threadIdx.x;
  {
    ushortx8 v0 = *(const ushortx8*)(v + (rbase + tid) * 128 + cbase);
    ushortx8 v1 = *(const ushortx8*)(v + (rbase + tid) * 128 + cbase + 8);
#pragma unroll
    for (int d = 0; d < 8; ++d) { vt[d][tid] = v0[d]; vt[8 + d][tid] = v1[d]; }
  }
  __syncthreads();
  const int wid = tid >> 6, lane = tid & 63;
  const int l31 = lane & 31, l15 = lane & 15;
  const int hi5 = lane >> 5, hi4 = lane >> 4;
#pragma unroll
  for (int qt = 0; qt < 2; ++qt) {
    const int q0 = (wid * 2 + qt) * 32;
    bf16x8 bq = *(const bf16x8*)(cq + (rbase + q0 + l31) * 128 + cbase + hi5 * 8);
    float lsum = 0.f;
#pragma unroll
    for (int kt = 0; kt < 8; ++kt) {
      bf16x8 ak = *(const bf16x8*)(ck + (rbase + kt * 32 + l31) * 128 + cbase + hi5 * 8);
      f32x16 z = {};
      f32x16 s = __builtin_amdgcn_mfma_f32_32x32x16_bf16(ak, bq, z, 0, 0, 0);
      float p[16];
#pragma unroll
      for (int r = 0; r < 16; ++r) { p[r] = __expf(s[r] * 0.25f); lsum += p[r]; }
#pragma unroll
      for (int r = 0; r < 16; r += 2) {
        unsigned int pk = cvt_pk_bf16(p[r], p[r + 1]);
        int key = kt * 32 + (r & 3) + 8 * (r >> 2) + 4 * hi5;
        *(unsigned int*)&ps[wid][l31][key] = pk;
      }
    }
    lsum += __shfl_xor(lsum, 32);
    if (lane < 32) rsum[wid][lane] = 1.0f / lsum;
#pragma unroll
    for (int m = 0; m < 2; ++m) {
      f32x4 o = {};
#pragma unroll
      for (int k2 = 0; k2 < 8; ++k2) {
        bf16x8 pa = *(const bf16x8*)&ps[wid][m * 16 + l15][k2 * 32 + hi4 * 8];
        bf16x8 vb = *(const bf16x8*)&vt[l15][k2 * 32 + hi4 * 8];
        o = __builtin_amdgcn_mfma_f32_16x16x32_bf16(pa, vb, o, 0, 0, 0);
      }
      unsigned short* dst = v + (rbase + q0 + m * 16 + hi4 * 4) * 128 + cbase + l15;
#pragma unroll
      for (int j = 0; j < 4; ++j) {
        float inv = rsum[wid][m * 16 + hi4 * 4 + j];
        dst[(size_t)j * 128] = f2bf(o[j] * inv);
      }
    }
  }
}

// ---- attn2 over M=16 axis (bf16 in/out); scrambled write g=q*4+b ----
__global__ __launch_bounds__(128) void attn2_kernel(
    const unsigned short* __restrict__ xa, unsigned short* __restrict__ xr) {
  __shared__ float xas[16][128];
  int b = blockIdx.x >> 8, t = blockIdx.x & 255;
  int tid = threadIdx.x;
#pragma unroll
  for (int jj = 0; jj < 2; ++jj) {
    int idx = tid + (jj << 7);
    int r = idx >> 4, c8 = (idx & 15) * 8;
    ushortx8 vv = *(const ushortx8*)(xa + ((size_t)((b * 16 + r) * 256 + t)) * 128 + c8);
#pragma unroll
    for (int j = 0; j < 8; ++j) xas[r][c8 + j] = bf2f(vv[j]);
  }
  __syncthreads();
  int h = tid >> 4, q = tid & 15;
  float xq[16];
#pragma unroll
  for (int d = 0; d < 16; d++) xq[d] = xas[q][h * 16 + d];
  float sc[16];
  float mx = -1e30f;
#pragma unroll
  for (int k = 0; k < 16; k++) {
    float s = 0.f;
#pragma unroll
    for (int d = 0; d < 16; d++) s += xq[d] * xas[k][h * 16 + d];
    s *= 0.25f;
    sc[k] = s;
    mx = fmaxf(mx, s);
  }
  float den = 0.f;
#pragma unroll
  for (int k = 0; k < 16; k++) { sc[k] = __expf(sc[k] - mx); den += sc[k]; }
  float inv = 1.0f / den;
  float out[16] = {};
#pragma unroll
  for (int k = 0; k < 16; k++) {
    float w = sc[k];
#pragma unroll
    for (int d = 0; d < 16; d++) out[d] += w * xas[k][h * 16 + d];
  }
  int g = q * 4 + b;
  unsigned short* dstp = xr + ((size_t)(g * 256 + t)) * 128 + h * 16;
  ushortx8 r0;
#pragma unroll
  for (int j = 0; j < 8; ++j) r0[j] = f2bf(out[j] * inv);
  *(ushortx8*)dstp = r0;
#pragma unroll
  for (int j = 0; j < 8; ++j) r0[j] = f2bf(out[8 + j] * inv);
  *(ushortx8*)(dstp + 8) = r0;
}

extern "C" void kernel_launch(void* const* d_in, const int* in_sizes, int n_in,
                              void* d_out, int out_size, void* d_ws, size_t ws_size,
                              hipStream_t stream) {
  const float* x    = (const float*)d_in[0];
  const float* Wq   = (const float*)d_in[1];
  const float* bq   = (const float*)d_in[2];
  const float* Wk   = (const float*)d_in[3];
  const float* bk   = (const float*)d_in[4];
  const float* Wv   = (const float*)d_in[5];
  const float* bv   = (const float*)d_in[6];
  const float* Wo   = (const float*)d_in[7];
  const float* bo   = (const float*)d_in[8];
  const float* W1   = (const float*)d_in[9];
  const float* b1   = (const float*)d_in[10];
  const float* W2   = (const float*)d_in[11];
  const float* b2   = (const float*)d_in[12];
  const float* ln1g = (const float*)d_in[13];
  const float* ln1b = (const float*)d_in[14];
  const float* ln2g = (const float*)d_in[15];
  const float* ln2b = (const float*)d_in[16];
  const float* lnfg = (const float*)d_in[17];
  const float* lnfb = (const float*)d_in[18];

  // ws layout (24.76 MB), all bf16 activations:
  char* base = (char*)d_ws;
  unsigned short* CQb = (unsigned short*)base;                 // [0,4M)
  unsigned short* CKb = (unsigned short*)(base + (4u  << 20)); // [4,8)
  unsigned short* Qb  = (unsigned short*)(base + (8u  << 20)); // [8,12)  Q|K|V contiguous
  unsigned short* Kb  = (unsigned short*)(base + (12u << 20)); // [12,16)
  unsigned short* Vb  = (unsigned short*)(base + (16u << 20)); // [16,20)  (attn1 out in-place)
  unsigned short* Ab  = (unsigned short*)(base + (20u << 20)); // [20,24)
  unsigned short* Wb  = (unsigned short*)(base + (24u << 20)); // 768 KB
  float*          Bs  = (float*)(base + (24u << 20) + 786432); // 9.2 KB
  float*          Y   = (float*)d_out;

  wconv_kernel<<<192, 256, 0, stream>>>(Wq, Wk, Wv, Wo, W1, W2, Wb);
  bconv_kernel<<<9, 256, 0, stream>>>(bq, bk, bv, bo, b1, b2, Bs);
  lnconv_kernel<<<4096, 256, 0, stream>>>(x, ln1g, ln1b, Ab);  // layer-0 LN1 only

  for (int i = 0; i < 2; ++i) {
    const float* rin = i ? Y : x;
    const unsigned short* Wl = Wb + (size_t)i * 196608;
    const float* Bl = Bs + i * 1152;
    // QKV: single 16384x384x128 GEMM, epilogue splits cols to Qb/Kb/Vb
    gemm_kernel<6, 2><<<512, 512, 0, stream>>>(Ab, 128, Wl, 128, Bl, Qb, 128);
    // context combine -> CQ, CK
    ctx_kernel<<<dim3(64, 2, 4), 128, 0, stream>>>(Qb, Kb, CQb, CKb);
    // T x T attention (writes bf16 in-place over Vb)
    attn1_kernel<<<512, 256, 0, stream>>>(CQb, CKb, Vb);
    // M attention with scramble -> Ab
    attn2_kernel<<<1024, 128, 0, stream>>>(Vb, Ab);
    // fused: Wo + rin -> LN2 -> W1+relu -> W2 + resid -> next-LN
    if (i == 0) {
      ffn_kernel<<<256, 512, 0, stream>>>(Ab, Wl + 49152, Wl + 65536, Wl + 131072, Bl,
          rin, ln2g, ln2b, ln1g + 128, ln1b + 128, Y, Ab, 0);
    } else {
      ffn_kernel<<<256, 512, 0, stream>>>(Ab, Wl + 49152, Wl + 65536, Wl + 131072, Bl,
          rin, ln2g + 128, ln2b + 128, lnfg, lnfb, Y, nullptr, 1);
    }
  }
}

// Round 11
// 186.935 us; speedup vs baseline: 4.9017x; 1.0042x over previous
//
#include <hip/hip_runtime.h>
#include <cstddef>
#include <cstdint>

// Shapes: B=4, M=16, T=256, D=128, H=8, CTX=16, L=2
static constexpr int D_ = 128;
static constexpr int NROW = 16384;               // B*M*T rows
static constexpr size_t S_ = (size_t)NROW * D_;  // elems per activation

typedef __attribute__((ext_vector_type(8))) short bf16x8;
typedef __attribute__((ext_vector_type(4))) float f32x4;
typedef __attribute__((ext_vector_type(16))) float f32x16;
typedef __attribute__((ext_vector_type(8))) unsigned short ushortx8;

__device__ __forceinline__ unsigned short f2bf(float f) {
  unsigned int u = __float_as_uint(f);
  u += 0x7fff + ((u >> 16) & 1);
  return (unsigned short)(u >> 16);
}
__device__ __forceinline__ float bf2f(unsigned short h) {
  return __uint_as_float(((unsigned int)h) << 16);
}
__device__ __forceinline__ unsigned int cvt_pk_bf16(float lo, float hi) {
  unsigned int r;
  asm volatile("v_cvt_pk_bf16_f32 %0, %1, %2" : "=v"(r) : "v"(lo), "v"(hi));
  return r;
}
__device__ __forceinline__ float wsum64(float s) {
#pragma unroll
  for (int off = 32; off >= 1; off >>= 1) s += __shfl_xor(s, off);
  return s;
}

// ---- prep: [0,192) wconv | [192,201) bconv | [201,4297) lnconv(x, layer-0) ----
__global__ __launch_bounds__(256) void prep_kernel(
    const float* __restrict__ X,
    const float* __restrict__ Wq, const float* __restrict__ Wk,
    const float* __restrict__ Wv, const float* __restrict__ Wo,
    const float* __restrict__ W1, const float* __restrict__ W2,
    const float* __restrict__ bq, const float* __restrict__ bk,
    const float* __restrict__ bv, const float* __restrict__ bo,
    const float* __restrict__ b1, const float* __restrict__ b2,
    const float* __restrict__ g, const float* __restrict__ b,
    unsigned short* __restrict__ Wb, float* __restrict__ Bs,
    unsigned short* __restrict__ Ab) {
  int bx = blockIdx.x;
  if (bx < 192) {  // weights fp32->bf16, packed per layer [QKV|Wo|W1|W2]
    size_t i = ((size_t)bx * 256 + threadIdx.x) * 8;
    int layer = i >= 196608;
    size_t o = i - (size_t)layer * 196608;
    const float* src; size_t off;
    if      (o < 16384)  { src = Wq + layer * 16384; off = o; }
    else if (o < 32768)  { src = Wk + layer * 16384; off = o - 16384; }
    else if (o < 49152)  { src = Wv + layer * 16384; off = o - 32768; }
    else if (o < 65536)  { src = Wo + layer * 16384; off = o - 49152; }
    else if (o < 131072) { src = W1 + layer * 65536; off = o - 65536; }
    else                 { src = W2 + layer * 65536; off = o - 131072; }
    ushortx8 r;
#pragma unroll
    for (int j = 0; j < 8; j++) r[j] = f2bf(src[off + j]);
    *(ushortx8*)(Wb + i) = r;
  } else if (bx < 201) {  // biases packed per layer [bq bk bv bo b1 b2]
    int tid = (bx - 192) * 256 + threadIdx.x;
    if (tid >= 2304) return;
    int layer = tid / 1152, o = tid % 1152;
    float v;
    if      (o < 128)  v = bq[layer * 128 + o];
    else if (o < 256)  v = bk[layer * 128 + o - 128];
    else if (o < 384)  v = bv[layer * 128 + o - 256];
    else if (o < 512)  v = bo[layer * 128 + o - 384];
    else if (o < 1024) v = b1[layer * 512 + o - 512];
    else               v = b2[layer * 128 + o - 1024];
    Bs[tid] = v;
  } else {  // LN(x) -> bf16 Ab
    int wid = threadIdx.x >> 6, lane = threadIdx.x & 63;
    int row = ((bx - 201) << 2) + wid;
    float2 xv = *(const float2*)(X + (size_t)row * D_ + lane * 2);
    float s = wsum64(xv.x + xv.y);
    float sq = wsum64(xv.x * xv.x + xv.y * xv.y);
    float mu = s * (1.0f / 128.0f);
    float var = sq * (1.0f / 128.0f) - mu * mu;
    float rstd = rsqrtf(var + 1e-6f);
    float2 gv = *(const float2*)(g + lane * 2);
    float2 bv2 = *(const float2*)(b + lane * 2);
    unsigned int lo = f2bf((xv.x - mu) * rstd * gv.x + bv2.x);
    unsigned int hi = f2bf((xv.y - mu) * rstd * gv.y + bv2.y);
    *(unsigned int*)(Ab + (size_t)row * D_ + lane * 2) = lo | (hi << 16);
  }
}

// ---- bf16 MFMA GEMM (QKV): 16-row blocks, 8 col-waves, zero W redundancy ----
template <int NT, int ROWW>
__global__ __launch_bounds__(512, 2) void gemm_kernel(
    const unsigned short* __restrict__ A, int lda,
    const unsigned short* __restrict__ W, int ldw,
    const float* __restrict__ bias,
    unsigned short* __restrict__ Cb, int K) {
  constexpr int COLW = 8 / ROWW;
  const int w = threadIdx.x >> 6;
  const int l = threadIdx.x & 63;
  const int rw = w / COLW, cw = w % COLW;
  const int r0 = blockIdx.x * (16 * ROWW) + rw * 16;
  const int c0 = cw * (NT * 16);
  const int lr = l & 15, lk = (l >> 4) * 8;
  f32x4 acc[NT] = {};
  const unsigned short* Ap = A + (size_t)(r0 + lr) * lda + lk;
  const unsigned short* Wp = W + (size_t)(c0 + lr) * ldw + lk;
  for (int kb = 0; kb < K; kb += 128) {
    bf16x8 aF[4];
    bf16x8 wF[4][NT];
#pragma unroll
    for (int kt = 0; kt < 4; ++kt) {
      int k0 = kb + kt * 32;
      aF[kt] = *(const bf16x8*)(Ap + k0);
#pragma unroll
      for (int n = 0; n < NT; ++n)
        wF[kt][n] = *(const bf16x8*)(Wp + (size_t)(n * 16) * ldw + k0);
    }
#pragma unroll
    for (int kt = 0; kt < 4; ++kt)
#pragma unroll
      for (int n = 0; n < NT; ++n)
        acc[n] = __builtin_amdgcn_mfma_f32_16x16x32_bf16(aF[kt], wF[kt][n], acc[n], 0, 0, 0);
  }
  const int rb = (l >> 4) * 4;
#pragma unroll
  for (int n = 0; n < NT; ++n) {
    int col = c0 + n * 16 + lr;
    float bval = bias[col];
    unsigned short* dst = Cb + (size_t)(col >> 7) * S_ + (col & 127);
#pragma unroll
    for (int j = 0; j < 4; ++j)
      dst[(size_t)(r0 + rb + j) * 128] = f2bf(acc[n][j] + bval);
  }
}

// ---- fused half-layer: col-split waves, LDS-staged A, pipelined W1/W2 chunks ----
static constexpr int LDH = 136;
__global__ __launch_bounds__(512, 2) void ffn_kernel(
    const unsigned short* __restrict__ Abuf,
    const unsigned short* __restrict__ Wo_, const unsigned short* __restrict__ W1_,
    const unsigned short* __restrict__ W2_, const float* __restrict__ Bl,
    const float* __restrict__ rin,
    const float* __restrict__ ln2G, const float* __restrict__ ln2B,
    const float* __restrict__ lnxG, const float* __restrict__ lnxB,
    float* __restrict__ Yout, unsigned short* __restrict__ AbOut, int finalMode) {
  __shared__ unsigned short As[64][LDH];
  __shared__ unsigned short Hs[64][LDH];
  __shared__ unsigned short Mid[64][LDH];
  __shared__ float2 lnred[64][8];
  const int tid = threadIdx.x;
  const int w = tid >> 6, l = tid & 63;
  const int r0 = blockIdx.x * 64;
  const int lr = l & 15, lk = (l >> 4) * 8, rb = (l >> 4) * 4;
  const int col = w * 16 + lr;

  bf16x8 wof[4], w1f[4], w2f[4];
#pragma unroll
  for (int kt = 0; kt < 4; ++kt) {
    wof[kt] = *(const bf16x8*)(Wo_ + (size_t)col * 128 + kt * 32 + lk);
    w1f[kt] = *(const bf16x8*)(W1_ + (size_t)col * 128 + kt * 32 + lk);
    w2f[kt] = *(const bf16x8*)(W2_ + (size_t)col * 512 + kt * 32 + lk);
  }
#pragma unroll
  for (int itr = 0; itr < 2; ++itr) {
    int idx = itr * 512 + tid;
    int r = idx >> 4, c8 = (idx & 15) * 8;
    *(ushortx8*)&As[r][c8] = *(const ushortx8*)(Abuf + (size_t)(r0 + r) * 128 + c8);
  }
  __syncthreads();

  f32x4 acc1[4] = {};
#pragma unroll
  for (int kt = 0; kt < 4; ++kt)
#pragma unroll
    for (int m = 0; m < 4; ++m) {
      bf16x8 a = *(const bf16x8*)&As[m * 16 + lr][kt * 32 + lk];
      acc1[m] = __builtin_amdgcn_mfma_f32_16x16x32_bf16(a, wof[kt], acc1[m], 0, 0, 0);
    }
  float yreg[4][4];
  {
    float bval = Bl[384 + col];
#pragma unroll
    for (int m = 0; m < 4; ++m)
#pragma unroll
      for (int j = 0; j < 4; ++j)
        yreg[m][j] = acc1[m][j] + bval + rin[(size_t)(r0 + m * 16 + rb + j) * 128 + col];
  }
  {
    float s[4][4], sq[4][4];
#pragma unroll
    for (int m = 0; m < 4; ++m)
#pragma unroll
      for (int j = 0; j < 4; ++j) { s[m][j] = yreg[m][j]; sq[m][j] = yreg[m][j] * yreg[m][j]; }
#pragma unroll
    for (int off = 1; off < 16; off <<= 1)
#pragma unroll
      for (int m = 0; m < 4; ++m)
#pragma unroll
        for (int j = 0; j < 4; ++j) {
          s[m][j] += __shfl_xor(s[m][j], off);
          sq[m][j] += __shfl_xor(sq[m][j], off);
        }
    if (lr == 0)
#pragma unroll
      for (int m = 0; m < 4; ++m)
#pragma unroll
        for (int j = 0; j < 4; ++j)
          lnred[m * 16 + rb + j][w] = make_float2(s[m][j], sq[m][j]);
    __syncthreads();
    if (tid < 64) {
      float ts = 0.f, tq = 0.f;
#pragma unroll
      for (int k = 0; k < 8; ++k) { float2 p = lnred[tid][k]; ts += p.x; tq += p.y; }
      float mu = ts * (1.0f / 128.0f);
      float rstd = rsqrtf(tq * (1.0f / 128.0f) - mu * mu + 1e-6f);
      lnred[tid][0] = make_float2(mu, rstd);
    }
    __syncthreads();
    float g = ln2G[col], bb = ln2B[col];
#pragma unroll
    for (int m = 0; m < 4; ++m)
#pragma unroll
      for (int j = 0; j < 4; ++j) {
        float2 st = lnred[m * 16 + rb + j][0];
        Hs[m * 16 + rb + j][col] = f2bf((yreg[m][j] - st.x) * st.y * g + bb);
      }
  }
  __syncthreads();
  f32x4 acc2[4] = {};
#pragma unroll
  for (int c = 0; c < 4; ++c) {
    bf16x8 w1n[4], w2n[4];
    if (c < 3) {
#pragma unroll
      for (int kt = 0; kt < 4; ++kt) {
        w1n[kt] = *(const bf16x8*)(W1_ + (size_t)((c + 1) * 128 + col) * 128 + kt * 32 + lk);
        w2n[kt] = *(const bf16x8*)(W2_ + (size_t)col * 512 + (c + 1) * 128 + kt * 32 + lk);
      }
    }
    f32x4 accm[4] = {};
#pragma unroll
    for (int kt = 0; kt < 4; ++kt)
#pragma unroll
      for (int m = 0; m < 4; ++m) {
        bf16x8 a = *(const bf16x8*)&Hs[m * 16 + lr][kt * 32 + lk];
        accm[m] = __builtin_amdgcn_mfma_f32_16x16x32_bf16(a, w1f[kt], accm[m], 0, 0, 0);
      }
    float b1v = Bl[512 + c * 128 + col];
#pragma unroll
    for (int m = 0; m < 4; ++m)
#pragma unroll
      for (int j = 0; j < 4; ++j)
        Mid[m * 16 + rb + j][col] = f2bf(fmaxf(accm[m][j] + b1v, 0.f));
    __syncthreads();
#pragma unroll
    for (int kt = 0; kt < 4; ++kt)
#pragma unroll
      for (int m = 0; m < 4; ++m) {
        bf16x8 a = *(const bf16x8*)&Mid[m * 16 + lr][kt * 32 + lk];
        acc2[m] = __builtin_amdgcn_mfma_f32_16x16x32_bf16(a, w2f[kt], acc2[m], 0, 0, 0);
      }
    __syncthreads();
    if (c < 3) {
#pragma unroll
      for (int kt = 0; kt < 4; ++kt) { w1f[kt] = w1n[kt]; w2f[kt] = w2n[kt]; }
    }
  }
  float vfin[4][4];
  {
    float bval = Bl[1024 + col];
    float s[4][4], sq[4][4];
#pragma unroll
    for (int m = 0; m < 4; ++m)
#pragma unroll
      for (int j = 0; j < 4; ++j) {
        float v = acc2[m][j] + bval + yreg[m][j];
        vfin[m][j] = v;
        s[m][j] = v;
        sq[m][j] = v * v;
      }
#pragma unroll
    for (int off = 1; off < 16; off <<= 1)
#pragma unroll
      for (int m = 0; m < 4; ++m)
#pragma unroll
        for (int j = 0; j < 4; ++j) {
          s[m][j] += __shfl_xor(s[m][j], off);
          sq[m][j] += __shfl_xor(sq[m][j], off);
        }
    if (lr == 0)
#pragma unroll
      for (int m = 0; m < 4; ++m)
#pragma unroll
        for (int j = 0; j < 4; ++j)
          lnred[m * 16 + rb + j][w] = make_float2(s[m][j], sq[m][j]);
    __syncthreads();
    if (tid < 64) {
      float ts = 0.f, tq = 0.f;
#pragma unroll
      for (int k = 0; k < 8; ++k) { float2 p = lnred[tid][k]; ts += p.x; tq += p.y; }
      float mu = ts * (1.0f / 128.0f);
      float rstd = rsqrtf(tq * (1.0f / 128.0f) - mu * mu + 1e-6f);
      lnred[tid][0] = make_float2(mu, rstd);
    }
    __syncthreads();
    float g = lnxG[col], bb = lnxB[col];
#pragma unroll
    for (int m = 0; m < 4; ++m)
#pragma unroll
      for (int j = 0; j < 4; ++j) {
        int row = r0 + m * 16 + rb + j;
        float2 st = lnred[m * 16 + rb + j][0];
        float t = (vfin[m][j] - st.x) * st.y * g + bb;
        if (finalMode == 0) {
          Yout[(size_t)row * 128 + col] = vfin[m][j];
          AbOut[(size_t)row * 128 + col] = f2bf(t);
        } else {
          Yout[(size_t)row * 128 + col] = t;
        }
      }
  }
}

// ---- context attention v3: 32-query chunks, 4 lanes/query, skewed fp32 LDS ----
static constexpr int CTXLD = 134;  // row stride; +2-skew per 32-col group
__global__ __launch_bounds__(128) void ctx_kernel(
    const unsigned short* __restrict__ qin, const unsigned short* __restrict__ kin,
    unsigned short* __restrict__ cqo, unsigned short* __restrict__ cko) {
  __shared__ float xs[47 * CTXLD];  // rows t0-15 .. t0+31, zero-filled pad
  const unsigned short* src = blockIdx.y ? kin : qin;
  unsigned short* dst = blockIdx.y ? cko : cqo;
  const size_t rbase = (size_t)blockIdx.x * 256;
  const int t0 = blockIdx.z * 32;
  const int tid = threadIdx.x;
#pragma unroll
  for (int it = 0; it < 6; ++it) {
    int idx = it * 128 + tid;
    int i = idx >> 4, c8 = (idx & 15) * 8;
    if (i < 47) {
      int rg = t0 - 15 + i;
      float f[8];
      if (rg >= 0) {
        ushortx8 wv = *(const ushortx8*)(src + (rbase + rg) * 128 + c8);
#pragma unroll
        for (int j = 0; j < 8; ++j) f[j] = bf2f(wv[j]);
      } else {
#pragma unroll
        for (int j = 0; j < 8; ++j) f[j] = 0.f;
      }
      int base = i * CTXLD + c8 + (c8 >> 5) * 2;  // skew keeps float2 even
#pragma unroll
      for (int j = 0; j < 8; j += 2)
        *(float2*)&xs[base + j] = make_float2(f[j], f[j + 1]);
    }
  }
  __syncthreads();
  const int ql = tid >> 2, qu = tid & 3;
  const int cb = qu * 34;        // skewed base of this lane's 32-col quarter
  const int cg = qu * 32;        // true column base
  float ow[32];
#pragma unroll
  for (int c = 0; c < 32; c += 2) {
    float2 w = *(const float2*)&xs[(ql + 15) * CTXLD + cb + c];
    ow[c] = w.x; ow[c + 1] = w.y;
  }
  float p[16];
#pragma unroll
  for (int l = 0; l < 16; ++l) {
    const float* row = &xs[(ql + l) * CTXLD + cb];
    float d = 0.f;
#pragma unroll
    for (int c = 0; c < 32; c += 2) {
      float2 w = *(const float2*)(row + c);
      d = fmaf(ow[c], w.x, d);
      d = fmaf(ow[c + 1], w.y, d);
    }
    p[l] = d;
  }
  float den = 0.f;
#pragma unroll
  for (int l = 0; l < 16; ++l) {
    float sc = p[l] + __shfl_xor(p[l], 1);
    sc += __shfl_xor(sc, 2);                      // full 128-dot across 4 lanes
    p[l] = __expf(sc * 0.08838834764831845f);     // pad rows: exp(0)=1
    den += p[l];
  }
  float o[32];
#pragma unroll
  for (int c = 0; c < 32; ++c) o[c] = 0.f;
#pragma unroll
  for (int l = 0; l < 16; ++l) {
    float pl = p[l];
    const float* row = &xs[(ql + l) * CTXLD + cb];
#pragma unroll
    for (int c = 0; c < 32; c += 2) {
      float2 w = *(const float2*)(row + c);
      o[c] = fmaf(pl, w.x, o[c]);
      o[c + 1] = fmaf(pl, w.y, o[c + 1]);
    }
  }
  float inv = 1.0f / den;
  unsigned short* op = dst + (rbase + t0 + ql) * 128 + cg;
#pragma unroll
  for (int c8 = 0; c8 < 4; ++c8) {
    ushortx8 r;
#pragma unroll
    for (int j = 0; j < 8; ++j) r[j] = f2bf(o[c8 * 8 + j] * inv);
    *(ushortx8*)(op + c8 * 8) = r;
  }
}

// ---- attn1 (MFMA): S^T = CK·CQ^T (32x32x16); P via LDS; O = P·V (16x16x32) ----
static constexpr int PW = 272;
__global__ __launch_bounds__(256) void attn1_kernel(
    const unsigned short* __restrict__ cq, const unsigned short* __restrict__ ck,
    unsigned short* __restrict__ v) {
  __shared__ unsigned short vt[16][PW];
  __shared__ unsigned short ps[4][32][PW];
  __shared__ float rsum[4][32];
  const int bm = blockIdx.x >> 3, h = blockIdx.x & 7;
  const size_t rbase = (size_t)bm * 256;
  const int cbase = h * 16;
  const int tid = threadIdx.x;
  {
    ushortx8 v0 = *(const ushortx8*)(v + (rbase + tid) * 128 + cbase);
    ushortx8 v1 = *(const ushortx8*)(v + (rbase + tid) * 128 + cbase + 8);
#pragma unroll
    for (int d = 0; d < 8; ++d) { vt[d][tid] = v0[d]; vt[8 + d][tid] = v1[d]; }
  }
  __syncthreads();
  const int wid = tid >> 6, lane = tid & 63;
  const int l31 = lane & 31, l15 = lane & 15;
  const int hi5 = lane >> 5, hi4 = lane >> 4;
#pragma unroll
  for (int qt = 0; qt < 2; ++qt) {
    const int q0 = (wid * 2 + qt) * 32;
    bf16x8 bq = *(const bf16x8*)(cq + (rbase + q0 + l31) * 128 + cbase + hi5 * 8);
    float lsum = 0.f;
#pragma unroll
    for (int kt = 0; kt < 8; ++kt) {
      bf16x8 ak = *(const bf16x8*)(ck + (rbase + kt * 32 + l31) * 128 + cbase + hi5 * 8);
      f32x16 z = {};
      f32x16 s = __builtin_amdgcn_mfma_f32_32x32x16_bf16(ak, bq, z, 0, 0, 0);
      float p[16];
#pragma unroll
      for (int r = 0; r < 16; ++r) { p[r] = __expf(s[r] * 0.25f); lsum += p[r]; }
#pragma unroll
      for (int r = 0; r < 16; r += 2) {
        unsigned int pk = cvt_pk_bf16(p[r], p[r + 1]);
        int key = kt * 32 + (r & 3) + 8 * (r >> 2) + 4 * hi5;
        *(unsigned int*)&ps[wid][l31][key] = pk;
      }
    }
    lsum += __shfl_xor(lsum, 32);
    if (lane < 32) rsum[wid][lane] = 1.0f / lsum;
#pragma unroll
    for (int m = 0; m < 2; ++m) {
      f32x4 o = {};
#pragma unroll
      for (int k2 = 0; k2 < 8; ++k2) {
        bf16x8 pa = *(const bf16x8*)&ps[wid][m * 16 + l15][k2 * 32 + hi4 * 8];
        bf16x8 vb = *(const bf16x8*)&vt[l15][k2 * 32 + hi4 * 8];
        o = __builtin_amdgcn_mfma_f32_16x16x32_bf16(pa, vb, o, 0, 0, 0);
      }
      unsigned short* dst = v + (rbase + q0 + m * 16 + hi4 * 4) * 128 + cbase + l15;
#pragma unroll
      for (int j = 0; j < 4; ++j) {
        float inv = rsum[wid][m * 16 + hi4 * 4 + j];
        dst[(size_t)j * 128] = f2bf(o[j] * inv);
      }
    }
  }
}

// ---- attn2 over M=16 axis (bf16 in/out); scrambled write g=q*4+b ----
__global__ __launch_bounds__(128) void attn2_kernel(
    const unsigned short* __restrict__ xa, unsigned short* __restrict__ xr) {
  __shared__ float xas[16][128];
  int b = blockIdx.x >> 8, t = blockIdx.x & 255;
  int tid = threadIdx.x;
#pragma unroll
  for (int jj = 0; jj < 2; ++jj) {
    int idx = tid + (jj << 7);
    int r = idx >> 4, c8 = (idx & 15) * 8;
    ushortx8 vv = *(const ushortx8*)(xa + ((size_t)((b * 16 + r) * 256 + t)) * 128 + c8);
#pragma unroll
    for (int j = 0; j < 8; ++j) xas[r][c8 + j] = bf2f(vv[j]);
  }
  __syncthreads();
  int h = tid >> 4, q = tid & 15;
  float xq[16];
#pragma unroll
  for (int d = 0; d < 16; d++) xq[d] = xas[q][h * 16 + d];
  float sc[16];
  float mx = -1e30f;
#pragma unroll
  for (int k = 0; k < 16; k++) {
    float s = 0.f;
#pragma unroll
    for (int d = 0; d < 16; d++) s += xq[d] * xas[k][h * 16 + d];
    s *= 0.25f;
    sc[k] = s;
    mx = fmaxf(mx, s);
  }
  float den = 0.f;
#pragma unroll
  for (int k = 0; k < 16; k++) { sc[k] = __expf(sc[k] - mx); den += sc[k]; }
  float inv = 1.0f / den;
  float out[16] = {};
#pragma unroll
  for (int k = 0; k < 16; k++) {
    float w = sc[k];
#pragma unroll
    for (int d = 0; d < 16; d++) out[d] += w * xas[k][h * 16 + d];
  }
  int g = q * 4 + b;
  unsigned short* dstp = xr + ((size_t)(g * 256 + t)) * 128 + h * 16;
  ushortx8 r0;
#pragma unroll
  for (int j = 0; j < 8; ++j) r0[j] = f2bf(out[j] * inv);
  *(ushortx8*)dstp = r0;
#pragma unroll
  for (int j = 0; j < 8; ++j) r0[j] = f2bf(out[8 + j] * inv);
  *(ushortx8*)(dstp + 8) = r0;
}

extern "C" void kernel_launch(void* const* d_in, const int* in_sizes, int n_in,
                              void* d_out, int out_size, void* d_ws, size_t ws_size,
                              hipStream_t stream) {
  const float* x    = (const float*)d_in[0];
  const float* Wq   = (const float*)d_in[1];
  const float* bq   = (const float*)d_in[2];
  const float* Wk   = (const float*)d_in[3];
  const float* bk   = (const float*)d_in[4];
  const float* Wv   = (const float*)d_in[5];
  const float* bv   = (const float*)d_in[6];
  const float* Wo   = (const float*)d_in[7];
  const float* bo   = (const float*)d_in[8];
  const float* W1   = (const float*)d_in[9];
  const float* b1   = (const float*)d_in[10];
  const float* W2   = (const float*)d_in[11];
  const float* b2   = (const float*)d_in[12];
  const float* ln1g = (const float*)d_in[13];
  const float* ln1b = (const float*)d_in[14];
  const float* ln2g = (const float*)d_in[15];
  const float* ln2b = (const float*)d_in[16];
  const float* lnfg = (const float*)d_in[17];
  const float* lnfb = (const float*)d_in[18];

  // ws layout (24.76 MB), all bf16 activations:
  char* base = (char*)d_ws;
  unsigned short* CQb = (unsigned short*)base;                 // [0,4M)
  unsigned short* CKb = (unsigned short*)(base + (4u  << 20)); // [4,8)
  unsigned short* Qb  = (unsigned short*)(base + (8u  << 20)); // [8,12)  Q|K|V contiguous
  unsigned short* Kb  = (unsigned short*)(base + (12u << 20)); // [12,16)
  unsigned short* Vb  = (unsigned short*)(base + (16u << 20)); // [16,20)  (attn1 out in-place)
  unsigned short* Ab  = (unsigned short*)(base + (20u << 20)); // [20,24)
  unsigned short* Wb  = (unsigned short*)(base + (24u << 20)); // 768 KB
  float*          Bs  = (float*)(base + (24u << 20) + 786432); // 9.2 KB
  float*          Y   = (float*)d_out;

  prep_kernel<<<4297, 256, 0, stream>>>(x, Wq, Wk, Wv, Wo, W1, W2,
                                        bq, bk, bv, bo, b1, b2,
                                        ln1g, ln1b, Wb, Bs, Ab);

  for (int i = 0; i < 2; ++i) {
    const float* rin = i ? Y : x;
    const unsigned short* Wl = Wb + (size_t)i * 196608;
    const float* Bl = Bs + i * 1152;
    // QKV: 16384x384x128 GEMM, 1024 16-row blocks, epilogue splits to Q/K/V
    gemm_kernel<3, 1><<<1024, 512, 0, stream>>>(Ab, 128, Wl, 128, Bl, Qb, 128);
    // context combine -> CQ, CK
    ctx_kernel<<<dim3(64, 2, 8), 128, 0, stream>>>(Qb, Kb, CQb, CKb);
    // T x T attention (writes bf16 in-place over Vb)
    attn1_kernel<<<512, 256, 0, stream>>>(CQb, CKb, Vb);
    // M attention with scramble -> Ab
    attn2_kernel<<<1024, 128, 0, stream>>>(Vb, Ab);
    // fused: Wo + rin -> LN2 -> W1+relu -> W2 + resid -> next-LN
    if (i == 0) {
      ffn_kernel<<<256, 512, 0, stream>>>(Ab, Wl + 49152, Wl + 65536, Wl + 131072, Bl,
          rin, ln2g, ln2b, ln1g + 128, ln1b + 128, Y, Ab, 0);
    } else {
      ffn_kernel<<<256, 512, 0, stream>>>(Ab, Wl + 49152, Wl + 65536, Wl + 131072, Bl,
          rin, ln2g + 128, ln2b + 128, lnfg, lnfb, Y, nullptr, 1);
    }
  }
}